// Round 6
// baseline (4241.900 us; speedup 1.0000x reference)
//
#include <hip/hip_runtime.h>

typedef unsigned short u16;
typedef _Float16 f16;
typedef _Float16 f16x8 __attribute__((ext_vector_type(8)));
typedef float f32x4 __attribute__((ext_vector_type(4)));
typedef unsigned short u16x8 __attribute__((ext_vector_type(8)));
typedef unsigned short u16x4 __attribute__((ext_vector_type(4)));

static __device__ __forceinline__ u16 f2h(float f) {
  f16 h = (f16)f;
  return __builtin_bit_cast(u16, h);
}
static __device__ __forceinline__ float h2f(u16 h) {
  return (float)__builtin_bit_cast(f16, h);
}

static __device__ __forceinline__ f32x4 mfma16h(u16x8 a, u16x8 b, f32x4 c) {
  return __builtin_amdgcn_mfma_f32_16x16x32_f16(
      __builtin_bit_cast(f16x8, a), __builtin_bit_cast(f16x8, b), c, 0, 0, 0);
}

// ---------------- cos/sin tables [S][64], f64-accurate ----------------
__global__ void k_trig(float* __restrict__ cosT, float* __restrict__ sinT) {
  int idx = blockIdx.x * blockDim.x + threadIdx.x;  // S*64 threads
  int s = idx >> 6, j = idx & 63;
  double theta = exp2(-0.4152410118609203 * (double)j);  // 10000^(-j/32), f64
  double ang = (double)s * theta;
  cosT[idx] = (float)cos(ang);
  sinT[idx] = (float)sin(ang);
}

// ---------------- split-fp16 TN GEMM: C = A (f32) * B^T (f32), 3-pass Dekker ----------------
// MODE 0: scatter split hi/lo to [BH][S][64]   MODE 2: scatter hi only to [BH][S][64]
template <int MODE>
__global__ __launch_bounds__(256) void k_gemm_split(
    const float* __restrict__ A, const float* __restrict__ Bw,
    int M, int N, int K,
    u16* __restrict__ outH, u16* __restrict__ outL) {
  constexpr int LDT = 40;
  __shared__ __align__(16) u16 Ash[128 * LDT];
  __shared__ __align__(16) u16 Asl[128 * LDT];
  __shared__ __align__(16) u16 Bsh[128 * LDT];
  __shared__ __align__(16) u16 Bsl[128 * LDT];
  const int tid = threadIdx.x;
  const int m0 = blockIdx.y * 128;
  const int n0 = blockIdx.x * 128;
  const int lane = tid & 63, lr = lane & 15, lg = lane >> 4;
  const int wid = tid >> 6;
  const int wm = (wid >> 1) * 64, wn = (wid & 1) * 64;

  const f32x4 fz = {0.f, 0.f, 0.f, 0.f};
  f32x4 acc[4][4];
#pragma unroll
  for (int i = 0; i < 4; i++)
#pragma unroll
    for (int j = 0; j < 4; j++) acc[i][j] = fz;

  for (int k0 = 0; k0 < K; k0 += 32) {
    __syncthreads();
#pragma unroll
    for (int p = 0; p < 4; p++) {
      int c = p * 256 + tid;
      int row = c >> 3, col = (c & 7) * 4;
      float4 av = *reinterpret_cast<const float4*>(&A[(size_t)(m0 + row) * K + k0 + col]);
      float4 bv = *reinterpret_cast<const float4*>(&Bw[(size_t)(n0 + row) * K + k0 + col]);
      const float* ap = reinterpret_cast<const float*>(&av);
      const float* bp = reinterpret_cast<const float*>(&bv);
#pragma unroll
      for (int e = 0; e < 4; e++) {
        u16 h = f2h(ap[e]);
        Ash[row * LDT + col + e] = h;
        Asl[row * LDT + col + e] = f2h(ap[e] - h2f(h));
        h = f2h(bp[e]);
        Bsh[row * LDT + col + e] = h;
        Bsl[row * LDT + col + e] = f2h(bp[e] - h2f(h));
      }
    }
    __syncthreads();
    u16x8 ah[4], al[4], bh[4], bl[4];
#pragma unroll
    for (int i = 0; i < 4; i++) {
      ah[i] = *reinterpret_cast<const u16x8*>(&Ash[(wm + i * 16 + lr) * LDT + 8 * lg]);
      al[i] = *reinterpret_cast<const u16x8*>(&Asl[(wm + i * 16 + lr) * LDT + 8 * lg]);
    }
#pragma unroll
    for (int j = 0; j < 4; j++) {
      bh[j] = *reinterpret_cast<const u16x8*>(&Bsh[(wn + j * 16 + lr) * LDT + 8 * lg]);
      bl[j] = *reinterpret_cast<const u16x8*>(&Bsl[(wn + j * 16 + lr) * LDT + 8 * lg]);
    }
#pragma unroll
    for (int i = 0; i < 4; i++)
#pragma unroll
      for (int j = 0; j < 4; j++) {
        acc[i][j] = mfma16h(ah[i], bh[j], acc[i][j]);
        acc[i][j] = mfma16h(ah[i], bl[j], acc[i][j]);
        acc[i][j] = mfma16h(al[i], bh[j], acc[i][j]);
      }
  }

#pragma unroll
  for (int i = 0; i < 4; i++)
#pragma unroll
    for (int j = 0; j < 4; j++)
#pragma unroll
      for (int r = 0; r < 4; r++) {
        int m = m0 + wm + i * 16 + 4 * lg + r;
        int n = n0 + wn + j * 16 + lr;
        float v = acc[i][j][r];
        int b = m >> 11, s = m & 2047;  // S = 2048
        int h = n >> 6, jj = n & 63;
        size_t o = (((size_t)(b * 16 + h)) * 2048 + s) * 64 + jj;
        u16 hh = f2h(v);
        outH[o] = hh;
        if constexpr (MODE == 0) outL[o] = f2h(v - h2f(hh));
      }
}

// ---------------- single-pass fp16 GEMM for out = Y @ Wo^T ----------------
__global__ __launch_bounds__(256) void k_gemm_out(
    const u16* __restrict__ A, const float* __restrict__ Bw,
    int M, int N, int K, float* __restrict__ outF) {
  constexpr int LDT = 40;
  __shared__ __align__(16) u16 As[128 * LDT];
  __shared__ __align__(16) u16 Bs[128 * LDT];
  const int tid = threadIdx.x;
  const int m0 = blockIdx.y * 128;
  const int n0 = blockIdx.x * 128;
  const int lane = tid & 63, lr = lane & 15, lg = lane >> 4;
  const int wid = tid >> 6;
  const int wm = (wid >> 1) * 64, wn = (wid & 1) * 64;

  const f32x4 fz = {0.f, 0.f, 0.f, 0.f};
  f32x4 acc[4][4];
#pragma unroll
  for (int i = 0; i < 4; i++)
#pragma unroll
    for (int j = 0; j < 4; j++) acc[i][j] = fz;

  for (int k0 = 0; k0 < K; k0 += 32) {
    __syncthreads();
#pragma unroll
    for (int p = 0; p < 2; p++) {
      int c = p * 256 + tid;
      int row = c >> 2, col = (c & 3) * 8;
      *reinterpret_cast<int4*>(&As[row * LDT + col]) =
          *reinterpret_cast<const int4*>(&A[(size_t)(m0 + row) * K + k0 + col]);
    }
#pragma unroll
    for (int p = 0; p < 4; p++) {
      int c = p * 256 + tid;
      int row = c >> 3, col = (c & 7) * 4;
      float4 bv = *reinterpret_cast<const float4*>(&Bw[(size_t)(n0 + row) * K + k0 + col]);
      const float* bp = reinterpret_cast<const float*>(&bv);
#pragma unroll
      for (int e = 0; e < 4; e++) Bs[row * LDT + col + e] = f2h(bp[e]);
    }
    __syncthreads();
    u16x8 af[4], bf[4];
#pragma unroll
    for (int i = 0; i < 4; i++)
      af[i] = *reinterpret_cast<const u16x8*>(&As[(wm + i * 16 + lr) * LDT + 8 * lg]);
#pragma unroll
    for (int j = 0; j < 4; j++)
      bf[j] = *reinterpret_cast<const u16x8*>(&Bs[(wn + j * 16 + lr) * LDT + 8 * lg]);
#pragma unroll
    for (int i = 0; i < 4; i++)
#pragma unroll
      for (int j = 0; j < 4; j++) acc[i][j] = mfma16h(af[i], bf[j], acc[i][j]);
  }

#pragma unroll
  for (int i = 0; i < 4; i++)
#pragma unroll
    for (int j = 0; j < 4; j++)
#pragma unroll
      for (int r = 0; r < 4; r++) {
        int m = m0 + wm + i * 16 + 4 * lg + r;
        int n = n0 + wn + j * 16 + lr;
        outF[(size_t)m * N + n] = acc[i][j][r];
      }
}

// ---------------- SIMPLE f32 retention (bisection probe): no MFMA anywhere ----------------
// Block = (bh, 32 s-rows). Stage rotated Q'/K' f32 in LDS, f32 scores+decay, f32 PV, f32 LN.
__global__ __launch_bounds__(256) void k_ret_simple(
    const u16* __restrict__ qh_, const u16* __restrict__ ql_,
    const u16* __restrict__ kh_, const u16* __restrict__ kl_,
    const u16* __restrict__ vh_,
    const float* __restrict__ cosT, const float* __restrict__ sinT,
    const float* __restrict__ lnw, const float* __restrict__ lnb,
    u16* __restrict__ Y) {
  __shared__ float Qs[32][132];   // padded stride to spread banks
  __shared__ float Kt[32][132];
  __shared__ float Vs[32][64];
  __shared__ float Ps[32][32];
  __shared__ float Rs[32][64];
  __shared__ float mus[32], rstds[32];
  const int tid = threadIdx.x;
  const int bh = blockIdx.y, b = bh >> 4, h = bh & 15;
  const int sc = (int)gridDim.x - 1 - (int)blockIdx.x;  // heavy chunks first
  const int s0 = sc * 32;
  const float lg2g = log2f(1.0f - exp2f(-5.0f - (float)h));

  for (int p = tid; p < 2048; p += 256) { int sl = p >> 6, j = p & 63; Rs[sl][j] = 0.f; }
  // stage rotated Q' [32][128]
  for (int p = tid; p < 4096; p += 256) {
    int sl = p >> 7, d = p & 127, s = s0 + sl, du = d & 63;
    size_t o = ((size_t)bh * 2048 + s) * 64 + du;
    float qv = h2f(qh_[o]) + h2f(ql_[o]);
    float tr = (d < 64) ? cosT[s * 64 + du] : sinT[s * 64 + du];
    Qs[sl][d] = qv * tr;
  }
  __syncthreads();

  for (int kt = 0; kt <= sc; ++kt) {
    const int t0 = kt * 32;
    for (int p = tid; p < 4096; p += 256) {
      int tl = p >> 7, d = p & 127, t = t0 + tl, du = d & 63;
      size_t o = ((size_t)bh * 2048 + t) * 64 + du;
      float kv = h2f(kh_[o]) + h2f(kl_[o]);
      float tr = (d < 64) ? cosT[t * 64 + du] : sinT[t * 64 + du];
      Kt[tl][d] = kv * tr;
    }
    for (int p = tid; p < 2048; p += 256) {
      int tl = p >> 6, j = p & 63;
      Vs[tl][j] = h2f(vh_[((size_t)bh * 2048 + t0 + tl) * 64 + j]);
    }
    __syncthreads();
    // scores: each thread computes a 2x2 block of Ps
    {
      int sl0 = 2 * (tid >> 4), tl0 = 2 * (tid & 15);
      float a00 = 0.f, a01 = 0.f, a10 = 0.f, a11 = 0.f;
      for (int d = 0; d < 128; d += 4) {
        float4 q0 = *reinterpret_cast<const float4*>(&Qs[sl0][d]);
        float4 q1 = *reinterpret_cast<const float4*>(&Qs[sl0 + 1][d]);
        float4 k0 = *reinterpret_cast<const float4*>(&Kt[tl0][d]);
        float4 k1 = *reinterpret_cast<const float4*>(&Kt[tl0 + 1][d]);
        a00 += q0.x * k0.x + q0.y * k0.y + q0.z * k0.z + q0.w * k0.w;
        a01 += q0.x * k1.x + q0.y * k1.y + q0.z * k1.z + q0.w * k1.w;
        a10 += q1.x * k0.x + q1.y * k0.y + q1.z * k0.z + q1.w * k0.w;
        a11 += q1.x * k1.x + q1.y * k1.y + q1.z * k1.z + q1.w * k1.w;
      }
#pragma unroll
      for (int ii = 0; ii < 2; ii++)
#pragma unroll
        for (int jj = 0; jj < 2; jj++) {
          int s = s0 + sl0 + ii, t = t0 + tl0 + jj;
          float v = (ii == 0 ? (jj == 0 ? a00 : a01) : (jj == 0 ? a10 : a11));
          Ps[sl0 + ii][tl0 + jj] = (t <= s) ? v * exp2f((float)(s - t) * lg2g) : 0.f;
        }
    }
    __syncthreads();
    // PV accumulate: thread owns fixed (sl,j) cells
    for (int p = tid; p < 2048; p += 256) {
      int sl = p >> 6, j = p & 63;
      float acc = Rs[sl][j];
      for (int tl = 0; tl < 32; ++tl) acc += Ps[sl][tl] * Vs[tl][j];
      Rs[sl][j] = acc;
    }
    __syncthreads();
  }

  if (tid < 32) {
    float s1 = 0.f, s2 = 0.f;
    for (int j = 0; j < 64; j++) { float v = Rs[tid][j]; s1 += v; s2 += v * v; }
    float mu = s1 * (1.f / 64.f);
    float var = s2 * (1.f / 64.f) - mu * mu;
    mus[tid] = mu; rstds[tid] = rsqrtf(var + 1e-5f);
  }
  __syncthreads();
  for (int p = tid; p < 2048; p += 256) {
    int sl = p >> 6, j = p & 63;
    int s = s0 + sl;
    float y = (Rs[sl][j] - mus[sl]) * rstds[sl] * lnw[j] + lnb[j];
    y = y / (1.f + expf(-y));
    Y[((size_t)b * 2048 + s) * 1024 + h * 64 + j] = f2h(y);
  }
}

// ---------------- f64-exact patch for rows s < SP ----------------
#define SP 32
__global__ __launch_bounds__(256) void k_patch(
    const float* __restrict__ x, const float* __restrict__ Wq,
    const float* __restrict__ Wk, const float* __restrict__ Wv,
    const float* __restrict__ cosT, const float* __restrict__ sinT,
    const float* __restrict__ lnw, const float* __restrict__ lnb,
    u16* __restrict__ Y) {
  const int bh = blockIdx.x, b = bh >> 4, h = bh & 15;
  __shared__ float qs[SP][128], ks[SP][128], vs[SP][64];
  __shared__ float ps[SP][SP];
  __shared__ double rs[SP][64];
  __shared__ double mus[SP], rstds[SP];
  const int tid = threadIdx.x;
  const int grp = tid >> 4, gl = tid & 15;
  const double lg2g = log2(1.0 - exp2(-5.0 - (double)h));

  for (int dd = grp; dd < 3 * SP * 64; dd += 16) {
    int type = dd / (SP * 64);
    int idx = dd % (SP * 64);
    int s = idx >> 6, hd = idx & 63;
    const float* wrow = (type == 0 ? Wq : type == 1 ? Wk : Wv) + (size_t)(h * 64 + hd) * 1024;
    const float* xrow = x + ((size_t)b * 2048 + s) * 1024;
    double acc = 0.0;
    for (int k = gl * 4; k < 1024; k += 64) {
      float4 xv = *reinterpret_cast<const float4*>(xrow + k);
      float4 wv = *reinterpret_cast<const float4*>(wrow + k);
      acc += (double)xv.x * wv.x + (double)xv.y * wv.y + (double)xv.z * wv.z + (double)xv.w * wv.w;
    }
#pragma unroll
    for (int m = 1; m < 16; m <<= 1) acc += __shfl_xor(acc, m, 64);
    if (gl == 0) {
      float accf = (float)acc;
      if (type == 2) {
        vs[s][hd] = accf;
      } else {
        float cv = cosT[s * 64 + hd], sv = sinT[s * 64 + hd];
        if (type == 0) { qs[s][hd] = accf * cv; qs[s][64 + hd] = accf * sv; }
        else           { ks[s][hd] = accf * cv; ks[s][64 + hd] = accf * sv; }
      }
    }
  }
  __syncthreads();
  for (int p = tid; p < SP * SP; p += 256) {
    int s = p / SP, t = p % SP;
    double sc = 0.0;
    if (t <= s) {
      for (int d = 0; d < 128; d++) sc += (double)qs[s][d] * ks[t][d];
      sc *= exp2((double)(s - t) * lg2g);
    }
    ps[s][t] = (float)sc;
  }
  __syncthreads();
  for (int p = tid; p < SP * 64; p += 256) {
    int s = p >> 6, j = p & 63;
    double r = 0.0;
    for (int t = 0; t <= s && t < SP; t++) r += (double)ps[s][t] * vs[t][j];
    rs[s][j] = r;
  }
  __syncthreads();
  if (tid < SP) {
    double s1 = 0.0, s2 = 0.0;
    for (int j = 0; j < 64; j++) { double v = rs[tid][j]; s1 += v; s2 += v * v; }
    double mu = s1 * (1.0 / 64.0);
    double var = s2 * (1.0 / 64.0) - mu * mu;
    mus[tid] = mu; rstds[tid] = 1.0 / sqrt(var + 1e-5);
  }
  __syncthreads();
  for (int p = tid; p < SP * 64; p += 256) {
    int s = p >> 6, j = p & 63;
    double y = (rs[s][j] - mus[s]) * rstds[s] * (double)lnw[j] + (double)lnb[j];
    y = y / (1.0 + exp(-y));
    Y[((size_t)b * 2048 + s) * 1024 + h * 64 + j] = f2h((float)y);
  }
}

extern "C" void kernel_launch(void* const* d_in, const int* in_sizes, int n_in,
                              void* d_out, int out_size, void* d_ws, size_t ws_size,
                              hipStream_t stream) {
  const float* x   = (const float*)d_in[0];
  const float* Wq  = (const float*)d_in[1];
  const float* Wk  = (const float*)d_in[2];
  const float* Wv  = (const float*)d_in[3];
  const float* Wo  = (const float*)d_in[4];
  const float* lnw = (const float*)d_in[5];
  const float* lnb = (const float*)d_in[6];
  float* out = (float*)d_out;

  char* ws = (char*)d_ws;
  u16*   qh   = (u16*)(ws + 0);            // [BH][S][64]
  u16*   ql   = (u16*)(ws + 16777216);
  u16*   kh   = (u16*)(ws + 33554432);
  u16*   kl   = (u16*)(ws + 50331648);
  u16*   vh   = (u16*)(ws + 67108864);
  u16*   Y    = (u16*)(ws + 83886080);     // [B*S][D] fp16
  float* cosT = (float*)(ws + 100663296);  // [S][64] f32
  float* sinT = (float*)(ws + 101187584);

  k_trig<<<512, 256, 0, stream>>>(cosT, sinT);

  dim3 gg(8, 64);  // N/128, M/128
  k_gemm_split<0><<<gg, 256, 0, stream>>>(x, Wq, 8192, 1024, 1024, qh, ql);
  k_gemm_split<0><<<gg, 256, 0, stream>>>(x, Wk, 8192, 1024, 1024, kh, kl);
  k_gemm_split<2><<<gg, 256, 0, stream>>>(x, Wv, 8192, 1024, 1024, vh, nullptr);

  k_ret_simple<<<dim3(64, 64), 256, 0, stream>>>(qh, ql, kh, kl, vh, cosT, sinT, lnw, lnb, Y);

  k_patch<<<64, 256, 0, stream>>>(x, Wq, Wk, Wv, cosT, sinT, lnw, lnb, Y);

  k_gemm_out<<<gg, 256, 0, stream>>>(Y, Wo, 8192, 1024, 1024, out);
}

// Round 8
// 2812.415 us; speedup vs baseline: 1.5083x; 1.5083x over previous
//
#include <hip/hip_runtime.h>

typedef unsigned short u16;
typedef _Float16 f16;
typedef _Float16 f16x8 __attribute__((ext_vector_type(8)));
typedef float f32x4 __attribute__((ext_vector_type(4)));
typedef unsigned short u16x8 __attribute__((ext_vector_type(8)));
typedef unsigned short u16x4 __attribute__((ext_vector_type(4)));

static __device__ __forceinline__ u16 f2h(float f) {
  f16 h = (f16)f;
  return __builtin_bit_cast(u16, h);
}
static __device__ __forceinline__ float h2f(u16 h) {
  return (float)__builtin_bit_cast(f16, h);
}

static __device__ __forceinline__ f32x4 mfma16h(u16x8 a, u16x8 b, f32x4 c) {
  return __builtin_amdgcn_mfma_f32_16x16x32_f16(
      __builtin_bit_cast(f16x8, a), __builtin_bit_cast(f16x8, b), c, 0, 0, 0);
}

// ---------------- cos/sin tables [S][64], f64-accurate ----------------
__global__ void k_trig(float* __restrict__ cosT, float* __restrict__ sinT) {
  int idx = blockIdx.x * blockDim.x + threadIdx.x;  // S*64 threads
  int s = idx >> 6, j = idx & 63;
  double theta = exp2(-0.4152410118609203 * (double)j);  // 10000^(-j/32), f64
  double ang = (double)s * theta;
  cosT[idx] = (float)cos(ang);
  sinT[idx] = (float)sin(ang);
}

// ---------------- split-fp16 TN GEMM: C = A (f32) * B^T (f32), 3-pass Dekker ----------------
// MODE 0: scatter split hi/lo to [BH][S][64]   MODE 2: scatter hi only to [BH][S][64]
template <int MODE>
__global__ __launch_bounds__(256) void k_gemm_split(
    const float* __restrict__ A, const float* __restrict__ Bw,
    int M, int N, int K,
    u16* __restrict__ outH, u16* __restrict__ outL) {
  constexpr int LDT = 40;
  __shared__ __align__(16) u16 Ash[128 * LDT];
  __shared__ __align__(16) u16 Asl[128 * LDT];
  __shared__ __align__(16) u16 Bsh[128 * LDT];
  __shared__ __align__(16) u16 Bsl[128 * LDT];
  const int tid = threadIdx.x;
  const int m0 = blockIdx.y * 128;
  const int n0 = blockIdx.x * 128;
  const int lane = tid & 63, lr = lane & 15, lg = lane >> 4;
  const int wid = tid >> 6;
  const int wm = (wid >> 1) * 64, wn = (wid & 1) * 64;

  const f32x4 fz = {0.f, 0.f, 0.f, 0.f};
  f32x4 acc[4][4];
#pragma unroll
  for (int i = 0; i < 4; i++)
#pragma unroll
    for (int j = 0; j < 4; j++) acc[i][j] = fz;

  for (int k0 = 0; k0 < K; k0 += 32) {
    __syncthreads();
#pragma unroll
    for (int p = 0; p < 4; p++) {
      int c = p * 256 + tid;
      int row = c >> 3, col = (c & 7) * 4;
      float4 av = *reinterpret_cast<const float4*>(&A[(size_t)(m0 + row) * K + k0 + col]);
      float4 bv = *reinterpret_cast<const float4*>(&Bw[(size_t)(n0 + row) * K + k0 + col]);
      const float* ap = reinterpret_cast<const float*>(&av);
      const float* bp = reinterpret_cast<const float*>(&bv);
#pragma unroll
      for (int e = 0; e < 4; e++) {
        u16 h = f2h(ap[e]);
        Ash[row * LDT + col + e] = h;
        Asl[row * LDT + col + e] = f2h(ap[e] - h2f(h));
        h = f2h(bp[e]);
        Bsh[row * LDT + col + e] = h;
        Bsl[row * LDT + col + e] = f2h(bp[e] - h2f(h));
      }
    }
    __syncthreads();
    u16x8 ah[4], al[4], bh[4], bl[4];
#pragma unroll
    for (int i = 0; i < 4; i++) {
      ah[i] = *reinterpret_cast<const u16x8*>(&Ash[(wm + i * 16 + lr) * LDT + 8 * lg]);
      al[i] = *reinterpret_cast<const u16x8*>(&Asl[(wm + i * 16 + lr) * LDT + 8 * lg]);
    }
#pragma unroll
    for (int j = 0; j < 4; j++) {
      bh[j] = *reinterpret_cast<const u16x8*>(&Bsh[(wn + j * 16 + lr) * LDT + 8 * lg]);
      bl[j] = *reinterpret_cast<const u16x8*>(&Bsl[(wn + j * 16 + lr) * LDT + 8 * lg]);
    }
#pragma unroll
    for (int i = 0; i < 4; i++)
#pragma unroll
      for (int j = 0; j < 4; j++) {
        acc[i][j] = mfma16h(ah[i], bh[j], acc[i][j]);
        acc[i][j] = mfma16h(ah[i], bl[j], acc[i][j]);
        acc[i][j] = mfma16h(al[i], bh[j], acc[i][j]);
      }
  }

#pragma unroll
  for (int i = 0; i < 4; i++)
#pragma unroll
    for (int j = 0; j < 4; j++)
#pragma unroll
      for (int r = 0; r < 4; r++) {
        int m = m0 + wm + i * 16 + 4 * lg + r;
        int n = n0 + wn + j * 16 + lr;
        float v = acc[i][j][r];
        int b = m >> 11, s = m & 2047;  // S = 2048
        int h = n >> 6, jj = n & 63;
        size_t o = (((size_t)(b * 16 + h)) * 2048 + s) * 64 + jj;
        if constexpr (MODE == 2) {
          outH[o] = f2h(v);
        } else {
          u16 hh = f2h(v);
          outH[o] = hh;
          outL[o] = f2h(v - h2f(hh));
        }
      }
}

// ---------------- single-pass fp16 GEMM for out = Y @ Wo^T ----------------
__global__ __launch_bounds__(256) void k_gemm_out(
    const u16* __restrict__ A, const float* __restrict__ Bw,
    int M, int N, int K, float* __restrict__ outF) {
  constexpr int LDT = 40;
  __shared__ __align__(16) u16 As[128 * LDT];
  __shared__ __align__(16) u16 Bs[128 * LDT];
  const int tid = threadIdx.x;
  const int m0 = blockIdx.y * 128;
  const int n0 = blockIdx.x * 128;
  const int lane = tid & 63, lr = lane & 15, lg = lane >> 4;
  const int wid = tid >> 6;
  const int wm = (wid >> 1) * 64, wn = (wid & 1) * 64;

  const f32x4 fz = {0.f, 0.f, 0.f, 0.f};
  f32x4 acc[4][4];
#pragma unroll
  for (int i = 0; i < 4; i++)
#pragma unroll
    for (int j = 0; j < 4; j++) acc[i][j] = fz;

  for (int k0 = 0; k0 < K; k0 += 32) {
    __syncthreads();
#pragma unroll
    for (int p = 0; p < 2; p++) {
      int c = p * 256 + tid;
      int row = c >> 2, col = (c & 3) * 8;
      *reinterpret_cast<int4*>(&As[row * LDT + col]) =
          *reinterpret_cast<const int4*>(&A[(size_t)(m0 + row) * K + k0 + col]);
    }
#pragma unroll
    for (int p = 0; p < 4; p++) {
      int c = p * 256 + tid;
      int row = c >> 3, col = (c & 7) * 4;
      float4 bv = *reinterpret_cast<const float4*>(&Bw[(size_t)(n0 + row) * K + k0 + col]);
      const float* bp = reinterpret_cast<const float*>(&bv);
#pragma unroll
      for (int e = 0; e < 4; e++) Bs[row * LDT + col + e] = f2h(bp[e]);
    }
    __syncthreads();
    u16x8 af[4], bf[4];
#pragma unroll
    for (int i = 0; i < 4; i++)
      af[i] = *reinterpret_cast<const u16x8*>(&As[(wm + i * 16 + lr) * LDT + 8 * lg]);
#pragma unroll
    for (int j = 0; j < 4; j++)
      bf[j] = *reinterpret_cast<const u16x8*>(&Bs[(wn + j * 16 + lr) * LDT + 8 * lg]);
#pragma unroll
    for (int i = 0; i < 4; i++)
#pragma unroll
      for (int j = 0; j < 4; j++) acc[i][j] = mfma16h(af[i], bf[j], acc[i][j]);
  }

#pragma unroll
  for (int i = 0; i < 4; i++)
#pragma unroll
    for (int j = 0; j < 4; j++)
#pragma unroll
      for (int r = 0; r < 4; r++) {
        int m = m0 + wm + i * 16 + 4 * lg + r;
        int n = n0 + wn + j * 16 + lr;
        outF[(size_t)m * N + n] = acc[i][j][r];
      }
}

// ---------------- hybrid retention: MFMA QK^T (Cluster A) + VALU PV (round-6-validated) ----------------
constexpr int LDK = 136;   // u16 stride, rotated split Q'/K' tiles [64][128]
constexpr int LDP = 76;    // f32 stride, P tile [64 q][64 t]
constexpr int LDVF = 68;   // f32 stride, V tile [64 t][64 j]

// stage 64 rows of rotated+split head-vectors (from unrotated hi/lo pairs) into LDS
static __device__ __forceinline__ void stage_rot_split(
    const u16* __restrict__ hsrc, const u16* __restrict__ lsrc,
    const float* __restrict__ cosT, const float* __restrict__ sinT,
    int bh, int r0, int tid, u16* Ksh, u16* Ksl) {
#pragma unroll
  for (int p = 0; p < 2; p++) {
    int c = p * 256 + tid;  // [0,512): 64 rows x 8 chunks of 8 dims
    int row = c >> 3, d0 = (c & 7) * 8;
    int sg = r0 + row;
    size_t gb = ((size_t)bh * 2048 + sg) * 64 + d0;
    u16x8 h8 = *reinterpret_cast<const u16x8*>(&hsrc[gb]);
    u16x8 l8 = *reinterpret_cast<const u16x8*>(&lsrc[gb]);
#pragma unroll
    for (int e = 0; e < 8; e++) {
      int d = d0 + e;
      float v = h2f(h8[e]) + h2f(l8[e]);
      float cv = cosT[sg * 64 + d], sv = sinT[sg * 64 + d];
      float a = v * cv;
      u16 ah = f2h(a);
      Ksh[row * LDK + d] = ah;
      Ksl[row * LDK + d] = f2h(a - h2f(ah));
      float bb = v * sv;
      u16 bh2 = f2h(bb);
      Ksh[row * LDK + 64 + d] = bh2;
      Ksl[row * LDK + 64 + d] = f2h(bb - h2f(bh2));
    }
  }
}

__global__ __launch_bounds__(256) void k_ret_hybrid(
    const u16* __restrict__ qh_, const u16* __restrict__ ql_,
    const u16* __restrict__ kh_, const u16* __restrict__ kl_,
    const u16* __restrict__ vh_,
    const float* __restrict__ cosT, const float* __restrict__ sinT,
    const float* __restrict__ lnw, const float* __restrict__ lnb,
    u16* __restrict__ Y) {
  // LDS plan (54272 B): Ksh[0,17408) Ksl[17408,34816) Ps[34816,54272)
  // Vs (f32 [64][68] = 17408 B) overlays Ksh after QK^T reads complete.
  __shared__ __align__(16) char SM[54272];
  u16*   Ksh = (u16*)SM;
  u16*   Ksl = (u16*)(SM + 17408);
  float* Ps  = (float*)(SM + 34816);
  float* Vs  = (float*)SM;

  const int tid = threadIdx.x;
  const int bh = blockIdx.y, b = bh >> 4, h = bh & 15;
  const int qt = (int)gridDim.x - 1 - (int)blockIdx.x;  // heavy tiles first
  const int qbase = qt * 64;
  const int wid = tid >> 6, lane = tid & 63, lr = lane & 15, lg = lane >> 4;
  const int qg = qbase + wid * 16;  // this wave's first q row
  const float lg2g = log2f(1.0f - exp2f(-5.0f - (float)h));

  // ---- prologue: stage rotated+split Q' via the K buffers, read A-fragments ----
  stage_rot_split(qh_, ql_, cosT, sinT, bh, qbase, tid, Ksh, Ksl);
  __syncthreads();
  u16x8 qah[4], qal[4];  // A-fragment (GEMM af pattern): row = wave base + lr
#pragma unroll
  for (int dc = 0; dc < 4; dc++) {
    qah[dc] = *reinterpret_cast<const u16x8*>(&Ksh[(wid * 16 + lr) * LDK + dc * 32 + 8 * lg]);
    qal[dc] = *reinterpret_cast<const u16x8*>(&Ksl[(wid * 16 + lr) * LDK + dc * 32 + 8 * lg]);
  }

  const f32x4 fz = {0.f, 0.f, 0.f, 0.f};
  // VALU PV accumulators: thread owns (row = 4*k + wid, col = lane), k = 0..15
  float racc[16];
#pragma unroll
  for (int k = 0; k < 16; k++) racc[k] = 0.f;

  for (int kt = 0; kt <= qt; ++kt) {
    const int t0 = kt * 64;
    __syncthreads();  // prior tile's Vs/Ps reads (and prologue frag reads) done
    stage_rot_split(kh_, kl_, cosT, sinT, bh, t0, tid, Ksh, Ksl);
    __syncthreads();

    // ---- Cluster A: MFMA QK^T, mask+decay on D-fragment, P -> LDS ----
#pragma unroll
    for (int tn = 0; tn < 4; tn++) {
      f32x4 st = fz;
#pragma unroll
      for (int dc = 0; dc < 4; dc++) {
        u16x8 kbh = *reinterpret_cast<const u16x8*>(&Ksh[(tn * 16 + lr) * LDK + dc * 32 + 8 * lg]);
        u16x8 kbl = *reinterpret_cast<const u16x8*>(&Ksl[(tn * 16 + lr) * LDK + dc * 32 + 8 * lg]);
        st = mfma16h(qah[dc], kbh, st);
        st = mfma16h(qal[dc], kbh, st);
        st = mfma16h(qah[dc], kbl, st);
      }
      const int t = t0 + tn * 16 + lr;
#pragma unroll
      for (int i = 0; i < 4; i++) {
        int q = qg + 4 * lg + i;
        float v = st[i];
        v = (t <= q) ? v * exp2f((float)(q - t) * lg2g) : 0.f;
        Ps[(wid * 16 + 4 * lg + i) * LDP + tn * 16 + lr] = v;
      }
    }
    __syncthreads();  // all P written; all K-tile LDS reads done

    // ---- stage V tile f32 row-major [t][j] (overlays Ksh) ----
#pragma unroll
    for (int p = 0; p < 2; p++) {
      int c = p * 256 + tid;
      int tl = c >> 3, j0 = (c & 7) * 8;
      u16x8 v8 = *reinterpret_cast<const u16x8*>(&vh_[((size_t)bh * 2048 + t0 + tl) * 64 + j0]);
#pragma unroll
      for (int e = 0; e < 8; e++) Vs[tl * LDVF + j0 + e] = h2f(v8[e]);
    }
    __syncthreads();

    // ---- round-6-style VALU PV ----
    for (int tl = 0; tl < 64; ++tl) {
      float v = Vs[tl * LDVF + lane];
#pragma unroll
      for (int k = 0; k < 16; ++k)
        racc[k] += Ps[(4 * k + wid) * LDP + tl] * v;
    }
  }

  // ---- round-6-style LN + SiLU: one row per (k, wid), cols across lanes ----
#pragma unroll
  for (int k = 0; k < 16; ++k) {
    float v = racc[k];
    float s1 = v, s2 = v * v;
#pragma unroll
    for (int msk = 1; msk < 64; msk <<= 1) {
      s1 += __shfl_xor(s1, msk, 64);
      s2 += __shfl_xor(s2, msk, 64);
    }
    float mu = s1 * (1.f / 64.f);
    float var = s2 * (1.f / 64.f) - mu * mu;
    float rstd = rsqrtf(var + 1e-5f);
    int srow = qbase + 4 * k + wid;
    float y = (v - mu) * rstd * lnw[lane] + lnb[lane];
    y = y / (1.f + expf(-y));
    Y[((size_t)b * 2048 + srow) * 1024 + h * 64 + lane] = f2h(y);
  }
}

// ---------------- f64-exact patch for rows s < SP ----------------
#define SP 32
__global__ __launch_bounds__(256) void k_patch(
    const float* __restrict__ x, const float* __restrict__ Wq,
    const float* __restrict__ Wk, const float* __restrict__ Wv,
    const float* __restrict__ cosT, const float* __restrict__ sinT,
    const float* __restrict__ lnw, const float* __restrict__ lnb,
    u16* __restrict__ Y) {
  const int bh = blockIdx.x, b = bh >> 4, h = bh & 15;
  __shared__ float qs[SP][128], ks[SP][128], vs[SP][64];
  __shared__ float ps[SP][SP];
  __shared__ double rs[SP][64];
  __shared__ double mus[SP], rstds[SP];
  const int tid = threadIdx.x;
  const int grp = tid >> 4, gl = tid & 15;
  const double lg2g = log2(1.0 - exp2(-5.0 - (double)h));

  for (int dd = grp; dd < 3 * SP * 64; dd += 16) {
    int type = dd / (SP * 64);
    int idx = dd % (SP * 64);
    int s = idx >> 6, hd = idx & 63;
    const float* wrow = (type == 0 ? Wq : type == 1 ? Wk : Wv) + (size_t)(h * 64 + hd) * 1024;
    const float* xrow = x + ((size_t)b * 2048 + s) * 1024;
    double acc = 0.0;
    for (int k = gl * 4; k < 1024; k += 64) {
      float4 xv = *reinterpret_cast<const float4*>(xrow + k);
      float4 wv = *reinterpret_cast<const float4*>(wrow + k);
      acc += (double)xv.x * wv.x + (double)xv.y * wv.y + (double)xv.z * wv.z + (double)xv.w * wv.w;
    }
#pragma unroll
    for (int m = 1; m < 16; m <<= 1) acc += __shfl_xor(acc, m, 64);
    if (gl == 0) {
      float accf = (float)acc;
      if (type == 2) {
        vs[s][hd] = accf;
      } else {
        float cv = cosT[s * 64 + hd], sv = sinT[s * 64 + hd];
        if (type == 0) { qs[s][hd] = accf * cv; qs[s][64 + hd] = accf * sv; }
        else           { ks[s][hd] = accf * cv; ks[s][64 + hd] = accf * sv; }
      }
    }
  }
  __syncthreads();
  for (int p = tid; p < SP * SP; p += 256) {
    int s = p / SP, t = p % SP;
    double sc = 0.0;
    if (t <= s) {
      for (int d = 0; d < 128; d++) sc += (double)qs[s][d] * ks[t][d];
      sc *= exp2((double)(s - t) * lg2g);
    }
    ps[s][t] = (float)sc;
  }
  __syncthreads();
  for (int p = tid; p < SP * 64; p += 256) {
    int s = p >> 6, j = p & 63;
    double r = 0.0;
    for (int t = 0; t <= s && t < SP; t++) r += (double)ps[s][t] * vs[t][j];
    rs[s][j] = r;
  }
  __syncthreads();
  if (tid < SP) {
    double s1 = 0.0, s2 = 0.0;
    for (int j = 0; j < 64; j++) { double v = rs[tid][j]; s1 += v; s2 += v * v; }
    double mu = s1 * (1.0 / 64.0);
    double var = s2 * (1.0 / 64.0) - mu * mu;
    mus[tid] = mu; rstds[tid] = 1.0 / sqrt(var + 1e-5);
  }
  __syncthreads();
  for (int p = tid; p < SP * 64; p += 256) {
    int s = p >> 6, j = p & 63;
    double y = (rs[s][j] - mus[s]) * rstds[s] * (double)lnw[j] + (double)lnb[j];
    y = y / (1.0 + exp(-y));
    Y[((size_t)b * 2048 + s) * 1024 + h * 64 + j] = f2h((float)y);
  }
}

extern "C" void kernel_launch(void* const* d_in, const int* in_sizes, int n_in,
                              void* d_out, int out_size, void* d_ws, size_t ws_size,
                              hipStream_t stream) {
  const float* x   = (const float*)d_in[0];
  const float* Wq  = (const float*)d_in[1];
  const float* Wk  = (const float*)d_in[2];
  const float* Wv  = (const float*)d_in[3];
  const float* Wo  = (const float*)d_in[4];
  const float* lnw = (const float*)d_in[5];
  const float* lnb = (const float*)d_in[6];
  float* out = (float*)d_out;

  char* ws = (char*)d_ws;
  u16*   qh   = (u16*)(ws + 0);            // [BH][S][64]
  u16*   ql   = (u16*)(ws + 16777216);
  u16*   kh   = (u16*)(ws + 33554432);
  u16*   kl   = (u16*)(ws + 50331648);
  u16*   vh   = (u16*)(ws + 67108864);     // [BH][S][64] fp16
  u16*   Y    = (u16*)(ws + 83886080);     // [B*S][D] fp16
  float* cosT = (float*)(ws + 100663296);  // [S][64] f32
  float* sinT = (float*)(ws + 101187584);

  k_trig<<<512, 256, 0, stream>>>(cosT, sinT);

  dim3 gg(8, 64);  // N/128, M/128
  k_gemm_split<0><<<gg, 256, 0, stream>>>(x, Wq, 8192, 1024, 1024, qh, ql);
  k_gemm_split<0><<<gg, 256, 0, stream>>>(x, Wk, 8192, 1024, 1024, kh, kl);
  k_gemm_split<2><<<gg, 256, 0, stream>>>(x, Wv, 8192, 1024, 1024, vh, nullptr);

  k_ret_hybrid<<<dim3(32, 64), 256, 0, stream>>>(qh, ql, kh, kl, vh, cosT, sinT, lnw, lnb, Y);

  k_patch<<<64, 256, 0, stream>>>(x, Wq, Wk, Wv, cosT, sinT, lnw, lnb, Y);

  k_gemm_out<<<gg, 256, 0, stream>>>(Y, Wo, 8192, 1024, 1024, out);
}

// Round 10
// 1732.804 us; speedup vs baseline: 2.4480x; 1.6230x over previous
//
#include <hip/hip_runtime.h>

typedef unsigned short u16;
typedef _Float16 f16;
typedef _Float16 f16x8 __attribute__((ext_vector_type(8)));
typedef float f32x4 __attribute__((ext_vector_type(4)));
typedef unsigned short u16x8 __attribute__((ext_vector_type(8)));

static __device__ __forceinline__ u16 f2h(float f) {
  f16 h = (f16)f;
  return __builtin_bit_cast(u16, h);
}
static __device__ __forceinline__ float h2f(u16 h) {
  return (float)__builtin_bit_cast(f16, h);
}

static __device__ __forceinline__ f32x4 mfma16h(u16x8 a, u16x8 b, f32x4 c) {
  return __builtin_amdgcn_mfma_f32_16x16x32_f16(
      __builtin_bit_cast(f16x8, a), __builtin_bit_cast(f16x8, b), c, 0, 0, 0);
}

// ---------------- cos/sin tables [S][64], f64-accurate ----------------
__global__ void k_trig(float* __restrict__ cosT, float* __restrict__ sinT) {
  int idx = blockIdx.x * blockDim.x + threadIdx.x;  // S*64 threads
  int s = idx >> 6, j = idx & 63;
  double theta = exp2(-0.4152410118609203 * (double)j);  // 10000^(-j/32), f64
  double ang = (double)s * theta;
  cosT[idx] = (float)cos(ang);
  sinT[idx] = (float)sin(ang);
}

// ---------------- split-fp16 TN GEMM (R8-verbatim, validated) ----------------
// MODE 0: scatter split hi/lo to [BH][S][64]   MODE 2: scatter hi only to [BH][S][64]
template <int MODE>
__global__ __launch_bounds__(256) void k_gemm_split(
    const float* __restrict__ A, const float* __restrict__ Bw,
    int M, int N, int K,
    u16* __restrict__ outH, u16* __restrict__ outL) {
  constexpr int LDT = 40;
  __shared__ __align__(16) u16 Ash[128 * LDT];
  __shared__ __align__(16) u16 Asl[128 * LDT];
  __shared__ __align__(16) u16 Bsh[128 * LDT];
  __shared__ __align__(16) u16 Bsl[128 * LDT];
  const int tid = threadIdx.x;
  const int m0 = blockIdx.y * 128;
  const int n0 = blockIdx.x * 128;
  const int lane = tid & 63, lr = lane & 15, lg = lane >> 4;
  const int wid = tid >> 6;
  const int wm = (wid >> 1) * 64, wn = (wid & 1) * 64;

  const f32x4 fz = {0.f, 0.f, 0.f, 0.f};
  f32x4 acc[4][4];
#pragma unroll
  for (int i = 0; i < 4; i++)
#pragma unroll
    for (int j = 0; j < 4; j++) acc[i][j] = fz;

  for (int k0 = 0; k0 < K; k0 += 32) {
    __syncthreads();
#pragma unroll
    for (int p = 0; p < 4; p++) {
      int c = p * 256 + tid;
      int row = c >> 3, col = (c & 7) * 4;
      float4 av = *reinterpret_cast<const float4*>(&A[(size_t)(m0 + row) * K + k0 + col]);
      float4 bv = *reinterpret_cast<const float4*>(&Bw[(size_t)(n0 + row) * K + k0 + col]);
      const float* ap = reinterpret_cast<const float*>(&av);
      const float* bp = reinterpret_cast<const float*>(&bv);
#pragma unroll
      for (int e = 0; e < 4; e++) {
        u16 h = f2h(ap[e]);
        Ash[row * LDT + col + e] = h;
        Asl[row * LDT + col + e] = f2h(ap[e] - h2f(h));
        h = f2h(bp[e]);
        Bsh[row * LDT + col + e] = h;
        Bsl[row * LDT + col + e] = f2h(bp[e] - h2f(h));
      }
    }
    __syncthreads();
    u16x8 ah[4], al[4], bh[4], bl[4];
#pragma unroll
    for (int i = 0; i < 4; i++) {
      ah[i] = *reinterpret_cast<const u16x8*>(&Ash[(wm + i * 16 + lr) * LDT + 8 * lg]);
      al[i] = *reinterpret_cast<const u16x8*>(&Asl[(wm + i * 16 + lr) * LDT + 8 * lg]);
    }
#pragma unroll
    for (int j = 0; j < 4; j++) {
      bh[j] = *reinterpret_cast<const u16x8*>(&Bsh[(wn + j * 16 + lr) * LDT + 8 * lg]);
      bl[j] = *reinterpret_cast<const u16x8*>(&Bsl[(wn + j * 16 + lr) * LDT + 8 * lg]);
    }
#pragma unroll
    for (int i = 0; i < 4; i++)
#pragma unroll
      for (int j = 0; j < 4; j++) {
        acc[i][j] = mfma16h(ah[i], bh[j], acc[i][j]);
        acc[i][j] = mfma16h(ah[i], bl[j], acc[i][j]);
        acc[i][j] = mfma16h(al[i], bh[j], acc[i][j]);
      }
  }

#pragma unroll
  for (int i = 0; i < 4; i++)
#pragma unroll
    for (int j = 0; j < 4; j++)
#pragma unroll
      for (int r = 0; r < 4; r++) {
        int m = m0 + wm + i * 16 + 4 * lg + r;
        int n = n0 + wn + j * 16 + lr;
        float v = acc[i][j][r];
        int b = m >> 11, s = m & 2047;  // S = 2048
        int h = n >> 6, jj = n & 63;
        size_t o = (((size_t)(b * 16 + h)) * 2048 + s) * 64 + jj;
        if constexpr (MODE == 2) {
          outH[o] = f2h(v);
        } else {
          u16 hh = f2h(v);
          outH[o] = hh;
          outL[o] = f2h(v - h2f(hh));
        }
      }
}

// ---------------- single-pass fp16 GEMM for out = Y @ Wo^T (validated) ----------------
__global__ __launch_bounds__(256) void k_gemm_out(
    const u16* __restrict__ A, const float* __restrict__ Bw,
    int M, int N, int K, float* __restrict__ outF) {
  constexpr int LDT = 40;
  __shared__ __align__(16) u16 As[128 * LDT];
  __shared__ __align__(16) u16 Bs[128 * LDT];
  const int tid = threadIdx.x;
  const int m0 = blockIdx.y * 128;
  const int n0 = blockIdx.x * 128;
  const int lane = tid & 63, lr = lane & 15, lg = lane >> 4;
  const int wid = tid >> 6;
  const int wm = (wid >> 1) * 64, wn = (wid & 1) * 64;

  const f32x4 fz = {0.f, 0.f, 0.f, 0.f};
  f32x4 acc[4][4];
#pragma unroll
  for (int i = 0; i < 4; i++)
#pragma unroll
    for (int j = 0; j < 4; j++) acc[i][j] = fz;

  for (int k0 = 0; k0 < K; k0 += 32) {
    __syncthreads();
#pragma unroll
    for (int p = 0; p < 2; p++) {
      int c = p * 256 + tid;
      int row = c >> 2, col = (c & 3) * 8;
      *reinterpret_cast<int4*>(&As[row * LDT + col]) =
          *reinterpret_cast<const int4*>(&A[(size_t)(m0 + row) * K + k0 + col]);
    }
#pragma unroll
    for (int p = 0; p < 4; p++) {
      int c = p * 256 + tid;
      int row = c >> 3, col = (c & 7) * 4;
      float4 bv = *reinterpret_cast<const float4*>(&Bw[(size_t)(n0 + row) * K + k0 + col]);
      const float* bp = reinterpret_cast<const float*>(&bv);
#pragma unroll
      for (int e = 0; e < 4; e++) Bs[row * LDT + col + e] = f2h(bp[e]);
    }
    __syncthreads();
    u16x8 af[4], bf[4];
#pragma unroll
    for (int i = 0; i < 4; i++)
      af[i] = *reinterpret_cast<const u16x8*>(&As[(wm + i * 16 + lr) * LDT + 8 * lg]);
#pragma unroll
    for (int j = 0; j < 4; j++)
      bf[j] = *reinterpret_cast<const u16x8*>(&Bs[(wn + j * 16 + lr) * LDT + 8 * lg]);
#pragma unroll
    for (int i = 0; i < 4; i++)
#pragma unroll
      for (int j = 0; j < 4; j++) acc[i][j] = mfma16h(af[i], bf[j], acc[i][j]);
  }

#pragma unroll
  for (int i = 0; i < 4; i++)
#pragma unroll
    for (int j = 0; j < 4; j++)
#pragma unroll
      for (int r = 0; r < 4; r++) {
        int m = m0 + wm + i * 16 + 4 * lg + r;
        int n = n0 + wn + j * 16 + lr;
        outF[(size_t)m * N + n] = acc[i][j][r];
      }
}

// ---------------- retention: MFMA QK^T + MFMA PV (row-major V, LDS epilogue) ----------------
constexpr int LDK = 136;   // u16 stride, rotated Q'/K' tile [64][128]
constexpr int LDP = 76;    // f32 stride, P tile [64 q][64 t]
constexpr int LDVS = 74;   // u16 stride, V tile row-major [64 t][64 j] (banks: 8lg+5e+8jn+(lr>>1))
constexpr int LDR = 65;    // f32 stride, O tile [64 q][64 j]

// stage 64 rows of rotated head-vectors (sum of split hi/lo source) into LDS fp16
static __device__ __forceinline__ void stage_rot_sum(
    const u16* __restrict__ hsrc, const u16* __restrict__ lsrc,
    const float* __restrict__ cosT, const float* __restrict__ sinT,
    int bh, int r0, int tid, u16* Ks) {
#pragma unroll
  for (int p = 0; p < 2; p++) {
    int c = p * 256 + tid;  // [0,512): 64 rows x 8 chunks of 8 dims
    int row = c >> 3, d0 = (c & 7) * 8;
    int sg = r0 + row;
    size_t gb = ((size_t)bh * 2048 + sg) * 64 + d0;
    u16x8 h8 = *reinterpret_cast<const u16x8*>(&hsrc[gb]);
    u16x8 l8 = *reinterpret_cast<const u16x8*>(&lsrc[gb]);
#pragma unroll
    for (int e = 0; e < 8; e++) {
      int d = d0 + e;
      float v = h2f(h8[e]) + h2f(l8[e]);
      float cv = cosT[sg * 64 + d], sv = sinT[sg * 64 + d];
      Ks[row * LDK + d] = f2h(v * cv);
      Ks[row * LDK + 64 + d] = f2h(v * sv);
    }
  }
}

__global__ __launch_bounds__(256) void k_retention(
    const u16* __restrict__ qh_, const u16* __restrict__ ql_,
    const u16* __restrict__ kh_, const u16* __restrict__ kl_,
    const u16* __restrict__ vh_,
    const float* __restrict__ cosT, const float* __restrict__ sinT,
    const float* __restrict__ lnw, const float* __restrict__ lnb,
    u16* __restrict__ Y) {
  // LDS: Ks 17408 | Vs 9472 | Ps 19456 (Rs 16640 overlays Ps) | stats 512
  __shared__ __align__(16) char SM[17408 + 9472 + 19456];
  u16*   Ks = (u16*)SM;
  u16*   Vs = (u16*)(SM + 17408);
  float* Ps = (float*)(SM + 17408 + 9472);
  float* Rs = (float*)(SM + 17408 + 9472);  // overlays Ps after kt loop
  __shared__ float mus[64], rstds[64];

  const int tid = threadIdx.x;
  const int bh = blockIdx.y, b = bh >> 4, h = bh & 15;
  const int qt = (int)gridDim.x - 1 - (int)blockIdx.x;  // heavy tiles first
  const int qbase = qt * 64;
  const int wid = tid >> 6, lane = tid & 63, lr = lane & 15, lg = lane >> 4;
  const int qg = qbase + wid * 16;  // this wave's first q row
  const float lg2g = log2f(1.0f - exp2f(-5.0f - (float)h));

  // ---- prologue: stage rotated Q' via Ks, read A-fragments (validated pattern) ----
  stage_rot_sum(qh_, ql_, cosT, sinT, bh, qbase, tid, Ks);
  __syncthreads();
  u16x8 qa[4];
#pragma unroll
  for (int dc = 0; dc < 4; dc++)
    qa[dc] = *reinterpret_cast<const u16x8*>(&Ks[(wid * 16 + lr) * LDK + dc * 32 + 8 * lg]);

  const f32x4 fz = {0.f, 0.f, 0.f, 0.f};
  f32x4 oacc[4];
#pragma unroll
  for (int j = 0; j < 4; j++) oacc[j] = fz;

  for (int kt = 0; kt <= qt; ++kt) {
    const int t0 = kt * 64;
    const bool active = (t0 <= qg + 15);  // wave-uniform
    __syncthreads();  // prior tile's reads done (and prologue frag reads)
    stage_rot_sum(kh_, kl_, cosT, sinT, bh, t0, tid, Ks);
    // stage V row-major [t][j] from validated vh layout (contiguous source reads)
#pragma unroll
    for (int p = 0; p < 2; p++) {
      int c = p * 256 + tid;
      int tl = c >> 3, j0 = (c & 7) * 8;
      u16x8 v8 = *reinterpret_cast<const u16x8*>(&vh_[((size_t)bh * 2048 + t0 + tl) * 64 + j0]);
#pragma unroll
      for (int e = 0; e < 8; e++) Vs[tl * LDVS + j0 + e] = v8[e];
    }
    __syncthreads();

    // ---- QK^T (validated cluster): D rows = q (4*lg+i), cols = t (lr) ----
    if (active) {
#pragma unroll
      for (int tn = 0; tn < 4; tn++) {
        f32x4 st = fz;
#pragma unroll
        for (int dc = 0; dc < 4; dc++) {
          u16x8 kb = *reinterpret_cast<const u16x8*>(&Ks[(tn * 16 + lr) * LDK + dc * 32 + 8 * lg]);
          st = mfma16h(qa[dc], kb, st);
        }
        const int t = t0 + tn * 16 + lr;
#pragma unroll
        for (int i = 0; i < 4; i++) {
          int q = qg + 4 * lg + i;
          float v = st[i];
          v = (t <= q) ? v * exp2f((float)(q - t) * lg2g) : 0.f;
          Ps[(wid * 16 + 4 * lg + i) * LDP + tn * 16 + lr] = v;
        }
      }
    }
    __syncthreads();  // fence between P-writes and P fragment reads

    // ---- PV MFMA: A = P (GEMM af pattern from Ps), B = V row-major scalar reads ----
    if (active) {
#pragma unroll
      for (int c2 = 0; c2 < 2; c2++) {
        const float* pr = &Ps[(wid * 16 + lr) * LDP + c2 * 32 + 8 * lg];
        float4 p0 = *reinterpret_cast<const float4*>(pr);
        float4 p1 = *reinterpret_cast<const float4*>(pr + 4);
        const float* f0 = reinterpret_cast<const float*>(&p0);
        const float* f1 = reinterpret_cast<const float*>(&p1);
        u16x8 pa;
#pragma unroll
        for (int e = 0; e < 4; e++) {
          pa[e] = f2h(f0[e]);
          pa[e + 4] = f2h(f1[e]);
        }
#pragma unroll
        for (int jn = 0; jn < 4; jn++) {
          u16x8 vb;
#pragma unroll
          for (int e = 0; e < 8; e++)
            vb[e] = Vs[(c2 * 32 + 8 * lg + e) * LDVS + jn * 16 + lr];
          oacc[jn] = mfma16h(pa, vb, oacc[jn]);
        }
      }
    }
  }

  // ---- epilogue via LDS roundtrip: oacc -> Rs (validated D-write pattern) ----
  __syncthreads();  // all Ps reads done before overlaying Rs
#pragma unroll
  for (int jn = 0; jn < 4; jn++)
#pragma unroll
    for (int i = 0; i < 4; i++)
      Rs[(wid * 16 + 4 * lg + i) * LDR + jn * 16 + lr] = oacc[jn][i];
  __syncthreads();
  // row stats (R6-validated style): one thread per q row
  if (tid < 64) {
    float s1 = 0.f, s2 = 0.f;
    for (int j = 0; j < 64; j++) { float v = Rs[tid * LDR + j]; s1 += v; s2 += v * v; }
    float mu = s1 * (1.f / 64.f);
    float var = s2 * (1.f / 64.f) - mu * mu;
    mus[tid] = mu; rstds[tid] = rsqrtf(var + 1e-5f);
  }
  __syncthreads();
  for (int p = tid; p < 4096; p += 256) {
    int sl = p >> 6, j = p & 63;
    float y = (Rs[sl * LDR + j] - mus[sl]) * rstds[sl] * lnw[j] + lnb[j];
    y = y / (1.f + expf(-y));
    Y[((size_t)b * 2048 + qbase + sl) * 1024 + h * 64 + j] = f2h(y);
  }
}

// ---------------- f64-exact patch for rows s < SP (validated) ----------------
#define SP 32
__global__ __launch_bounds__(256) void k_patch(
    const float* __restrict__ x, const float* __restrict__ Wq,
    const float* __restrict__ Wk, const float* __restrict__ Wv,
    const float* __restrict__ cosT, const float* __restrict__ sinT,
    const float* __restrict__ lnw, const float* __restrict__ lnb,
    u16* __restrict__ Y) {
  const int bh = blockIdx.x, b = bh >> 4, h = bh & 15;
  __shared__ float qs[SP][128], ks[SP][128], vs[SP][64];
  __shared__ float ps[SP][SP];
  __shared__ double rs[SP][64];
  __shared__ double mus[SP], rstds[SP];
  const int tid = threadIdx.x;
  const int grp = tid >> 4, gl = tid & 15;
  const double lg2g = log2(1.0 - exp2(-5.0 - (double)h));

  for (int dd = grp; dd < 3 * SP * 64; dd += 16) {
    int type = dd / (SP * 64);
    int idx = dd % (SP * 64);
    int s = idx >> 6, hd = idx & 63;
    const float* wrow = (type == 0 ? Wq : type == 1 ? Wk : Wv) + (size_t)(h * 64 + hd) * 1024;
    const float* xrow = x + ((size_t)b * 2048 + s) * 1024;
    double acc = 0.0;
    for (int k = gl * 4; k < 1024; k += 64) {
      float4 xv = *reinterpret_cast<const float4*>(xrow + k);
      float4 wv = *reinterpret_cast<const float4*>(wrow + k);
      acc += (double)xv.x * wv.x + (double)xv.y * wv.y + (double)xv.z * wv.z + (double)xv.w * wv.w;
    }
#pragma unroll
    for (int m = 1; m < 16; m <<= 1) acc += __shfl_xor(acc, m, 64);
    if (gl == 0) {
      float accf = (float)acc;
      if (type == 2) {
        vs[s][hd] = accf;
      } else {
        float cv = cosT[s * 64 + hd], sv = sinT[s * 64 + hd];
        if (type == 0) { qs[s][hd] = accf * cv; qs[s][64 + hd] = accf * sv; }
        else           { ks[s][hd] = accf * cv; ks[s][64 + hd] = accf * sv; }
      }
    }
  }
  __syncthreads();
  for (int p = tid; p < SP * SP; p += 256) {
    int s = p / SP, t = p % SP;
    double sc = 0.0;
    if (t <= s) {
      for (int d = 0; d < 128; d++) sc += (double)qs[s][d] * ks[t][d];
      sc *= exp2((double)(s - t) * lg2g);
    }
    ps[s][t] = (float)sc;
  }
  __syncthreads();
  for (int p = tid; p < SP * 64; p += 256) {
    int s = p >> 6, j = p & 63;
    double r = 0.0;
    for (int t = 0; t <= s && t < SP; t++) r += (double)ps[s][t] * vs[t][j];
    rs[s][j] = r;
  }
  __syncthreads();
  if (tid < SP) {
    double s1 = 0.0, s2 = 0.0;
    for (int j = 0; j < 64; j++) { double v = rs[tid][j]; s1 += v; s2 += v * v; }
    double mu = s1 * (1.0 / 64.0);
    double var = s2 * (1.0 / 64.0) - mu * mu;
    mus[tid] = mu; rstds[tid] = 1.0 / sqrt(var + 1e-5);
  }
  __syncthreads();
  for (int p = tid; p < SP * 64; p += 256) {
    int s = p >> 6, j = p & 63;
    double y = (rs[s][j] - mus[s]) * rstds[s] * (double)lnw[j] + (double)lnb[j];
    y = y / (1.0 + exp(-y));
    Y[((size_t)b * 2048 + s) * 1024 + h * 64 + j] = f2h((float)y);
  }
}

extern "C" void kernel_launch(void* const* d_in, const int* in_sizes, int n_in,
                              void* d_out, int out_size, void* d_ws, size_t ws_size,
                              hipStream_t stream) {
  const float* x   = (const float*)d_in[0];
  const float* Wq  = (const float*)d_in[1];
  const float* Wk  = (const float*)d_in[2];
  const float* Wv  = (const float*)d_in[3];
  const float* Wo  = (const float*)d_in[4];
  const float* lnw = (const float*)d_in[5];
  const float* lnb = (const float*)d_in[6];
  float* out = (float*)d_out;

  char* ws = (char*)d_ws;
  u16*   qh   = (u16*)(ws + 0);            // [BH][S][64]
  u16*   ql   = (u16*)(ws + 16777216);
  u16*   kh   = (u16*)(ws + 33554432);
  u16*   kl   = (u16*)(ws + 50331648);
  u16*   vh   = (u16*)(ws + 67108864);     // [BH][S][64] fp16
  u16*   Y    = (u16*)(ws + 83886080);     // [B*S][D] fp16
  float* cosT = (float*)(ws + 100663296);  // [S][64] f32
  float* sinT = (float*)(ws + 101187584);

  k_trig<<<512, 256, 0, stream>>>(cosT, sinT);

  dim3 gg(8, 64);  // N/128, M/128
  k_gemm_split<0><<<gg, 256, 0, stream>>>(x, Wq, 8192, 1024, 1024, qh, ql);
  k_gemm_split<0><<<gg, 256, 0, stream>>>(x, Wk, 8192, 1024, 1024, kh, kl);
  k_gemm_split<2><<<gg, 256, 0, stream>>>(x, Wv, 8192, 1024, 1024, vh, nullptr);

  k_retention<<<dim3(32, 64), 256, 0, stream>>>(qh, ql, kh, kl, vh, cosT, sinT, lnw, lnb, Y);

  k_patch<<<64, 256, 0, stream>>>(x, Wq, Wk, Wv, cosT, sinT, lnw, lnb, Y);

  k_gemm_out<<<gg, 256, 0, stream>>>(Y, Wo, 8192, 1024, 1024, out);
}

// Round 11
// 564.167 us; speedup vs baseline: 7.5189x; 3.0714x over previous
//
#include <hip/hip_runtime.h>

typedef unsigned short u16;
typedef _Float16 f16;
typedef _Float16 f16x8 __attribute__((ext_vector_type(8)));
typedef float f32x4 __attribute__((ext_vector_type(4)));
typedef unsigned short u16x8 __attribute__((ext_vector_type(8)));

static __device__ __forceinline__ u16 f2h(float f) {
  f16 h = (f16)f;
  return __builtin_bit_cast(u16, h);
}
static __device__ __forceinline__ float h2f(u16 h) {
  return (float)__builtin_bit_cast(f16, h);
}

static __device__ __forceinline__ f32x4 mfma16h(u16x8 a, u16x8 b, f32x4 c) {
  return __builtin_amdgcn_mfma_f32_16x16x32_f16(
      __builtin_bit_cast(f16x8, a), __builtin_bit_cast(f16x8, b), c, 0, 0, 0);
}

// ---------------- cos/sin tables [S][64], f64-accurate ----------------
__global__ void k_trig(float* __restrict__ cosT, float* __restrict__ sinT) {
  int idx = blockIdx.x * blockDim.x + threadIdx.x;  // S*64 threads
  int s = idx >> 6, j = idx & 63;
  double theta = exp2(-0.4152410118609203 * (double)j);  // 10000^(-j/32), f64
  double ang = (double)s * theta;
  cosT[idx] = (float)cos(ang);
  sinT[idx] = (float)sin(ang);
}

// ---------------- split-fp16 TN GEMM (validated structure) ----------------
// MODE 0: 3-pass Dekker, scatter split hi/lo to [BH][S][64]
// MODE 2: single-pass, scatter hi only to [BH][S][64]
template <int MODE>
__global__ __launch_bounds__(256) void k_gemm_split(
    const float* __restrict__ A, const float* __restrict__ Bw,
    int M, int N, int K,
    u16* __restrict__ outH, u16* __restrict__ outL) {
  constexpr int LDT = 40;
  __shared__ __align__(16) u16 Ash[128 * LDT];
  __shared__ __align__(16) u16 Asl[128 * LDT];
  __shared__ __align__(16) u16 Bsh[128 * LDT];
  __shared__ __align__(16) u16 Bsl[128 * LDT];
  const int tid = threadIdx.x;
  const int m0 = blockIdx.y * 128;
  const int n0 = blockIdx.x * 128;
  const int lane = tid & 63, lr = lane & 15, lg = lane >> 4;
  const int wid = tid >> 6;
  const int wm = (wid >> 1) * 64, wn = (wid & 1) * 64;

  const f32x4 fz = {0.f, 0.f, 0.f, 0.f};
  f32x4 acc[4][4];
#pragma unroll
  for (int i = 0; i < 4; i++)
#pragma unroll
    for (int j = 0; j < 4; j++) acc[i][j] = fz;

  for (int k0 = 0; k0 < K; k0 += 32) {
    __syncthreads();
#pragma unroll
    for (int p = 0; p < 4; p++) {
      int c = p * 256 + tid;
      int row = c >> 3, col = (c & 7) * 4;
      float4 av = *reinterpret_cast<const float4*>(&A[(size_t)(m0 + row) * K + k0 + col]);
      float4 bv = *reinterpret_cast<const float4*>(&Bw[(size_t)(n0 + row) * K + k0 + col]);
      const float* ap = reinterpret_cast<const float*>(&av);
      const float* bp = reinterpret_cast<const float*>(&bv);
#pragma unroll
      for (int e = 0; e < 4; e++) {
        u16 h = f2h(ap[e]);
        Ash[row * LDT + col + e] = h;
        if constexpr (MODE == 0) Asl[row * LDT + col + e] = f2h(ap[e] - h2f(h));
        u16 hb = f2h(bp[e]);
        Bsh[row * LDT + col + e] = hb;
        if constexpr (MODE == 0) Bsl[row * LDT + col + e] = f2h(bp[e] - h2f(hb));
      }
    }
    __syncthreads();
    u16x8 ah[4], al[4], bh[4], bl[4];
#pragma unroll
    for (int i = 0; i < 4; i++) {
      ah[i] = *reinterpret_cast<const u16x8*>(&Ash[(wm + i * 16 + lr) * LDT + 8 * lg]);
      if constexpr (MODE == 0)
        al[i] = *reinterpret_cast<const u16x8*>(&Asl[(wm + i * 16 + lr) * LDT + 8 * lg]);
    }
#pragma unroll
    for (int j = 0; j < 4; j++) {
      bh[j] = *reinterpret_cast<const u16x8*>(&Bsh[(wn + j * 16 + lr) * LDT + 8 * lg]);
      if constexpr (MODE == 0)
        bl[j] = *reinterpret_cast<const u16x8*>(&Bsl[(wn + j * 16 + lr) * LDT + 8 * lg]);
    }
#pragma unroll
    for (int i = 0; i < 4; i++)
#pragma unroll
      for (int j = 0; j < 4; j++) {
        acc[i][j] = mfma16h(ah[i], bh[j], acc[i][j]);
        if constexpr (MODE == 0) {
          acc[i][j] = mfma16h(ah[i], bl[j], acc[i][j]);
          acc[i][j] = mfma16h(al[i], bh[j], acc[i][j]);
        }
      }
  }

#pragma unroll
  for (int i = 0; i < 4; i++)
#pragma unroll
    for (int j = 0; j < 4; j++)
#pragma unroll
      for (int r = 0; r < 4; r++) {
        int m = m0 + wm + i * 16 + 4 * lg + r;
        int n = n0 + wn + j * 16 + lr;
        float v = acc[i][j][r];
        int b = m >> 11, s = m & 2047;  // S = 2048
        int h = n >> 6, jj = n & 63;
        size_t o = (((size_t)(b * 16 + h)) * 2048 + s) * 64 + jj;
        if constexpr (MODE == 2) {
          outH[o] = f2h(v);
        } else {
          u16 hh = f2h(v);
          outH[o] = hh;
          outL[o] = f2h(v - h2f(hh));
        }
      }
}

// ---------------- single-pass fp16 GEMM for out = Y @ Wo^T (validated) ----------------
__global__ __launch_bounds__(256) void k_gemm_out(
    const u16* __restrict__ A, const float* __restrict__ Bw,
    int M, int N, int K, float* __restrict__ outF) {
  constexpr int LDT = 40;
  __shared__ __align__(16) u16 As[128 * LDT];
  __shared__ __align__(16) u16 Bs[128 * LDT];
  const int tid = threadIdx.x;
  const int m0 = blockIdx.y * 128;
  const int n0 = blockIdx.x * 128;
  const int lane = tid & 63, lr = lane & 15, lg = lane >> 4;
  const int wid = tid >> 6;
  const int wm = (wid >> 1) * 64, wn = (wid & 1) * 64;

  const f32x4 fz = {0.f, 0.f, 0.f, 0.f};
  f32x4 acc[4][4];
#pragma unroll
  for (int i = 0; i < 4; i++)
#pragma unroll
    for (int j = 0; j < 4; j++) acc[i][j] = fz;

  for (int k0 = 0; k0 < K; k0 += 32) {
    __syncthreads();
#pragma unroll
    for (int p = 0; p < 2; p++) {
      int c = p * 256 + tid;
      int row = c >> 2, col = (c & 3) * 8;
      *reinterpret_cast<int4*>(&As[row * LDT + col]) =
          *reinterpret_cast<const int4*>(&A[(size_t)(m0 + row) * K + k0 + col]);
    }
#pragma unroll
    for (int p = 0; p < 4; p++) {
      int c = p * 256 + tid;
      int row = c >> 3, col = (c & 7) * 4;
      float4 bv = *reinterpret_cast<const float4*>(&Bw[(size_t)(n0 + row) * K + k0 + col]);
      const float* bp = reinterpret_cast<const float*>(&bv);
#pragma unroll
      for (int e = 0; e < 4; e++) Bs[row * LDT + col + e] = f2h(bp[e]);
    }
    __syncthreads();
    u16x8 af[4], bf[4];
#pragma unroll
    for (int i = 0; i < 4; i++)
      af[i] = *reinterpret_cast<const u16x8*>(&As[(wm + i * 16 + lr) * LDT + 8 * lg]);
#pragma unroll
    for (int j = 0; j < 4; j++)
      bf[j] = *reinterpret_cast<const u16x8*>(&Bs[(wn + j * 16 + lr) * LDT + 8 * lg]);
#pragma unroll
    for (int i = 0; i < 4; i++)
#pragma unroll
      for (int j = 0; j < 4; j++) acc[i][j] = mfma16h(af[i], bf[j], acc[i][j]);
  }

#pragma unroll
  for (int i = 0; i < 4; i++)
#pragma unroll
    for (int j = 0; j < 4; j++)
#pragma unroll
      for (int r = 0; r < 4; r++) {
        int m = m0 + wm + i * 16 + 4 * lg + r;
        int n = n0 + wn + j * 16 + lr;
        outF[(size_t)m * N + n] = acc[i][j][r];
      }
}

// ---------------- retention (R10-verbatim, validated) ----------------
constexpr int LDK = 136;   // u16 stride, rotated Q'/K' tile [64][128]
constexpr int LDP = 76;    // f32 stride, P tile [64 q][64 t]
constexpr int LDVS = 74;   // u16 stride, V tile row-major [64 t][64 j]
constexpr int LDR = 65;    // f32 stride, O tile [64 q][64 j]

static __device__ __forceinline__ void stage_rot_sum(
    const u16* __restrict__ hsrc, const u16* __restrict__ lsrc,
    const float* __restrict__ cosT, const float* __restrict__ sinT,
    int bh, int r0, int tid, u16* Ks) {
#pragma unroll
  for (int p = 0; p < 2; p++) {
    int c = p * 256 + tid;  // [0,512): 64 rows x 8 chunks of 8 dims
    int row = c >> 3, d0 = (c & 7) * 8;
    int sg = r0 + row;
    size_t gb = ((size_t)bh * 2048 + sg) * 64 + d0;
    u16x8 h8 = *reinterpret_cast<const u16x8*>(&hsrc[gb]);
    u16x8 l8 = *reinterpret_cast<const u16x8*>(&lsrc[gb]);
#pragma unroll
    for (int e = 0; e < 8; e++) {
      int d = d0 + e;
      float v = h2f(h8[e]) + h2f(l8[e]);
      float cv = cosT[sg * 64 + d], sv = sinT[sg * 64 + d];
      Ks[row * LDK + d] = f2h(v * cv);
      Ks[row * LDK + 64 + d] = f2h(v * sv);
    }
  }
}

__global__ __launch_bounds__(256) void k_retention(
    const u16* __restrict__ qh_, const u16* __restrict__ ql_,
    const u16* __restrict__ kh_, const u16* __restrict__ kl_,
    const u16* __restrict__ vh_,
    const float* __restrict__ cosT, const float* __restrict__ sinT,
    const float* __restrict__ lnw, const float* __restrict__ lnb,
    u16* __restrict__ Y) {
  __shared__ __align__(16) char SM[17408 + 9472 + 19456];
  u16*   Ks = (u16*)SM;
  u16*   Vs = (u16*)(SM + 17408);
  float* Ps = (float*)(SM + 17408 + 9472);
  float* Rs = (float*)(SM + 17408 + 9472);  // overlays Ps after kt loop
  __shared__ float mus[64], rstds[64];

  const int tid = threadIdx.x;
  const int bh = blockIdx.y, b = bh >> 4, h = bh & 15;
  const int qt = (int)gridDim.x - 1 - (int)blockIdx.x;  // heavy tiles first
  const int qbase = qt * 64;
  const int wid = tid >> 6, lane = tid & 63, lr = lane & 15, lg = lane >> 4;
  const int qg = qbase + wid * 16;
  const float lg2g = log2f(1.0f - exp2f(-5.0f - (float)h));

  stage_rot_sum(qh_, ql_, cosT, sinT, bh, qbase, tid, Ks);
  __syncthreads();
  u16x8 qa[4];
#pragma unroll
  for (int dc = 0; dc < 4; dc++)
    qa[dc] = *reinterpret_cast<const u16x8*>(&Ks[(wid * 16 + lr) * LDK + dc * 32 + 8 * lg]);

  const f32x4 fz = {0.f, 0.f, 0.f, 0.f};
  f32x4 oacc[4];
#pragma unroll
  for (int j = 0; j < 4; j++) oacc[j] = fz;

  for (int kt = 0; kt <= qt; ++kt) {
    const int t0 = kt * 64;
    const bool active = (t0 <= qg + 15);
    __syncthreads();
    stage_rot_sum(kh_, kl_, cosT, sinT, bh, t0, tid, Ks);
#pragma unroll
    for (int p = 0; p < 2; p++) {
      int c = p * 256 + tid;
      int tl = c >> 3, j0 = (c & 7) * 8;
      u16x8 v8 = *reinterpret_cast<const u16x8*>(&vh_[((size_t)bh * 2048 + t0 + tl) * 64 + j0]);
#pragma unroll
      for (int e = 0; e < 8; e++) Vs[tl * LDVS + j0 + e] = v8[e];
    }
    __syncthreads();

    if (active) {
#pragma unroll
      for (int tn = 0; tn < 4; tn++) {
        f32x4 st = fz;
#pragma unroll
        for (int dc = 0; dc < 4; dc++) {
          u16x8 kb = *reinterpret_cast<const u16x8*>(&Ks[(tn * 16 + lr) * LDK + dc * 32 + 8 * lg]);
          st = mfma16h(qa[dc], kb, st);
        }
        const int t = t0 + tn * 16 + lr;
#pragma unroll
        for (int i = 0; i < 4; i++) {
          int q = qg + 4 * lg + i;
          float v = st[i];
          v = (t <= q) ? v * exp2f((float)(q - t) * lg2g) : 0.f;
          Ps[(wid * 16 + 4 * lg + i) * LDP + tn * 16 + lr] = v;
        }
      }
    }
    __syncthreads();

    if (active) {
#pragma unroll
      for (int c2 = 0; c2 < 2; c2++) {
        const float* pr = &Ps[(wid * 16 + lr) * LDP + c2 * 32 + 8 * lg];
        float4 p0 = *reinterpret_cast<const float4*>(pr);
        float4 p1 = *reinterpret_cast<const float4*>(pr + 4);
        const float* f0 = reinterpret_cast<const float*>(&p0);
        const float* f1 = reinterpret_cast<const float*>(&p1);
        u16x8 pa;
#pragma unroll
        for (int e = 0; e < 4; e++) {
          pa[e] = f2h(f0[e]);
          pa[e + 4] = f2h(f1[e]);
        }
#pragma unroll
        for (int jn = 0; jn < 4; jn++) {
          u16x8 vb;
#pragma unroll
          for (int e = 0; e < 8; e++)
            vb[e] = Vs[(c2 * 32 + 8 * lg + e) * LDVS + jn * 16 + lr];
          oacc[jn] = mfma16h(pa, vb, oacc[jn]);
        }
      }
    }
  }

  __syncthreads();
#pragma unroll
  for (int jn = 0; jn < 4; jn++)
#pragma unroll
    for (int i = 0; i < 4; i++)
      Rs[(wid * 16 + 4 * lg + i) * LDR + jn * 16 + lr] = oacc[jn][i];
  __syncthreads();
  if (tid < 64) {
    float s1 = 0.f, s2 = 0.f;
    for (int j = 0; j < 64; j++) { float v = Rs[tid * LDR + j]; s1 += v; s2 += v * v; }
    float mu = s1 * (1.f / 64.f);
    float var = s2 * (1.f / 64.f) - mu * mu;
    mus[tid] = mu; rstds[tid] = rsqrtf(var + 1e-5f);
  }
  __syncthreads();
  for (int p = tid; p < 4096; p += 256) {
    int sl = p >> 6, j = p & 63;
    float y = (Rs[sl * LDR + j] - mus[sl]) * rstds[sl] * lnw[j] + lnb[j];
    y = y / (1.f + expf(-y));
    Y[((size_t)b * 2048 + qbase + sl) * 1024 + h * 64 + j] = f2h(y);
  }
}

// ---------------- f32 patch for rows s < SP, sourced from ws q/k/v ----------------
#define SP 32
__global__ __launch_bounds__(256) void k_patch(
    const u16* __restrict__ qh_, const u16* __restrict__ ql_,
    const u16* __restrict__ kh_, const u16* __restrict__ kl_,
    const u16* __restrict__ vh_,
    const float* __restrict__ cosT, const float* __restrict__ sinT,
    const float* __restrict__ lnw, const float* __restrict__ lnb,
    u16* __restrict__ Y) {
  const int bh = blockIdx.x, b = bh >> 4, h = bh & 15;
  __shared__ float qs[SP][132], ks[SP][132];
  __shared__ float vs[SP][64], rs[SP][64];
  __shared__ float ps[SP][SP];
  __shared__ float mus[SP], rstds[SP];
  const int tid = threadIdx.x;
  const float lg2g = log2f(1.0f - exp2f(-5.0f - (float)h));

  // phase 1: rotated q', k' (f32 from hi+lo) and v
  for (int p = tid; p < SP * 64; p += 256) {
    int s = p >> 6, d = p & 63;
    size_t o = ((size_t)bh * 2048 + s) * 64 + d;
    float qv = h2f(qh_[o]) + h2f(ql_[o]);
    float kv = h2f(kh_[o]) + h2f(kl_[o]);
    float cv = cosT[s * 64 + d], sv = sinT[s * 64 + d];
    qs[s][d] = qv * cv; qs[s][64 + d] = qv * sv;
    ks[s][d] = kv * cv; ks[s][64 + d] = kv * sv;
    vs[s][d] = h2f(vh_[o]);
  }
  __syncthreads();
  // phase 2: scores with decay (f32)
  for (int p = tid; p < SP * SP; p += 256) {
    int s = p / SP, t = p % SP;
    float sc = 0.f;
    if (t <= s) {
      for (int d = 0; d < 128; d += 4) {
        float4 q4 = *reinterpret_cast<const float4*>(&qs[s][d]);
        float4 k4 = *reinterpret_cast<const float4*>(&ks[t][d]);
        sc += q4.x * k4.x + q4.y * k4.y + q4.z * k4.z + q4.w * k4.w;
      }
      sc *= exp2f((float)(s - t) * lg2g);
    }
    ps[s][t] = sc;
  }
  __syncthreads();
  // phase 3: r = P V
  for (int p = tid; p < SP * 64; p += 256) {
    int s = p >> 6, j = p & 63;
    float r = 0.f;
    for (int t = 0; t <= s; t++) r += ps[s][t] * vs[t][j];
    rs[s][j] = r;
  }
  __syncthreads();
  // phase 4: LN stats + store
  if (tid < SP) {
    float s1 = 0.f, s2 = 0.f;
    for (int j = 0; j < 64; j++) { float v = rs[tid][j]; s1 += v; s2 += v * v; }
    float mu = s1 * (1.f / 64.f);
    float var = s2 * (1.f / 64.f) - mu * mu;
    mus[tid] = mu; rstds[tid] = rsqrtf(var + 1e-5f);
  }
  __syncthreads();
  for (int p = tid; p < SP * 64; p += 256) {
    int s = p >> 6, j = p & 63;
    float y = (rs[s][j] - mus[s]) * rstds[s] * lnw[j] + lnb[j];
    y = y / (1.f + expf(-y));
    Y[((size_t)b * 2048 + s) * 1024 + h * 64 + j] = f2h(y);
  }
}

extern "C" void kernel_launch(void* const* d_in, const int* in_sizes, int n_in,
                              void* d_out, int out_size, void* d_ws, size_t ws_size,
                              hipStream_t stream) {
  const float* x   = (const float*)d_in[0];
  const float* Wq  = (const float*)d_in[1];
  const float* Wk  = (const float*)d_in[2];
  const float* Wv  = (const float*)d_in[3];
  const float* Wo  = (const float*)d_in[4];
  const float* lnw = (const float*)d_in[5];
  const float* lnb = (const float*)d_in[6];
  float* out = (float*)d_out;

  char* ws = (char*)d_ws;
  u16*   qh   = (u16*)(ws + 0);            // [BH][S][64]
  u16*   ql   = (u16*)(ws + 16777216);
  u16*   kh   = (u16*)(ws + 33554432);
  u16*   kl   = (u16*)(ws + 50331648);
  u16*   vh   = (u16*)(ws + 67108864);     // [BH][S][64] fp16
  u16*   Y    = (u16*)(ws + 83886080);     // [B*S][D] fp16
  float* cosT = (float*)(ws + 100663296);  // [S][64] f32
  float* sinT = (float*)(ws + 101187584);

  k_trig<<<512, 256, 0, stream>>>(cosT, sinT);

  dim3 gg(8, 64);  // N/128, M/128
  k_gemm_split<0><<<gg, 256, 0, stream>>>(x, Wq, 8192, 1024, 1024, qh, ql);
  k_gemm_split<0><<<gg, 256, 0, stream>>>(x, Wk, 8192, 1024, 1024, kh, kl);
  k_gemm_split<2><<<gg, 256, 0, stream>>>(x, Wv, 8192, 1024, 1024, vh, nullptr);

  k_retention<<<dim3(32, 64), 256, 0, stream>>>(qh, ql, kh, kl, vh, cosT, sinT, lnw, lnb, Y);

  k_patch<<<64, 256, 0, stream>>>(qh, ql, kh, kl, vh, cosT, sinT, lnw, lnb, Y);

  k_gemm_out<<<gg, 256, 0, stream>>>(Y, Wo, 8192, 1024, 1024, out);
}

// Round 12
// 546.065 us; speedup vs baseline: 7.7681x; 1.0332x over previous
//
#include <hip/hip_runtime.h>

typedef unsigned short u16;
typedef _Float16 f16;
typedef _Float16 f16x8 __attribute__((ext_vector_type(8)));
typedef float f32x4 __attribute__((ext_vector_type(4)));
typedef unsigned short u16x8 __attribute__((ext_vector_type(8)));

static __device__ __forceinline__ u16 f2h(float f) {
  f16 h = (f16)f;
  return __builtin_bit_cast(u16, h);
}
static __device__ __forceinline__ float h2f(u16 h) {
  return (float)__builtin_bit_cast(f16, h);
}

static __device__ __forceinline__ f32x4 mfma16h(u16x8 a, u16x8 b, f32x4 c) {
  return __builtin_amdgcn_mfma_f32_16x16x32_f16(
      __builtin_bit_cast(f16x8, a), __builtin_bit_cast(f16x8, b), c, 0, 0, 0);
}

// ---------------- cos/sin tables [S][64], f64-accurate ----------------
__global__ void k_trig(float* __restrict__ cosT, float* __restrict__ sinT) {
  int idx = blockIdx.x * blockDim.x + threadIdx.x;  // S*64 threads
  int s = idx >> 6, j = idx & 63;
  double theta = exp2(-0.4152410118609203 * (double)j);  // 10000^(-j/32), f64
  double ang = (double)s * theta;
  cosT[idx] = (float)cos(ang);
  sinT[idx] = (float)sin(ang);
}

// ---------------- split-fp16 TN GEMM (validated structure) ----------------
// MODE 0: 3-pass Dekker; epilogue ROTATES and scatters fp16 to [BH][S][128];
//         lo-residual of rotated values stored for s<32 rows into loB [BH][32][128].
// MODE 2: single-pass; scatter hi to [BH][S][64] (V).
template <int MODE>
__global__ __launch_bounds__(256) void k_gemm_split(
    const float* __restrict__ A, const float* __restrict__ Bw,
    int M, int N, int K,
    u16* __restrict__ outH, u16* __restrict__ loB,
    const float* __restrict__ cosT, const float* __restrict__ sinT) {
  constexpr int LDT = 40;
  __shared__ __align__(16) u16 Ash[128 * LDT];
  __shared__ __align__(16) u16 Asl[128 * LDT];
  __shared__ __align__(16) u16 Bsh[128 * LDT];
  __shared__ __align__(16) u16 Bsl[128 * LDT];
  const int tid = threadIdx.x;
  const int m0 = blockIdx.y * 128;
  const int n0 = blockIdx.x * 128;
  const int lane = tid & 63, lr = lane & 15, lg = lane >> 4;
  const int wid = tid >> 6;
  const int wm = (wid >> 1) * 64, wn = (wid & 1) * 64;

  const f32x4 fz = {0.f, 0.f, 0.f, 0.f};
  f32x4 acc[4][4];
#pragma unroll
  for (int i = 0; i < 4; i++)
#pragma unroll
    for (int j = 0; j < 4; j++) acc[i][j] = fz;

  for (int k0 = 0; k0 < K; k0 += 32) {
    __syncthreads();
#pragma unroll
    for (int p = 0; p < 4; p++) {
      int c = p * 256 + tid;
      int row = c >> 3, col = (c & 7) * 4;
      float4 av = *reinterpret_cast<const float4*>(&A[(size_t)(m0 + row) * K + k0 + col]);
      float4 bv = *reinterpret_cast<const float4*>(&Bw[(size_t)(n0 + row) * K + k0 + col]);
      const float* ap = reinterpret_cast<const float*>(&av);
      const float* bp = reinterpret_cast<const float*>(&bv);
#pragma unroll
      for (int e = 0; e < 4; e++) {
        u16 h = f2h(ap[e]);
        Ash[row * LDT + col + e] = h;
        if constexpr (MODE == 0) Asl[row * LDT + col + e] = f2h(ap[e] - h2f(h));
        u16 hb = f2h(bp[e]);
        Bsh[row * LDT + col + e] = hb;
        if constexpr (MODE == 0) Bsl[row * LDT + col + e] = f2h(bp[e] - h2f(hb));
      }
    }
    __syncthreads();
    u16x8 ah[4], al[4], bh[4], bl[4];
#pragma unroll
    for (int i = 0; i < 4; i++) {
      ah[i] = *reinterpret_cast<const u16x8*>(&Ash[(wm + i * 16 + lr) * LDT + 8 * lg]);
      if constexpr (MODE == 0)
        al[i] = *reinterpret_cast<const u16x8*>(&Asl[(wm + i * 16 + lr) * LDT + 8 * lg]);
    }
#pragma unroll
    for (int j = 0; j < 4; j++) {
      bh[j] = *reinterpret_cast<const u16x8*>(&Bsh[(wn + j * 16 + lr) * LDT + 8 * lg]);
      if constexpr (MODE == 0)
        bl[j] = *reinterpret_cast<const u16x8*>(&Bsl[(wn + j * 16 + lr) * LDT + 8 * lg]);
    }
#pragma unroll
    for (int i = 0; i < 4; i++)
#pragma unroll
      for (int j = 0; j < 4; j++) {
        acc[i][j] = mfma16h(ah[i], bh[j], acc[i][j]);
        if constexpr (MODE == 0) {
          acc[i][j] = mfma16h(ah[i], bl[j], acc[i][j]);
          acc[i][j] = mfma16h(al[i], bh[j], acc[i][j]);
        }
      }
  }

#pragma unroll
  for (int i = 0; i < 4; i++)
#pragma unroll
    for (int j = 0; j < 4; j++)
#pragma unroll
      for (int r = 0; r < 4; r++) {
        int m = m0 + wm + i * 16 + 4 * lg + r;
        int n = n0 + wn + j * 16 + lr;
        float v = acc[i][j][r];
        int b = m >> 11, s = m & 2047;  // S = 2048
        int h = n >> 6, jj = n & 63;
        if constexpr (MODE == 2) {
          outH[(((size_t)(b * 16 + h)) * 2048 + s) * 64 + jj] = f2h(v);
        } else {
          // rotate: cos half at d=jj, sin half at d=64+jj
          float cv = cosT[s * 64 + jj], sv = sinT[s * 64 + jj];
          float a = v * cv, bb = v * sv;
          size_t o = (((size_t)(b * 16 + h)) * 2048 + s) * 128 + jj;
          u16 ahh = f2h(a), bhh = f2h(bb);
          outH[o] = ahh;
          outH[o + 64] = bhh;
          if (s < 32) {  // lo-residual for the f32-grade patch
            size_t ol = (((size_t)(b * 16 + h)) * 32 + s) * 128 + jj;
            loB[ol] = f2h(a - h2f(ahh));
            loB[ol + 64] = f2h(bb - h2f(bhh));
          }
        }
      }
}

// ---------------- single-pass fp16 GEMM for out = Y @ Wo^T (validated) ----------------
__global__ __launch_bounds__(256) void k_gemm_out(
    const u16* __restrict__ A, const float* __restrict__ Bw,
    int M, int N, int K, float* __restrict__ outF) {
  constexpr int LDT = 40;
  __shared__ __align__(16) u16 As[128 * LDT];
  __shared__ __align__(16) u16 Bs[128 * LDT];
  const int tid = threadIdx.x;
  const int m0 = blockIdx.y * 128;
  const int n0 = blockIdx.x * 128;
  const int lane = tid & 63, lr = lane & 15, lg = lane >> 4;
  const int wid = tid >> 6;
  const int wm = (wid >> 1) * 64, wn = (wid & 1) * 64;

  const f32x4 fz = {0.f, 0.f, 0.f, 0.f};
  f32x4 acc[4][4];
#pragma unroll
  for (int i = 0; i < 4; i++)
#pragma unroll
    for (int j = 0; j < 4; j++) acc[i][j] = fz;

  for (int k0 = 0; k0 < K; k0 += 32) {
    __syncthreads();
#pragma unroll
    for (int p = 0; p < 2; p++) {
      int c = p * 256 + tid;
      int row = c >> 2, col = (c & 3) * 8;
      *reinterpret_cast<int4*>(&As[row * LDT + col]) =
          *reinterpret_cast<const int4*>(&A[(size_t)(m0 + row) * K + k0 + col]);
    }
#pragma unroll
    for (int p = 0; p < 4; p++) {
      int c = p * 256 + tid;
      int row = c >> 3, col = (c & 7) * 4;
      float4 bv = *reinterpret_cast<const float4*>(&Bw[(size_t)(n0 + row) * K + k0 + col]);
      const float* bp = reinterpret_cast<const float*>(&bv);
#pragma unroll
      for (int e = 0; e < 4; e++) Bs[row * LDT + col + e] = f2h(bp[e]);
    }
    __syncthreads();
    u16x8 af[4], bf[4];
#pragma unroll
    for (int i = 0; i < 4; i++)
      af[i] = *reinterpret_cast<const u16x8*>(&As[(wm + i * 16 + lr) * LDT + 8 * lg]);
#pragma unroll
    for (int j = 0; j < 4; j++)
      bf[j] = *reinterpret_cast<const u16x8*>(&Bs[(wn + j * 16 + lr) * LDT + 8 * lg]);
#pragma unroll
    for (int i = 0; i < 4; i++)
#pragma unroll
      for (int j = 0; j < 4; j++) acc[i][j] = mfma16h(af[i], bf[j], acc[i][j]);
  }

#pragma unroll
  for (int i = 0; i < 4; i++)
#pragma unroll
    for (int j = 0; j < 4; j++)
#pragma unroll
      for (int r = 0; r < 4; r++) {
        int m = m0 + wm + i * 16 + 4 * lg + r;
        int n = n0 + wn + j * 16 + lr;
        outF[(size_t)m * N + n] = acc[i][j][r];
      }
}

// ---------------- retention: pre-rotated Qr/Kr, int4 staging (validated math) ----------------
constexpr int LDK = 136;   // u16 stride, rotated Q'/K' tile [64][128]
constexpr int LDP = 76;    // f32 stride, P tile [64 q][64 t]
constexpr int LDVS = 74;   // u16 stride, V tile row-major [64 t][64 j]
constexpr int LDR = 65;    // f32 stride, O tile [64 q][64 j]

// stage a [64][128] fp16 tile via pure int4 copies (GEMM-validated pattern)
static __device__ __forceinline__ void stage_tile(
    const u16* __restrict__ src, int bh, int r0, int tid, u16* Ks) {
#pragma unroll
  for (int p = 0; p < 4; p++) {
    int c = p * 256 + tid;  // 1024 16B-chunks
    int row = c >> 4, col = (c & 15) * 8;
    *reinterpret_cast<int4*>(&Ks[row * LDK + col]) =
        *reinterpret_cast<const int4*>(&src[((size_t)bh * 2048 + r0 + row) * 128 + col]);
  }
}

__global__ __launch_bounds__(256) void k_retention(
    const u16* __restrict__ Qr, const u16* __restrict__ Kr,
    const u16* __restrict__ vh_,
    const float* __restrict__ lnw, const float* __restrict__ lnb,
    u16* __restrict__ Y) {
  __shared__ __align__(16) char SM[17408 + 9472 + 19456];
  u16*   Ks = (u16*)SM;
  u16*   Vs = (u16*)(SM + 17408);
  float* Ps = (float*)(SM + 17408 + 9472);
  float* Rs = (float*)(SM + 17408 + 9472);  // overlays Ps after kt loop
  __shared__ float mus[64], rstds[64];

  const int tid = threadIdx.x;
  const int bh = blockIdx.y, b = bh >> 4, h = bh & 15;
  const int qt = (int)gridDim.x - 1 - (int)blockIdx.x;  // heavy tiles first
  const int qbase = qt * 64;
  const int wid = tid >> 6, lane = tid & 63, lr = lane & 15, lg = lane >> 4;
  const int qg = qbase + wid * 16;
  const float lg2g = log2f(1.0f - exp2f(-5.0f - (float)h));

  // prologue: stage Q' tile, read A-fragments (validated pattern)
  stage_tile(Qr, bh, qbase, tid, Ks);
  __syncthreads();
  u16x8 qa[4];
#pragma unroll
  for (int dc = 0; dc < 4; dc++)
    qa[dc] = *reinterpret_cast<const u16x8*>(&Ks[(wid * 16 + lr) * LDK + dc * 32 + 8 * lg]);

  const f32x4 fz = {0.f, 0.f, 0.f, 0.f};
  f32x4 oacc[4];
#pragma unroll
  for (int j = 0; j < 4; j++) oacc[j] = fz;

  for (int kt = 0; kt <= qt; ++kt) {
    const int t0 = kt * 64;
    const bool active = (t0 <= qg + 15);
    __syncthreads();
    stage_tile(Kr, bh, t0, tid, Ks);
#pragma unroll
    for (int p = 0; p < 2; p++) {
      int c = p * 256 + tid;
      int tl = c >> 3, j0 = (c & 7) * 8;
      u16x8 v8 = *reinterpret_cast<const u16x8*>(&vh_[((size_t)bh * 2048 + t0 + tl) * 64 + j0]);
#pragma unroll
      for (int e = 0; e < 8; e++) Vs[tl * LDVS + j0 + e] = v8[e];
    }
    __syncthreads();

    if (active) {
#pragma unroll
      for (int tn = 0; tn < 4; tn++) {
        f32x4 st = fz;
#pragma unroll
        for (int dc = 0; dc < 4; dc++) {
          u16x8 kb = *reinterpret_cast<const u16x8*>(&Ks[(tn * 16 + lr) * LDK + dc * 32 + 8 * lg]);
          st = mfma16h(qa[dc], kb, st);
        }
        const int t = t0 + tn * 16 + lr;
#pragma unroll
        for (int i = 0; i < 4; i++) {
          int q = qg + 4 * lg + i;
          float v = st[i];
          v = (t <= q) ? v * exp2f((float)(q - t) * lg2g) : 0.f;
          Ps[(wid * 16 + 4 * lg + i) * LDP + tn * 16 + lr] = v;
        }
      }
    }
    __syncthreads();  // fence between P-writes and P fragment reads

    if (active) {
#pragma unroll
      for (int c2 = 0; c2 < 2; c2++) {
        const float* pr = &Ps[(wid * 16 + lr) * LDP + c2 * 32 + 8 * lg];
        float4 p0 = *reinterpret_cast<const float4*>(pr);
        float4 p1 = *reinterpret_cast<const float4*>(pr + 4);
        const float* f0 = reinterpret_cast<const float*>(&p0);
        const float* f1 = reinterpret_cast<const float*>(&p1);
        u16x8 pa;
#pragma unroll
        for (int e = 0; e < 4; e++) {
          pa[e] = f2h(f0[e]);
          pa[e + 4] = f2h(f1[e]);
        }
#pragma unroll
        for (int jn = 0; jn < 4; jn++) {
          u16x8 vb;
#pragma unroll
          for (int e = 0; e < 8; e++)
            vb[e] = Vs[(c2 * 32 + 8 * lg + e) * LDVS + jn * 16 + lr];
          oacc[jn] = mfma16h(pa, vb, oacc[jn]);
        }
      }
    }
  }

  __syncthreads();
#pragma unroll
  for (int jn = 0; jn < 4; jn++)
#pragma unroll
    for (int i = 0; i < 4; i++)
      Rs[(wid * 16 + 4 * lg + i) * LDR + jn * 16 + lr] = oacc[jn][i];
  __syncthreads();
  if (tid < 64) {
    float s1 = 0.f, s2 = 0.f;
    for (int j = 0; j < 64; j++) { float v = Rs[tid * LDR + j]; s1 += v; s2 += v * v; }
    float mu = s1 * (1.f / 64.f);
    float var = s2 * (1.f / 64.f) - mu * mu;
    mus[tid] = mu; rstds[tid] = rsqrtf(var + 1e-5f);
  }
  __syncthreads();
  for (int p = tid; p < 4096; p += 256) {
    int sl = p >> 6, j = p & 63;
    float y = (Rs[sl * LDR + j] - mus[sl]) * rstds[sl] * lnw[j] + lnb[j];
    y = y / (1.f + expf(-y));
    Y[((size_t)b * 2048 + qbase + sl) * 1024 + h * 64 + j] = f2h(y);
  }
}

// ---------------- f32 patch for rows s < SP, from rotated hi+lo ----------------
#define SP 32
__global__ __launch_bounds__(256) void k_patch(
    const u16* __restrict__ Qr, const u16* __restrict__ qlo,
    const u16* __restrict__ Kr, const u16* __restrict__ klo,
    const u16* __restrict__ vh_,
    const float* __restrict__ lnw, const float* __restrict__ lnb,
    u16* __restrict__ Y) {
  const int bh = blockIdx.x, b = bh >> 4, h = bh & 15;
  __shared__ float qs[SP][132], ks[SP][132];
  __shared__ float vs[SP][64], rs[SP][64];
  __shared__ float ps[SP][SP];
  __shared__ float mus[SP], rstds[SP];
  const int tid = threadIdx.x;
  const float lg2g = log2f(1.0f - exp2f(-5.0f - (float)h));

  // phase 1: f32-grade rotated q', k' (hi+lo) and v
  for (int p = tid; p < SP * 128; p += 256) {
    int s = p >> 7, d = p & 127;
    size_t oh = ((size_t)bh * 2048 + s) * 128 + d;
    size_t ol = ((size_t)bh * 32 + s) * 128 + d;
    qs[s][d] = h2f(Qr[oh]) + h2f(qlo[ol]);
    ks[s][d] = h2f(Kr[oh]) + h2f(klo[ol]);
  }
  for (int p = tid; p < SP * 64; p += 256) {
    int s = p >> 6, d = p & 63;
    vs[s][d] = h2f(vh_[((size_t)bh * 2048 + s) * 64 + d]);
  }
  __syncthreads();
  // phase 2: scores with decay (f32)
  for (int p = tid; p < SP * SP; p += 256) {
    int s = p / SP, t = p % SP;
    float sc = 0.f;
    if (t <= s) {
      for (int d = 0; d < 128; d += 4) {
        float4 q4 = *reinterpret_cast<const float4*>(&qs[s][d]);
        float4 k4 = *reinterpret_cast<const float4*>(&ks[t][d]);
        sc += q4.x * k4.x + q4.y * k4.y + q4.z * k4.z + q4.w * k4.w;
      }
      sc *= exp2f((float)(s - t) * lg2g);
    }
    ps[s][t] = sc;
  }
  __syncthreads();
  // phase 3: r = P V
  for (int p = tid; p < SP * 64; p += 256) {
    int s = p >> 6, j = p & 63;
    float r = 0.f;
    for (int t = 0; t <= s; t++) r += ps[s][t] * vs[t][j];
    rs[s][j] = r;
  }
  __syncthreads();
  // phase 4: LN stats + store
  if (tid < SP) {
    float s1 = 0.f, s2 = 0.f;
    for (int j = 0; j < 64; j++) { float v = rs[tid][j]; s1 += v; s2 += v * v; }
    float mu = s1 * (1.f / 64.f);
    float var = s2 * (1.f / 64.f) - mu * mu;
    mus[tid] = mu; rstds[tid] = rsqrtf(var + 1e-5f);
  }
  __syncthreads();
  for (int p = tid; p < SP * 64; p += 256) {
    int s = p >> 6, j = p & 63;
    float y = (rs[s][j] - mus[s]) * rstds[s] * lnw[j] + lnb[j];
    y = y / (1.f + expf(-y));
    Y[((size_t)b * 2048 + s) * 1024 + h * 64 + j] = f2h(y);
  }
}

extern "C" void kernel_launch(void* const* d_in, const int* in_sizes, int n_in,
                              void* d_out, int out_size, void* d_ws, size_t ws_size,
                              hipStream_t stream) {
  const float* x   = (const float*)d_in[0];
  const float* Wq  = (const float*)d_in[1];
  const float* Wk  = (const float*)d_in[2];
  const float* Wv  = (const float*)d_in[3];
  const float* Wo  = (const float*)d_in[4];
  const float* lnw = (const float*)d_in[5];
  const float* lnb = (const float*)d_in[6];
  float* out = (float*)d_out;

  char* ws = (char*)d_ws;
  u16*   Qr   = (u16*)(ws + 0);            // [BH][S][128] rotated fp16, 32 MB
  u16*   Kr   = (u16*)(ws + 33554432);     // 32 MB
  u16*   vh   = (u16*)(ws + 67108864);     // [BH][S][64] fp16, 16 MB
  u16*   Y    = (u16*)(ws + 83886080);     // [B*S][D] fp16, 16 MB
  float* cosT = (float*)(ws + 100663296);  // [S][64] f32
  float* sinT = (float*)(ws + 101187584);
  u16*   qlo  = (u16*)(ws + 101711872);    // [BH][32][128] fp16 lo-residual
  u16*   klo  = (u16*)(ws + 102236160);
  // total 102,760,448 B

  k_trig<<<512, 256, 0, stream>>>(cosT, sinT);

  dim3 gg(8, 64);  // N/128, M/128
  k_gemm_split<0><<<gg, 256, 0, stream>>>(x, Wq, 8192, 1024, 1024, Qr, qlo, cosT, sinT);
  k_gemm_split<0><<<gg, 256, 0, stream>>>(x, Wk, 8192, 1024, 1024, Kr, klo, cosT, sinT);
  k_gemm_split<2><<<gg, 256, 0, stream>>>(x, Wv, 8192, 1024, 1024, vh, nullptr, nullptr, nullptr);

  k_retention<<<dim3(32, 64), 256, 0, stream>>>(Qr, Kr, vh, lnw, lnb, Y);

  k_patch<<<64, 256, 0, stream>>>(Qr, qlo, Kr, klo, vh, lnw, lnb, Y);

  k_gemm_out<<<gg, 256, 0, stream>>>(Y, Wo, 8192, 1024, 1024, out);
}

// Round 13
// 519.369 us; speedup vs baseline: 8.1674x; 1.0514x over previous
//
#include <hip/hip_runtime.h>

typedef unsigned short u16;
typedef _Float16 f16;
typedef _Float16 f16x8 __attribute__((ext_vector_type(8)));
typedef float f32x4 __attribute__((ext_vector_type(4)));
typedef unsigned short u16x8 __attribute__((ext_vector_type(8)));

static __device__ __forceinline__ u16 f2h(float f) {
  f16 h = (f16)f;
  return __builtin_bit_cast(u16, h);
}
static __device__ __forceinline__ float h2f(u16 h) {
  return (float)__builtin_bit_cast(f16, h);
}

static __device__ __forceinline__ f32x4 mfma16h(u16x8 a, u16x8 b, f32x4 c) {
  return __builtin_amdgcn_mfma_f32_16x16x32_f16(
      __builtin_bit_cast(f16x8, a), __builtin_bit_cast(f16x8, b), c, 0, 0, 0);
}

// ---------------- cos/sin tables [S][64], f64-accurate ----------------
__global__ void k_trig(float* __restrict__ cosT, float* __restrict__ sinT) {
  int idx = blockIdx.x * blockDim.x + threadIdx.x;  // S*64 threads
  int s = idx >> 6, j = idx & 63;
  double theta = exp2(-0.4152410118609203 * (double)j);  // 10000^(-j/32), f64
  double ang = (double)s * theta;
  cosT[idx] = (float)cos(ang);
  sinT[idx] = (float)sin(ang);
}

// ---------------- split-fp16 TN GEMM (validated structure) ----------------
// MODE 0: 3-pass Dekker; epilogue ROTATES and scatters fp16 to [BH][S][128];
//         lo-residual of rotated values stored for s<32 rows into loB [BH][32][128].
// MODE 2: single-pass; scatter hi to [BH][S][64] (V).
template <int MODE>
__global__ __launch_bounds__(256) void k_gemm_split(
    const float* __restrict__ A, const float* __restrict__ Bw,
    int M, int N, int K,
    u16* __restrict__ outH, u16* __restrict__ loB,
    const float* __restrict__ cosT, const float* __restrict__ sinT) {
  constexpr int LDT = 40;
  __shared__ __align__(16) u16 Ash[128 * LDT];
  __shared__ __align__(16) u16 Asl[128 * LDT];
  __shared__ __align__(16) u16 Bsh[128 * LDT];
  __shared__ __align__(16) u16 Bsl[128 * LDT];
  const int tid = threadIdx.x;
  const int m0 = blockIdx.y * 128;
  const int n0 = blockIdx.x * 128;
  const int lane = tid & 63, lr = lane & 15, lg = lane >> 4;
  const int wid = tid >> 6;
  const int wm = (wid >> 1) * 64, wn = (wid & 1) * 64;

  const f32x4 fz = {0.f, 0.f, 0.f, 0.f};
  f32x4 acc[4][4];
#pragma unroll
  for (int i = 0; i < 4; i++)
#pragma unroll
    for (int j = 0; j < 4; j++) acc[i][j] = fz;

  for (int k0 = 0; k0 < K; k0 += 32) {
    __syncthreads();
#pragma unroll
    for (int p = 0; p < 4; p++) {
      int c = p * 256 + tid;
      int row = c >> 3, col = (c & 7) * 4;
      float4 av = *reinterpret_cast<const float4*>(&A[(size_t)(m0 + row) * K + k0 + col]);
      float4 bv = *reinterpret_cast<const float4*>(&Bw[(size_t)(n0 + row) * K + k0 + col]);
      const float* ap = reinterpret_cast<const float*>(&av);
      const float* bp = reinterpret_cast<const float*>(&bv);
#pragma unroll
      for (int e = 0; e < 4; e++) {
        u16 h = f2h(ap[e]);
        Ash[row * LDT + col + e] = h;
        if constexpr (MODE == 0) Asl[row * LDT + col + e] = f2h(ap[e] - h2f(h));
        u16 hb = f2h(bp[e]);
        Bsh[row * LDT + col + e] = hb;
        if constexpr (MODE == 0) Bsl[row * LDT + col + e] = f2h(bp[e] - h2f(hb));
      }
    }
    __syncthreads();
    u16x8 ah[4], al[4], bh[4], bl[4];
#pragma unroll
    for (int i = 0; i < 4; i++) {
      ah[i] = *reinterpret_cast<const u16x8*>(&Ash[(wm + i * 16 + lr) * LDT + 8 * lg]);
      if constexpr (MODE == 0)
        al[i] = *reinterpret_cast<const u16x8*>(&Asl[(wm + i * 16 + lr) * LDT + 8 * lg]);
    }
#pragma unroll
    for (int j = 0; j < 4; j++) {
      bh[j] = *reinterpret_cast<const u16x8*>(&Bsh[(wn + j * 16 + lr) * LDT + 8 * lg]);
      if constexpr (MODE == 0)
        bl[j] = *reinterpret_cast<const u16x8*>(&Bsl[(wn + j * 16 + lr) * LDT + 8 * lg]);
    }
#pragma unroll
    for (int i = 0; i < 4; i++)
#pragma unroll
      for (int j = 0; j < 4; j++) {
        acc[i][j] = mfma16h(ah[i], bh[j], acc[i][j]);
        if constexpr (MODE == 0) {
          acc[i][j] = mfma16h(ah[i], bl[j], acc[i][j]);
          acc[i][j] = mfma16h(al[i], bh[j], acc[i][j]);
        }
      }
  }

#pragma unroll
  for (int i = 0; i < 4; i++)
#pragma unroll
    for (int j = 0; j < 4; j++)
#pragma unroll
      for (int r = 0; r < 4; r++) {
        int m = m0 + wm + i * 16 + 4 * lg + r;
        int n = n0 + wn + j * 16 + lr;
        float v = acc[i][j][r];
        int b = m >> 11, s = m & 2047;  // S = 2048
        int h = n >> 6, jj = n & 63;
        if constexpr (MODE == 2) {
          outH[(((size_t)(b * 16 + h)) * 2048 + s) * 64 + jj] = f2h(v);
        } else {
          float cv = cosT[s * 64 + jj], sv = sinT[s * 64 + jj];
          float a = v * cv, bb = v * sv;
          size_t o = (((size_t)(b * 16 + h)) * 2048 + s) * 128 + jj;
          u16 ahh = f2h(a), bhh = f2h(bb);
          outH[o] = ahh;
          outH[o + 64] = bhh;
          if (s < 32) {
            size_t ol = (((size_t)(b * 16 + h)) * 32 + s) * 128 + jj;
            loB[ol] = f2h(a - h2f(ahh));
            loB[ol + 64] = f2h(bb - h2f(bhh));
          }
        }
      }
}

// ---------------- single-pass fp16 GEMM for out = Y @ Wo^T (validated) ----------------
__global__ __launch_bounds__(256) void k_gemm_out(
    const u16* __restrict__ A, const float* __restrict__ Bw,
    int M, int N, int K, float* __restrict__ outF) {
  constexpr int LDT = 40;
  __shared__ __align__(16) u16 As[128 * LDT];
  __shared__ __align__(16) u16 Bs[128 * LDT];
  const int tid = threadIdx.x;
  const int m0 = blockIdx.y * 128;
  const int n0 = blockIdx.x * 128;
  const int lane = tid & 63, lr = lane & 15, lg = lane >> 4;
  const int wid = tid >> 6;
  const int wm = (wid >> 1) * 64, wn = (wid & 1) * 64;

  const f32x4 fz = {0.f, 0.f, 0.f, 0.f};
  f32x4 acc[4][4];
#pragma unroll
  for (int i = 0; i < 4; i++)
#pragma unroll
    for (int j = 0; j < 4; j++) acc[i][j] = fz;

  for (int k0 = 0; k0 < K; k0 += 32) {
    __syncthreads();
#pragma unroll
    for (int p = 0; p < 2; p++) {
      int c = p * 256 + tid;
      int row = c >> 2, col = (c & 3) * 8;
      *reinterpret_cast<int4*>(&As[row * LDT + col]) =
          *reinterpret_cast<const int4*>(&A[(size_t)(m0 + row) * K + k0 + col]);
    }
#pragma unroll
    for (int p = 0; p < 4; p++) {
      int c = p * 256 + tid;
      int row = c >> 3, col = (c & 7) * 4;
      float4 bv = *reinterpret_cast<const float4*>(&Bw[(size_t)(n0 + row) * K + k0 + col]);
      const float* bp = reinterpret_cast<const float*>(&bv);
#pragma unroll
      for (int e = 0; e < 4; e++) Bs[row * LDT + col + e] = f2h(bp[e]);
    }
    __syncthreads();
    u16x8 af[4], bf[4];
#pragma unroll
    for (int i = 0; i < 4; i++)
      af[i] = *reinterpret_cast<const u16x8*>(&As[(wm + i * 16 + lr) * LDT + 8 * lg]);
#pragma unroll
    for (int j = 0; j < 4; j++)
      bf[j] = *reinterpret_cast<const u16x8*>(&Bs[(wn + j * 16 + lr) * LDT + 8 * lg]);
#pragma unroll
    for (int i = 0; i < 4; i++)
#pragma unroll
      for (int j = 0; j < 4; j++) acc[i][j] = mfma16h(af[i], bf[j], acc[i][j]);
  }

#pragma unroll
  for (int i = 0; i < 4; i++)
#pragma unroll
    for (int j = 0; j < 4; j++)
#pragma unroll
      for (int r = 0; r < 4; r++) {
        int m = m0 + wm + i * 16 + 4 * lg + r;
        int n = n0 + wn + j * 16 + lr;
        outF[(size_t)m * N + n] = acc[i][j][r];
      }
}

// ---------------- retention: QBLK=128, 8 waves, validated per-wave math ----------------
constexpr int LDK = 136;   // u16 stride, rotated Q'/K' tile [64][128]
constexpr int LDP = 68;    // f32 stride, P tile [128 q][64 t]
constexpr int LDVS = 74;   // u16 stride, V tile row-major [64 t][64 j]
constexpr int LDR = 65;    // f32 stride, O tile [128 q][64 j]

// stage a [64][128] fp16 tile via pure int4 copies, 512 threads (2 chunks each)
static __device__ __forceinline__ void stage_tile(
    const u16* __restrict__ src, int bh, int r0, int tid, u16* Ks) {
#pragma unroll
  for (int p = 0; p < 2; p++) {
    int c = p * 512 + tid;  // 1024 16B-chunks
    int row = c >> 4, col = (c & 15) * 8;
    *reinterpret_cast<int4*>(&Ks[row * LDK + col]) =
        *reinterpret_cast<const int4*>(&src[((size_t)bh * 2048 + r0 + row) * 128 + col]);
  }
}

__global__ __launch_bounds__(512) void k_retention(
    const u16* __restrict__ Qr, const u16* __restrict__ Kr,
    const u16* __restrict__ vh_,
    const float* __restrict__ lnw, const float* __restrict__ lnb,
    u16* __restrict__ Y) {
  // LDS: Ks 17408 | Vs 9472 | Ps 34816 (Rs 33280 overlays Ps) = 61696 B
  __shared__ __align__(16) char SM[17408 + 9472 + 34816];
  u16*   Ks = (u16*)SM;
  u16*   Vs = (u16*)(SM + 17408);
  float* Ps = (float*)(SM + 17408 + 9472);
  float* Rs = (float*)(SM + 17408 + 9472);  // overlays Ps after kt loop
  __shared__ float mus[128], rstds[128];

  const int tid = threadIdx.x;
  const int bh = blockIdx.y, b = bh >> 4, h = bh & 15;
  const int qt = (int)gridDim.x - 1 - (int)blockIdx.x;  // heavy tiles first
  const int qbase = qt * 128;
  const int wid = tid >> 6, lane = tid & 63, lr = lane & 15, lg = lane >> 4;
  const int qg = qbase + wid * 16;  // this wave's first q row
  const float lg2g = log2f(1.0f - exp2f(-5.0f - (float)h));

  // ---- prologue: stage Q' in two 64-row halves through Ks, read A-fragments ----
  u16x8 qa[4];
  stage_tile(Qr, bh, qbase, tid, Ks);
  __syncthreads();
  if (wid < 4) {
#pragma unroll
    for (int dc = 0; dc < 4; dc++)
      qa[dc] = *reinterpret_cast<const u16x8*>(&Ks[(wid * 16 + lr) * LDK + dc * 32 + 8 * lg]);
  }
  __syncthreads();
  stage_tile(Qr, bh, qbase + 64, tid, Ks);
  __syncthreads();
  if (wid >= 4) {
#pragma unroll
    for (int dc = 0; dc < 4; dc++)
      qa[dc] = *reinterpret_cast<const u16x8*>(&Ks[((wid - 4) * 16 + lr) * LDK + dc * 32 + 8 * lg]);
  }

  const f32x4 fz = {0.f, 0.f, 0.f, 0.f};
  f32x4 oacc[4];
#pragma unroll
  for (int j = 0; j < 4; j++) oacc[j] = fz;

  const int ntiles = 2 * qt + 2;
  for (int kt = 0; kt < ntiles; ++kt) {
    const int t0 = kt * 64;
    const bool active = (t0 <= qg + 15);  // wave-uniform
    __syncthreads();  // prior tile's reads done (and prologue frag reads)
    stage_tile(Kr, bh, t0, tid, Ks);
    // stage V tile row-major [t][j]: 512 chunks, 1 per thread
    {
      int tl = tid >> 3, j0 = (tid & 7) * 8;
      u16x8 v8 = *reinterpret_cast<const u16x8*>(&vh_[((size_t)bh * 2048 + t0 + tl) * 64 + j0]);
#pragma unroll
      for (int e = 0; e < 8; e++) Vs[tl * LDVS + j0 + e] = v8[e];
    }
    __syncthreads();

    // ---- QK^T (validated cluster): D rows = q (4*lg+i), cols = t (lr) ----
    if (active) {
#pragma unroll
      for (int tn = 0; tn < 4; tn++) {
        f32x4 st = fz;
#pragma unroll
        for (int dc = 0; dc < 4; dc++) {
          u16x8 kb = *reinterpret_cast<const u16x8*>(&Ks[(tn * 16 + lr) * LDK + dc * 32 + 8 * lg]);
          st = mfma16h(qa[dc], kb, st);
        }
        const int t = t0 + tn * 16 + lr;
#pragma unroll
        for (int i = 0; i < 4; i++) {
          int q = qg + 4 * lg + i;
          float v = st[i];
          v = (t <= q) ? v * exp2f((float)(q - t) * lg2g) : 0.f;
          Ps[(wid * 16 + 4 * lg + i) * LDP + tn * 16 + lr] = v;
        }
      }
    }
    __syncthreads();  // fence between P-writes and P fragment reads

    // ---- PV MFMA: A = P (GEMM af pattern), B = V row-major scalar reads ----
    if (active) {
#pragma unroll
      for (int c2 = 0; c2 < 2; c2++) {
        const float* pr = &Ps[(wid * 16 + lr) * LDP + c2 * 32 + 8 * lg];
        float4 p0 = *reinterpret_cast<const float4*>(pr);
        float4 p1 = *reinterpret_cast<const float4*>(pr + 4);
        const float* f0 = reinterpret_cast<const float*>(&p0);
        const float* f1 = reinterpret_cast<const float*>(&p1);
        u16x8 pa;
#pragma unroll
        for (int e = 0; e < 4; e++) {
          pa[e] = f2h(f0[e]);
          pa[e + 4] = f2h(f1[e]);
        }
#pragma unroll
        for (int jn = 0; jn < 4; jn++) {
          u16x8 vb;
#pragma unroll
          for (int e = 0; e < 8; e++)
            vb[e] = Vs[(c2 * 32 + 8 * lg + e) * LDVS + jn * 16 + lr];
          oacc[jn] = mfma16h(pa, vb, oacc[jn]);
        }
      }
    }
  }

  // ---- epilogue via LDS roundtrip (validated) ----
  __syncthreads();  // all Ps reads done before overlaying Rs
#pragma unroll
  for (int jn = 0; jn < 4; jn++)
#pragma unroll
    for (int i = 0; i < 4; i++)
      Rs[(wid * 16 + 4 * lg + i) * LDR + jn * 16 + lr] = oacc[jn][i];
  __syncthreads();
  if (tid < 128) {
    float s1 = 0.f, s2 = 0.f;
    for (int j = 0; j < 64; j++) { float v = Rs[tid * LDR + j]; s1 += v; s2 += v * v; }
    float mu = s1 * (1.f / 64.f);
    float var = s2 * (1.f / 64.f) - mu * mu;
    mus[tid] = mu; rstds[tid] = rsqrtf(var + 1e-5f);
  }
  __syncthreads();
  for (int p = tid; p < 8192; p += 512) {
    int sl = p >> 6, j = p & 63;
    float y = (Rs[sl * LDR + j] - mus[sl]) * rstds[sl] * lnw[j] + lnb[j];
    y = y / (1.f + expf(-y));
    Y[((size_t)b * 2048 + qbase + sl) * 1024 + h * 64 + j] = f2h(y);
  }
}

// ---------------- f32 patch for rows s < SP, from rotated hi+lo (validated) ----------------
#define SP 32
__global__ __launch_bounds__(256) void k_patch(
    const u16* __restrict__ Qr, const u16* __restrict__ qlo,
    const u16* __restrict__ Kr, const u16* __restrict__ klo,
    const u16* __restrict__ vh_,
    const float* __restrict__ lnw, const float* __restrict__ lnb,
    u16* __restrict__ Y) {
  const int bh = blockIdx.x, b = bh >> 4, h = bh & 15;
  __shared__ float qs[SP][132], ks[SP][132];
  __shared__ float vs[SP][64], rs[SP][64];
  __shared__ float ps[SP][SP];
  __shared__ float mus[SP], rstds[SP];
  const int tid = threadIdx.x;
  const float lg2g = log2f(1.0f - exp2f(-5.0f - (float)h));

  for (int p = tid; p < SP * 128; p += 256) {
    int s = p >> 7, d = p & 127;
    size_t oh = ((size_t)bh * 2048 + s) * 128 + d;
    size_t ol = ((size_t)bh * 32 + s) * 128 + d;
    qs[s][d] = h2f(Qr[oh]) + h2f(qlo[ol]);
    ks[s][d] = h2f(Kr[oh]) + h2f(klo[ol]);
  }
  for (int p = tid; p < SP * 64; p += 256) {
    int s = p >> 6, d = p & 63;
    vs[s][d] = h2f(vh_[((size_t)bh * 2048 + s) * 64 + d]);
  }
  __syncthreads();
  for (int p = tid; p < SP * SP; p += 256) {
    int s = p / SP, t = p % SP;
    float sc = 0.f;
    if (t <= s) {
      for (int d = 0; d < 128; d += 4) {
        float4 q4 = *reinterpret_cast<const float4*>(&qs[s][d]);
        float4 k4 = *reinterpret_cast<const float4*>(&ks[t][d]);
        sc += q4.x * k4.x + q4.y * k4.y + q4.z * k4.z + q4.w * k4.w;
      }
      sc *= exp2f((float)(s - t) * lg2g);
    }
    ps[s][t] = sc;
  }
  __syncthreads();
  for (int p = tid; p < SP * 64; p += 256) {
    int s = p >> 6, j = p & 63;
    float r = 0.f;
    for (int t = 0; t <= s; t++) r += ps[s][t] * vs[t][j];
    rs[s][j] = r;
  }
  __syncthreads();
  if (tid < SP) {
    float s1 = 0.f, s2 = 0.f;
    for (int j = 0; j < 64; j++) { float v = rs[tid][j]; s1 += v; s2 += v * v; }
    float mu = s1 * (1.f / 64.f);
    float var = s2 * (1.f / 64.f) - mu * mu;
    mus[tid] = mu; rstds[tid] = rsqrtf(var + 1e-5f);
  }
  __syncthreads();
  for (int p = tid; p < SP * 64; p += 256) {
    int s = p >> 6, j = p & 63;
    float y = (rs[s][j] - mus[s]) * rstds[s] * lnw[j] + lnb[j];
    y = y / (1.f + expf(-y));
    Y[((size_t)b * 2048 + s) * 1024 + h * 64 + j] = f2h(y);
  }
}

extern "C" void kernel_launch(void* const* d_in, const int* in_sizes, int n_in,
                              void* d_out, int out_size, void* d_ws, size_t ws_size,
                              hipStream_t stream) {
  const float* x   = (const float*)d_in[0];
  const float* Wq  = (const float*)d_in[1];
  const float* Wk  = (const float*)d_in[2];
  const float* Wv  = (const float*)d_in[3];
  const float* Wo  = (const float*)d_in[4];
  const float* lnw = (const float*)d_in[5];
  const float* lnb = (const float*)d_in[6];
  float* out = (float*)d_out;

  char* ws = (char*)d_ws;
  u16*   Qr   = (u16*)(ws + 0);            // [BH][S][128] rotated fp16, 32 MB
  u16*   Kr   = (u16*)(ws + 33554432);     // 32 MB
  u16*   vh   = (u16*)(ws + 67108864);     // [BH][S][64] fp16, 16 MB
  u16*   Y    = (u16*)(ws + 83886080);     // [B*S][D] fp16, 16 MB
  float* cosT = (float*)(ws + 100663296);  // [S][64] f32
  float* sinT = (float*)(ws + 101187584);
  u16*   qlo  = (u16*)(ws + 101711872);    // [BH][32][128] fp16 lo-residual
  u16*   klo  = (u16*)(ws + 102236160);

  k_trig<<<512, 256, 0, stream>>>(cosT, sinT);

  dim3 gg(8, 64);  // N/128, M/128
  k_gemm_split<0><<<gg, 256, 0, stream>>>(x, Wq, 8192, 1024, 1024, Qr, qlo, cosT, sinT);
  k_gemm_split<0><<<gg, 256, 0, stream>>>(x, Wk, 8192, 1024, 1024, Kr, klo, cosT, sinT);
  k_gemm_split<2><<<gg, 256, 0, stream>>>(x, Wv, 8192, 1024, 1024, vh, nullptr, nullptr, nullptr);

  k_retention<<<dim3(16, 64), 512, 0, stream>>>(Qr, Kr, vh, lnw, lnb, Y);

  k_patch<<<64, 256, 0, stream>>>(Qr, qlo, Kr, klo, vh, lnw, lnb, Y);

  k_gemm_out<<<gg, 256, 0, stream>>>(Y, Wo, 8192, 1024, 1024, out);
}

// Round 14
// 457.327 us; speedup vs baseline: 9.2754x; 1.1357x over previous
//
#include <hip/hip_runtime.h>

typedef unsigned short u16;
typedef _Float16 f16;
typedef _Float16 f16x8 __attribute__((ext_vector_type(8)));
typedef float f32x4 __attribute__((ext_vector_type(4)));
typedef unsigned short u16x8 __attribute__((ext_vector_type(8)));

static __device__ __forceinline__ u16 f2h(float f) {
  f16 h = (f16)f;
  return __builtin_bit_cast(u16, h);
}
static __device__ __forceinline__ float h2f(u16 h) {
  return (float)__builtin_bit_cast(f16, h);
}

static __device__ __forceinline__ f32x4 mfma16h(u16x8 a, u16x8 b, f32x4 c) {
  return __builtin_amdgcn_mfma_f32_16x16x32_f16(
      __builtin_bit_cast(f16x8, a), __builtin_bit_cast(f16x8, b), c, 0, 0, 0);
}

// ---------------- cos/sin tables [S][64], f64-accurate ----------------
__global__ void k_trig(float* __restrict__ cosT, float* __restrict__ sinT) {
  int idx = blockIdx.x * blockDim.x + threadIdx.x;  // S*64 threads
  int s = idx >> 6, j = idx & 63;
  double theta = exp2(-0.4152410118609203 * (double)j);  // 10000^(-j/32), f64
  double ang = (double)s * theta;
  cosT[idx] = (float)cos(ang);
  sinT[idx] = (float)sin(ang);
}

// ---------------- split-fp16 TN GEMM (validated structure) ----------------
// MODE 0: 3-pass Dekker; epilogue ROTATES and scatters fp16 to [BH][S][128];
//         lo-residual of rotated values stored for s<32 rows into loB [BH][32][128].
// MODE 2: single-pass; scatter hi to [BH][S][64] (V).
template <int MODE>
__global__ __launch_bounds__(256) void k_gemm_split(
    const float* __restrict__ A, const float* __restrict__ Bw,
    int M, int N, int K,
    u16* __restrict__ outH, u16* __restrict__ loB,
    const float* __restrict__ cosT, const float* __restrict__ sinT) {
  constexpr int LDT = 40;
  __shared__ __align__(16) u16 Ash[128 * LDT];
  __shared__ __align__(16) u16 Asl[128 * LDT];
  __shared__ __align__(16) u16 Bsh[128 * LDT];
  __shared__ __align__(16) u16 Bsl[128 * LDT];
  const int tid = threadIdx.x;
  const int m0 = blockIdx.y * 128;
  const int n0 = blockIdx.x * 128;
  const int lane = tid & 63, lr = lane & 15, lg = lane >> 4;
  const int wid = tid >> 6;
  const int wm = (wid >> 1) * 64, wn = (wid & 1) * 64;

  const f32x4 fz = {0.f, 0.f, 0.f, 0.f};
  f32x4 acc[4][4];
#pragma unroll
  for (int i = 0; i < 4; i++)
#pragma unroll
    for (int j = 0; j < 4; j++) acc[i][j] = fz;

  for (int k0 = 0; k0 < K; k0 += 32) {
    __syncthreads();
#pragma unroll
    for (int p = 0; p < 4; p++) {
      int c = p * 256 + tid;
      int row = c >> 3, col = (c & 7) * 4;
      float4 av = *reinterpret_cast<const float4*>(&A[(size_t)(m0 + row) * K + k0 + col]);
      float4 bv = *reinterpret_cast<const float4*>(&Bw[(size_t)(n0 + row) * K + k0 + col]);
      const float* ap = reinterpret_cast<const float*>(&av);
      const float* bp = reinterpret_cast<const float*>(&bv);
#pragma unroll
      for (int e = 0; e < 4; e++) {
        u16 h = f2h(ap[e]);
        Ash[row * LDT + col + e] = h;
        if constexpr (MODE == 0) Asl[row * LDT + col + e] = f2h(ap[e] - h2f(h));
        u16 hb = f2h(bp[e]);
        Bsh[row * LDT + col + e] = hb;
        if constexpr (MODE == 0) Bsl[row * LDT + col + e] = f2h(bp[e] - h2f(hb));
      }
    }
    __syncthreads();
    u16x8 ah[4], al[4], bh[4], bl[4];
#pragma unroll
    for (int i = 0; i < 4; i++) {
      ah[i] = *reinterpret_cast<const u16x8*>(&Ash[(wm + i * 16 + lr) * LDT + 8 * lg]);
      if constexpr (MODE == 0)
        al[i] = *reinterpret_cast<const u16x8*>(&Asl[(wm + i * 16 + lr) * LDT + 8 * lg]);
    }
#pragma unroll
    for (int j = 0; j < 4; j++) {
      bh[j] = *reinterpret_cast<const u16x8*>(&Bsh[(wn + j * 16 + lr) * LDT + 8 * lg]);
      if constexpr (MODE == 0)
        bl[j] = *reinterpret_cast<const u16x8*>(&Bsl[(wn + j * 16 + lr) * LDT + 8 * lg]);
    }
#pragma unroll
    for (int i = 0; i < 4; i++)
#pragma unroll
      for (int j = 0; j < 4; j++) {
        acc[i][j] = mfma16h(ah[i], bh[j], acc[i][j]);
        if constexpr (MODE == 0) {
          acc[i][j] = mfma16h(ah[i], bl[j], acc[i][j]);
          acc[i][j] = mfma16h(al[i], bh[j], acc[i][j]);
        }
      }
  }

#pragma unroll
  for (int i = 0; i < 4; i++)
#pragma unroll
    for (int j = 0; j < 4; j++)
#pragma unroll
      for (int r = 0; r < 4; r++) {
        int m = m0 + wm + i * 16 + 4 * lg + r;
        int n = n0 + wn + j * 16 + lr;
        float v = acc[i][j][r];
        int b = m >> 11, s = m & 2047;  // S = 2048
        int h = n >> 6, jj = n & 63;
        if constexpr (MODE == 2) {
          outH[(((size_t)(b * 16 + h)) * 2048 + s) * 64 + jj] = f2h(v);
        } else {
          float cv = cosT[s * 64 + jj], sv = sinT[s * 64 + jj];
          float a = v * cv, bb = v * sv;
          size_t o = (((size_t)(b * 16 + h)) * 2048 + s) * 128 + jj;
          u16 ahh = f2h(a), bhh = f2h(bb);
          outH[o] = ahh;
          outH[o + 64] = bhh;
          if (s < 32) {
            size_t ol = (((size_t)(b * 16 + h)) * 32 + s) * 128 + jj;
            loB[ol] = f2h(a - h2f(ahh));
            loB[ol + 64] = f2h(bb - h2f(bhh));
          }
        }
      }
}

// ---------------- single-pass fp16 GEMM for out = Y @ Wo^T (validated) ----------------
__global__ __launch_bounds__(256) void k_gemm_out(
    const u16* __restrict__ A, const float* __restrict__ Bw,
    int M, int N, int K, float* __restrict__ outF) {
  constexpr int LDT = 40;
  __shared__ __align__(16) u16 As[128 * LDT];
  __shared__ __align__(16) u16 Bs[128 * LDT];
  const int tid = threadIdx.x;
  const int m0 = blockIdx.y * 128;
  const int n0 = blockIdx.x * 128;
  const int lane = tid & 63, lr = lane & 15, lg = lane >> 4;
  const int wid = tid >> 6;
  const int wm = (wid >> 1) * 64, wn = (wid & 1) * 64;

  const f32x4 fz = {0.f, 0.f, 0.f, 0.f};
  f32x4 acc[4][4];
#pragma unroll
  for (int i = 0; i < 4; i++)
#pragma unroll
    for (int j = 0; j < 4; j++) acc[i][j] = fz;

  for (int k0 = 0; k0 < K; k0 += 32) {
    __syncthreads();
#pragma unroll
    for (int p = 0; p < 2; p++) {
      int c = p * 256 + tid;
      int row = c >> 2, col = (c & 3) * 8;
      *reinterpret_cast<int4*>(&As[row * LDT + col]) =
          *reinterpret_cast<const int4*>(&A[(size_t)(m0 + row) * K + k0 + col]);
    }
#pragma unroll
    for (int p = 0; p < 4; p++) {
      int c = p * 256 + tid;
      int row = c >> 3, col = (c & 7) * 4;
      float4 bv = *reinterpret_cast<const float4*>(&Bw[(size_t)(n0 + row) * K + k0 + col]);
      const float* bp = reinterpret_cast<const float*>(&bv);
#pragma unroll
      for (int e = 0; e < 4; e++) Bs[row * LDT + col + e] = f2h(bp[e]);
    }
    __syncthreads();
    u16x8 af[4], bf[4];
#pragma unroll
    for (int i = 0; i < 4; i++)
      af[i] = *reinterpret_cast<const u16x8*>(&As[(wm + i * 16 + lr) * LDT + 8 * lg]);
#pragma unroll
    for (int j = 0; j < 4; j++)
      bf[j] = *reinterpret_cast<const u16x8*>(&Bs[(wn + j * 16 + lr) * LDT + 8 * lg]);
#pragma unroll
    for (int i = 0; i < 4; i++)
#pragma unroll
      for (int j = 0; j < 4; j++) acc[i][j] = mfma16h(af[i], bf[j], acc[i][j]);
  }

#pragma unroll
  for (int i = 0; i < 4; i++)
#pragma unroll
    for (int j = 0; j < 4; j++)
#pragma unroll
      for (int r = 0; r < 4; r++) {
        int m = m0 + wm + i * 16 + 4 * lg + r;
        int n = n0 + wn + j * 16 + lr;
        outF[(size_t)m * N + n] = acc[i][j][r];
      }
}

// ---------------- retention: QBLK=128, fp16 P in LDS, wave-local P fence ----------------
constexpr int LDK = 136;   // u16 stride, rotated Q'/K' tile [64][128]
constexpr int LDPh = 72;   // u16 stride, P tile fp16 [128 q][64 t] (rows 16B-aligned)
constexpr int LDVS = 74;   // u16 stride, V tile row-major [64 t][64 j]
constexpr int LDR = 65;    // f32 stride, O tile [128 q][64 j]

// stage a [64][128] fp16 tile via pure int4 copies, 512 threads (2 chunks each)
static __device__ __forceinline__ void stage_tile(
    const u16* __restrict__ src, int bh, int r0, int tid, u16* Ks) {
#pragma unroll
  for (int p = 0; p < 2; p++) {
    int c = p * 512 + tid;  // 1024 16B-chunks
    int row = c >> 4, col = (c & 15) * 8;
    *reinterpret_cast<int4*>(&Ks[row * LDK + col]) =
        *reinterpret_cast<const int4*>(&src[((size_t)bh * 2048 + r0 + row) * 128 + col]);
  }
}

__global__ __launch_bounds__(512) void k_retention(
    const u16* __restrict__ Qr, const u16* __restrict__ Kr,
    const u16* __restrict__ vh_,
    const float* __restrict__ lnw, const float* __restrict__ lnb,
    u16* __restrict__ Y) {
  // LDS: Ks 17408 | Vs 9472 | Psh 18432 = 45312 B; Rs (33280) overlays SM base.
  __shared__ __align__(16) char SM[17408 + 9472 + 18432];
  u16*   Ks  = (u16*)SM;
  u16*   Vs  = (u16*)(SM + 17408);
  u16*   Psh = (u16*)(SM + 17408 + 9472);
  float* Rs  = (float*)SM;  // overlays everything after kt loop
  __shared__ float mus[128], rstds[128];

  const int tid = threadIdx.x;
  const int bh = blockIdx.y, b = bh >> 4, h = bh & 15;
  const int qt = (int)gridDim.x - 1 - (int)blockIdx.x;  // heavy tiles first
  const int qbase = qt * 128;
  const int wid = tid >> 6, lane = tid & 63, lr = lane & 15, lg = lane >> 4;
  const int qg = qbase + wid * 16;  // this wave's first q row
  const float lg2g = log2f(1.0f - exp2f(-5.0f - (float)h));

  // ---- prologue: stage Q' in two 64-row halves through Ks, read A-fragments ----
  u16x8 qa[4];
  stage_tile(Qr, bh, qbase, tid, Ks);
  __syncthreads();
  if (wid < 4) {
#pragma unroll
    for (int dc = 0; dc < 4; dc++)
      qa[dc] = *reinterpret_cast<const u16x8*>(&Ks[(wid * 16 + lr) * LDK + dc * 32 + 8 * lg]);
  }
  __syncthreads();
  stage_tile(Qr, bh, qbase + 64, tid, Ks);
  __syncthreads();
  if (wid >= 4) {
#pragma unroll
    for (int dc = 0; dc < 4; dc++)
      qa[dc] = *reinterpret_cast<const u16x8*>(&Ks[((wid - 4) * 16 + lr) * LDK + dc * 32 + 8 * lg]);
  }

  const f32x4 fz = {0.f, 0.f, 0.f, 0.f};
  f32x4 oacc[4];
#pragma unroll
  for (int j = 0; j < 4; j++) oacc[j] = fz;

  const int ntiles = 2 * qt + 2;
  for (int kt = 0; kt < ntiles; ++kt) {
    const int t0 = kt * 64;
    const bool active = (t0 <= qg + 15);  // wave-uniform
    __syncthreads();  // prior tile's Ks/Vs/Psh reads done
    stage_tile(Kr, bh, t0, tid, Ks);
    {
      int tl = tid >> 3, j0 = (tid & 7) * 8;
      u16x8 v8 = *reinterpret_cast<const u16x8*>(&vh_[((size_t)bh * 2048 + t0 + tl) * 64 + j0]);
#pragma unroll
      for (int e = 0; e < 8; e++) Vs[tl * LDVS + j0 + e] = v8[e];
    }
    __syncthreads();

    if (active) {
      // ---- QK^T: D rows = q (4*lg+i), cols = t (lr); P stored fp16 (same bits as before) ----
#pragma unroll
      for (int tn = 0; tn < 4; tn++) {
        f32x4 st = fz;
#pragma unroll
        for (int dc = 0; dc < 4; dc++) {
          u16x8 kb = *reinterpret_cast<const u16x8*>(&Ks[(tn * 16 + lr) * LDK + dc * 32 + 8 * lg]);
          st = mfma16h(qa[dc], kb, st);
        }
        const int t = t0 + tn * 16 + lr;
#pragma unroll
        for (int i = 0; i < 4; i++) {
          int q = qg + 4 * lg + i;
          float v = st[i];
          v = (t <= q) ? v * exp2f((float)(q - t) * lg2g) : 0.f;
          Psh[(wid * 16 + 4 * lg + i) * LDPh + tn * 16 + lr] = f2h(v);
        }
      }
      // ---- wave-local fence: P rows wid*16..wid*16+15 are written and read by THIS wave only.
      // __syncthreads() not needed; we need the LDS writes drained + no compiler reordering (R7 lesson).
      asm volatile("s_waitcnt lgkmcnt(0)" ::: "memory");
      __builtin_amdgcn_sched_barrier(0);
      // ---- PV MFMA: A = P fp16 (GEMM af pattern, u16x8), B = V row-major scalar reads ----
#pragma unroll
      for (int c2 = 0; c2 < 2; c2++) {
        u16x8 pa = *reinterpret_cast<const u16x8*>(&Psh[(wid * 16 + lr) * LDPh + c2 * 32 + 8 * lg]);
#pragma unroll
        for (int jn = 0; jn < 4; jn++) {
          u16x8 vb;
#pragma unroll
          for (int e = 0; e < 8; e++)
            vb[e] = Vs[(c2 * 32 + 8 * lg + e) * LDVS + jn * 16 + lr];
          oacc[jn] = mfma16h(pa, vb, oacc[jn]);
        }
      }
    }
  }

  // ---- epilogue via LDS roundtrip (validated) ----
  __syncthreads();  // all Ks/Vs/Psh reads done before overlaying Rs
#pragma unroll
  for (int jn = 0; jn < 4; jn++)
#pragma unroll
    for (int i = 0; i < 4; i++)
      Rs[(wid * 16 + 4 * lg + i) * LDR + jn * 16 + lr] = oacc[jn][i];
  __syncthreads();
  if (tid < 128) {
    float s1 = 0.f, s2 = 0.f;
    for (int j = 0; j < 64; j++) { float v = Rs[tid * LDR + j]; s1 += v; s2 += v * v; }
    float mu = s1 * (1.f / 64.f);
    float var = s2 * (1.f / 64.f) - mu * mu;
    mus[tid] = mu; rstds[tid] = rsqrtf(var + 1e-5f);
  }
  __syncthreads();
  for (int p = tid; p < 8192; p += 512) {
    int sl = p >> 6, j = p & 63;
    float y = (Rs[sl * LDR + j] - mus[sl]) * rstds[sl] * lnw[j] + lnb[j];
    y = y / (1.f + expf(-y));
    Y[((size_t)b * 2048 + qbase + sl) * 1024 + h * 64 + j] = f2h(y);
  }
}

// ---------------- f32 patch for rows s < SP, from rotated hi+lo (validated) ----------------
#define SP 32
__global__ __launch_bounds__(256) void k_patch(
    const u16* __restrict__ Qr, const u16* __restrict__ qlo,
    const u16* __restrict__ Kr, const u16* __restrict__ klo,
    const u16* __restrict__ vh_,
    const float* __restrict__ lnw, const float* __restrict__ lnb,
    u16* __restrict__ Y) {
  const int bh = blockIdx.x, b = bh >> 4, h = bh & 15;
  __shared__ float qs[SP][132], ks[SP][132];
  __shared__ float vs[SP][64], rs[SP][64];
  __shared__ float ps[SP][SP];
  __shared__ float mus[SP], rstds[SP];
  const int tid = threadIdx.x;
  const float lg2g = log2f(1.0f - exp2f(-5.0f - (float)h));

  for (int p = tid; p < SP * 128; p += 256) {
    int s = p >> 7, d = p & 127;
    size_t oh = ((size_t)bh * 2048 + s) * 128 + d;
    size_t ol = ((size_t)bh * 32 + s) * 128 + d;
    qs[s][d] = h2f(Qr[oh]) + h2f(qlo[ol]);
    ks[s][d] = h2f(Kr[oh]) + h2f(klo[ol]);
  }
  for (int p = tid; p < SP * 64; p += 256) {
    int s = p >> 6, d = p & 63;
    vs[s][d] = h2f(vh_[((size_t)bh * 2048 + s) * 64 + d]);
  }
  __syncthreads();
  for (int p = tid; p < SP * SP; p += 256) {
    int s = p / SP, t = p % SP;
    float sc = 0.f;
    if (t <= s) {
      for (int d = 0; d < 128; d += 4) {
        float4 q4 = *reinterpret_cast<const float4*>(&qs[s][d]);
        float4 k4 = *reinterpret_cast<const float4*>(&ks[t][d]);
        sc += q4.x * k4.x + q4.y * k4.y + q4.z * k4.z + q4.w * k4.w;
      }
      sc *= exp2f((float)(s - t) * lg2g);
    }
    ps[s][t] = sc;
  }
  __syncthreads();
  for (int p = tid; p < SP * 64; p += 256) {
    int s = p >> 6, j = p & 63;
    float r = 0.f;
    for (int t = 0; t <= s; t++) r += ps[s][t] * vs[t][j];
    rs[s][j] = r;
  }
  __syncthreads();
  if (tid < SP) {
    float s1 = 0.f, s2 = 0.f;
    for (int j = 0; j < 64; j++) { float v = rs[tid][j]; s1 += v; s2 += v * v; }
    float mu = s1 * (1.f / 64.f);
    float var = s2 * (1.f / 64.f) - mu * mu;
    mus[tid] = mu; rstds[tid] = rsqrtf(var + 1e-5f);
  }
  __syncthreads();
  for (int p = tid; p < SP * 64; p += 256) {
    int s = p >> 6, j = p & 63;
    float y = (rs[s][j] - mus[s]) * rstds[s] * lnw[j] + lnb[j];
    y = y / (1.f + expf(-y));
    Y[((size_t)b * 2048 + s) * 1024 + h * 64 + j] = f2h(y);
  }
}

extern "C" void kernel_launch(void* const* d_in, const int* in_sizes, int n_in,
                              void* d_out, int out_size, void* d_ws, size_t ws_size,
                              hipStream_t stream) {
  const float* x   = (const float*)d_in[0];
  const float* Wq  = (const float*)d_in[1];
  const float* Wk  = (const float*)d_in[2];
  const float* Wv  = (const float*)d_in[3];
  const float* Wo  = (const float*)d_in[4];
  const float* lnw = (const float*)d_in[5];
  const float* lnb = (const float*)d_in[6];
  float* out = (float*)d_out;

  char* ws = (char*)d_ws;
  u16*   Qr   = (u16*)(ws + 0);            // [BH][S][128] rotated fp16, 32 MB
  u16*   Kr   = (u16*)(ws + 33554432);     // 32 MB
  u16*   vh   = (u16*)(ws + 67108864);     // [BH][S][64] fp16, 16 MB
  u16*   Y    = (u16*)(ws + 83886080);     // [B*S][D] fp16, 16 MB
  float* cosT = (float*)(ws + 100663296);  // [S][64] f32
  float* sinT = (float*)(ws + 101187584);
  u16*   qlo  = (u16*)(ws + 101711872);    // [BH][32][128] fp16 lo-residual
  u16*   klo  = (u16*)(ws + 102236160);

  k_trig<<<512, 256, 0, stream>>>(cosT, sinT);

  dim3 gg(8, 64);  // N/128, M/128
  k_gemm_split<0><<<gg, 256, 0, stream>>>(x, Wq, 8192, 1024, 1024, Qr, qlo, cosT, sinT);
  k_gemm_split<0><<<gg, 256, 0, stream>>>(x, Wk, 8192, 1024, 1024, Kr, klo, cosT, sinT);
  k_gemm_split<2><<<gg, 256, 0, stream>>>(x, Wv, 8192, 1024, 1024, vh, nullptr, nullptr, nullptr);

  k_retention<<<dim3(16, 64), 512, 0, stream>>>(Qr, Kr, vh, lnw, lnb, Y);

  k_patch<<<64, 256, 0, stream>>>(Qr, qlo, Kr, klo, vh, lnw, lnb, Y);

  k_gemm_out<<<gg, 256, 0, stream>>>(Y, Wo, 8192, 1024, 1024, out);
}

// Round 15
// 434.686 us; speedup vs baseline: 9.7585x; 1.0521x over previous
//
#include <hip/hip_runtime.h>

typedef unsigned short u16;
typedef _Float16 f16;
typedef _Float16 f16x8 __attribute__((ext_vector_type(8)));
typedef float f32x4 __attribute__((ext_vector_type(4)));
typedef unsigned short u16x8 __attribute__((ext_vector_type(8)));

static __device__ __forceinline__ u16 f2h(float f) {
  f16 h = (f16)f;
  return __builtin_bit_cast(u16, h);
}
static __device__ __forceinline__ float h2f(u16 h) {
  return (float)__builtin_bit_cast(f16, h);
}

static __device__ __forceinline__ f32x4 mfma16h(u16x8 a, u16x8 b, f32x4 c) {
  return __builtin_amdgcn_mfma_f32_16x16x32_f16(
      __builtin_bit_cast(f16x8, a), __builtin_bit_cast(f16x8, b), c, 0, 0, 0);
}

// ---------------- cos/sin tables [S][64], f64-accurate ----------------
__global__ void k_trig(float* __restrict__ cosT, float* __restrict__ sinT) {
  int idx = blockIdx.x * blockDim.x + threadIdx.x;  // S*64 threads
  int s = idx >> 6, j = idx & 63;
  double theta = exp2(-0.4152410118609203 * (double)j);  // 10000^(-j/32), f64
  double ang = (double)s * theta;
  cosT[idx] = (float)cos(ang);
  sinT[idx] = (float)sin(ang);
}

// ---------------- split-fp16 TN GEMM (validated structure) ----------------
// MODE 0: 3-pass Dekker; epilogue ROTATES and scatters fp16 to [BH][S][128];
//         lo-residual of rotated values stored for s<32 rows into loB [BH][32][128].
// MODE 2: single-pass; scatter hi to [BH][S][64] (V).
template <int MODE>
__global__ __launch_bounds__(256) void k_gemm_split(
    const float* __restrict__ A, const float* __restrict__ Bw,
    int M, int N, int K,
    u16* __restrict__ outH, u16* __restrict__ loB,
    const float* __restrict__ cosT, const float* __restrict__ sinT) {
  constexpr int LDT = 40;
  __shared__ __align__(16) u16 Ash[128 * LDT];
  __shared__ __align__(16) u16 Asl[128 * LDT];
  __shared__ __align__(16) u16 Bsh[128 * LDT];
  __shared__ __align__(16) u16 Bsl[128 * LDT];
  const int tid = threadIdx.x;
  const int m0 = blockIdx.y * 128;
  const int n0 = blockIdx.x * 128;
  const int lane = tid & 63, lr = lane & 15, lg = lane >> 4;
  const int wid = tid >> 6;
  const int wm = (wid >> 1) * 64, wn = (wid & 1) * 64;

  const f32x4 fz = {0.f, 0.f, 0.f, 0.f};
  f32x4 acc[4][4];
#pragma unroll
  for (int i = 0; i < 4; i++)
#pragma unroll
    for (int j = 0; j < 4; j++) acc[i][j] = fz;

  for (int k0 = 0; k0 < K; k0 += 32) {
    __syncthreads();
#pragma unroll
    for (int p = 0; p < 4; p++) {
      int c = p * 256 + tid;
      int row = c >> 3, col = (c & 7) * 4;
      float4 av = *reinterpret_cast<const float4*>(&A[(size_t)(m0 + row) * K + k0 + col]);
      float4 bv = *reinterpret_cast<const float4*>(&Bw[(size_t)(n0 + row) * K + k0 + col]);
      const float* ap = reinterpret_cast<const float*>(&av);
      const float* bp = reinterpret_cast<const float*>(&bv);
#pragma unroll
      for (int e = 0; e < 4; e++) {
        u16 h = f2h(ap[e]);
        Ash[row * LDT + col + e] = h;
        if constexpr (MODE == 0) Asl[row * LDT + col + e] = f2h(ap[e] - h2f(h));
        u16 hb = f2h(bp[e]);
        Bsh[row * LDT + col + e] = hb;
        if constexpr (MODE == 0) Bsl[row * LDT + col + e] = f2h(bp[e] - h2f(hb));
      }
    }
    __syncthreads();
    u16x8 ah[4], al[4], bh[4], bl[4];
#pragma unroll
    for (int i = 0; i < 4; i++) {
      ah[i] = *reinterpret_cast<const u16x8*>(&Ash[(wm + i * 16 + lr) * LDT + 8 * lg]);
      if constexpr (MODE == 0)
        al[i] = *reinterpret_cast<const u16x8*>(&Asl[(wm + i * 16 + lr) * LDT + 8 * lg]);
    }
#pragma unroll
    for (int j = 0; j < 4; j++) {
      bh[j] = *reinterpret_cast<const u16x8*>(&Bsh[(wn + j * 16 + lr) * LDT + 8 * lg]);
      if constexpr (MODE == 0)
        bl[j] = *reinterpret_cast<const u16x8*>(&Bsl[(wn + j * 16 + lr) * LDT + 8 * lg]);
    }
#pragma unroll
    for (int i = 0; i < 4; i++)
#pragma unroll
      for (int j = 0; j < 4; j++) {
        acc[i][j] = mfma16h(ah[i], bh[j], acc[i][j]);
        if constexpr (MODE == 0) {
          acc[i][j] = mfma16h(ah[i], bl[j], acc[i][j]);
          acc[i][j] = mfma16h(al[i], bh[j], acc[i][j]);
        }
      }
  }

#pragma unroll
  for (int i = 0; i < 4; i++)
#pragma unroll
    for (int j = 0; j < 4; j++)
#pragma unroll
      for (int r = 0; r < 4; r++) {
        int m = m0 + wm + i * 16 + 4 * lg + r;
        int n = n0 + wn + j * 16 + lr;
        float v = acc[i][j][r];
        int b = m >> 11, s = m & 2047;  // S = 2048
        int h = n >> 6, jj = n & 63;
        if constexpr (MODE == 2) {
          outH[(((size_t)(b * 16 + h)) * 2048 + s) * 64 + jj] = f2h(v);
        } else {
          float cv = cosT[s * 64 + jj], sv = sinT[s * 64 + jj];
          float a = v * cv, bb = v * sv;
          size_t o = (((size_t)(b * 16 + h)) * 2048 + s) * 128 + jj;
          u16 ahh = f2h(a), bhh = f2h(bb);
          outH[o] = ahh;
          outH[o + 64] = bhh;
          if (s < 32) {
            size_t ol = (((size_t)(b * 16 + h)) * 32 + s) * 128 + jj;
            loB[ol] = f2h(a - h2f(ahh));
            loB[ol + 64] = f2h(bb - h2f(bhh));
          }
        }
      }
}

// ---------------- single-pass fp16 GEMM for out = Y @ Wo^T (validated) ----------------
__global__ __launch_bounds__(256) void k_gemm_out(
    const u16* __restrict__ A, const float* __restrict__ Bw,
    int M, int N, int K, float* __restrict__ outF) {
  constexpr int LDT = 40;
  __shared__ __align__(16) u16 As[128 * LDT];
  __shared__ __align__(16) u16 Bs[128 * LDT];
  const int tid = threadIdx.x;
  const int m0 = blockIdx.y * 128;
  const int n0 = blockIdx.x * 128;
  const int lane = tid & 63, lr = lane & 15, lg = lane >> 4;
  const int wid = tid >> 6;
  const int wm = (wid >> 1) * 64, wn = (wid & 1) * 64;

  const f32x4 fz = {0.f, 0.f, 0.f, 0.f};
  f32x4 acc[4][4];
#pragma unroll
  for (int i = 0; i < 4; i++)
#pragma unroll
    for (int j = 0; j < 4; j++) acc[i][j] = fz;

  for (int k0 = 0; k0 < K; k0 += 32) {
    __syncthreads();
#pragma unroll
    for (int p = 0; p < 2; p++) {
      int c = p * 256 + tid;
      int row = c >> 2, col = (c & 3) * 8;
      *reinterpret_cast<int4*>(&As[row * LDT + col]) =
          *reinterpret_cast<const int4*>(&A[(size_t)(m0 + row) * K + k0 + col]);
    }
#pragma unroll
    for (int p = 0; p < 4; p++) {
      int c = p * 256 + tid;
      int row = c >> 3, col = (c & 7) * 4;
      float4 bv = *reinterpret_cast<const float4*>(&Bw[(size_t)(n0 + row) * K + k0 + col]);
      const float* bp = reinterpret_cast<const float*>(&bv);
#pragma unroll
      for (int e = 0; e < 4; e++) Bs[row * LDT + col + e] = f2h(bp[e]);
    }
    __syncthreads();
    u16x8 af[4], bf[4];
#pragma unroll
    for (int i = 0; i < 4; i++)
      af[i] = *reinterpret_cast<const u16x8*>(&As[(wm + i * 16 + lr) * LDT + 8 * lg]);
#pragma unroll
    for (int j = 0; j < 4; j++)
      bf[j] = *reinterpret_cast<const u16x8*>(&Bs[(wn + j * 16 + lr) * LDT + 8 * lg]);
#pragma unroll
    for (int i = 0; i < 4; i++)
#pragma unroll
      for (int j = 0; j < 4; j++) acc[i][j] = mfma16h(af[i], bf[j], acc[i][j]);
  }

#pragma unroll
  for (int i = 0; i < 4; i++)
#pragma unroll
    for (int j = 0; j < 4; j++)
#pragma unroll
      for (int r = 0; r < 4; r++) {
        int m = m0 + wm + i * 16 + 4 * lg + r;
        int n = n0 + wn + j * 16 + lr;
        outF[(size_t)m * N + n] = acc[i][j][r];
      }
}

// ---------------- V transpose: vh [BH][S][64] -> VT [BH][64][S] ----------------
__global__ __launch_bounds__(256) void k_vt(const u16* __restrict__ vh,
                                            u16* __restrict__ VT) {
  __shared__ u16 T[64][72];
  const int tid = threadIdx.x;
  const int bh = blockIdx.y, s0 = blockIdx.x * 64;
#pragma unroll
  for (int p = 0; p < 2; p++) {
    int c = p * 256 + tid;
    int r = c >> 3, j0 = (c & 7) * 8;
    *reinterpret_cast<u16x8*>(&T[r][j0]) =
        *reinterpret_cast<const u16x8*>(&vh[((size_t)bh * 2048 + s0 + r) * 64 + j0]);
  }
  __syncthreads();
#pragma unroll
  for (int p = 0; p < 2; p++) {
    int c = p * 256 + tid;
    int j = c >> 3, r0 = (c & 7) * 8;
    u16x8 o;
#pragma unroll
    for (int e = 0; e < 8; e++) o[e] = T[r0 + e][j];
    *reinterpret_cast<u16x8*>(&VT[((size_t)bh * 64 + j) * 2048 + s0 + r0]) = o;
  }
}

// ---------------- retention: QBLK=128, fp16 P, transposed-V LDS (vector B reads) ----------------
constexpr int LDK = 136;   // u16 stride, rotated Q'/K' tile [64][128]
constexpr int LDPh = 72;   // u16 stride, P tile fp16 [128 q][64 t]
constexpr int LDVT = 72;   // u16 stride, V^T tile [64 j][64 t] (rows 144B: 16B-aligned, reads 2-way free)
constexpr int LDR = 65;    // f32 stride, O tile [128 q][64 j]

// stage a [64][128] fp16 tile via pure int4 copies, 512 threads (2 chunks each)
static __device__ __forceinline__ void stage_tile(
    const u16* __restrict__ src, int bh, int r0, int tid, u16* Ks) {
#pragma unroll
  for (int p = 0; p < 2; p++) {
    int c = p * 512 + tid;  // 1024 16B-chunks
    int row = c >> 4, col = (c & 15) * 8;
    *reinterpret_cast<int4*>(&Ks[row * LDK + col]) =
        *reinterpret_cast<const int4*>(&src[((size_t)bh * 2048 + r0 + row) * 128 + col]);
  }
}

__global__ __launch_bounds__(512) void k_retention(
    const u16* __restrict__ Qr, const u16* __restrict__ Kr,
    const u16* __restrict__ VT_,
    const float* __restrict__ lnw, const float* __restrict__ lnb,
    u16* __restrict__ Y) {
  // LDS: Ks 17408 | Vt 9216 | Psh 18432 = 45056 B; Rs (33280) overlays SM base.
  __shared__ __align__(16) char SM[17408 + 9216 + 18432];
  u16*   Ks  = (u16*)SM;
  u16*   Vt  = (u16*)(SM + 17408);
  u16*   Psh = (u16*)(SM + 17408 + 9216);
  float* Rs  = (float*)SM;  // overlays everything after kt loop
  __shared__ float mus[128], rstds[128];

  const int tid = threadIdx.x;
  const int bh = blockIdx.y, b = bh >> 4, h = bh & 15;
  const int qt = (int)gridDim.x - 1 - (int)blockIdx.x;  // heavy tiles first
  const int qbase = qt * 128;
  const int wid = tid >> 6, lane = tid & 63, lr = lane & 15, lg = lane >> 4;
  const int qg = qbase + wid * 16;  // this wave's first q row
  const float lg2g = log2f(1.0f - exp2f(-5.0f - (float)h));

  // ---- prologue: stage Q' in two 64-row halves through Ks, read A-fragments ----
  u16x8 qa[4];
  stage_tile(Qr, bh, qbase, tid, Ks);
  __syncthreads();
  if (wid < 4) {
#pragma unroll
    for (int dc = 0; dc < 4; dc++)
      qa[dc] = *reinterpret_cast<const u16x8*>(&Ks[(wid * 16 + lr) * LDK + dc * 32 + 8 * lg]);
  }
  __syncthreads();
  stage_tile(Qr, bh, qbase + 64, tid, Ks);
  __syncthreads();
  if (wid >= 4) {
#pragma unroll
    for (int dc = 0; dc < 4; dc++)
      qa[dc] = *reinterpret_cast<const u16x8*>(&Ks[((wid - 4) * 16 + lr) * LDK + dc * 32 + 8 * lg]);
  }

  const f32x4 fz = {0.f, 0.f, 0.f, 0.f};
  f32x4 oacc[4];
#pragma unroll
  for (int j = 0; j < 4; j++) oacc[j] = fz;

  const int ntiles = 2 * qt + 2;
  for (int kt = 0; kt < ntiles; ++kt) {
    const int t0 = kt * 64;
    const bool active = (t0 <= qg + 15);  // wave-uniform
    __syncthreads();  // prior tile's Ks/Vt/Psh reads done
    stage_tile(Kr, bh, t0, tid, Ks);
    // stage V^T tile [64 j][64 t]: 512 contiguous u16x8 copies (no scalar writes)
    {
      int j = tid >> 3, tl0 = (tid & 7) * 8;
      *reinterpret_cast<u16x8*>(&Vt[j * LDVT + tl0]) =
          *reinterpret_cast<const u16x8*>(&VT_[((size_t)bh * 64 + j) * 2048 + t0 + tl0]);
    }
    __syncthreads();

    if (active) {
      // ---- QK^T: D rows = q (4*lg+i), cols = t (lr); P stored fp16 ----
#pragma unroll
      for (int tn = 0; tn < 4; tn++) {
        f32x4 st = fz;
#pragma unroll
        for (int dc = 0; dc < 4; dc++) {
          u16x8 kb = *reinterpret_cast<const u16x8*>(&Ks[(tn * 16 + lr) * LDK + dc * 32 + 8 * lg]);
          st = mfma16h(qa[dc], kb, st);
        }
        const int t = t0 + tn * 16 + lr;
#pragma unroll
        for (int i = 0; i < 4; i++) {
          int q = qg + 4 * lg + i;
          float v = st[i];
          v = (t <= q) ? v * exp2f((float)(q - t) * lg2g) : 0.f;
          Psh[(wid * 16 + 4 * lg + i) * LDPh + tn * 16 + lr] = f2h(v);
        }
      }
      // wave-local fence (R13-validated): drain LDS writes + block compiler reordering
      asm volatile("s_waitcnt lgkmcnt(0)" ::: "memory");
      __builtin_amdgcn_sched_barrier(0);
      // ---- PV MFMA: A = P fp16 (af pattern), B = V^T vector reads (same bits/lanes as R14) ----
#pragma unroll
      for (int c2 = 0; c2 < 2; c2++) {
        u16x8 pa = *reinterpret_cast<const u16x8*>(&Psh[(wid * 16 + lr) * LDPh + c2 * 32 + 8 * lg]);
#pragma unroll
        for (int jn = 0; jn < 4; jn++) {
          u16x8 vb = *reinterpret_cast<const u16x8*>(&Vt[(jn * 16 + lr) * LDVT + c2 * 32 + 8 * lg]);
          oacc[jn] = mfma16h(pa, vb, oacc[jn]);
        }
      }
    }
  }

  // ---- epilogue via LDS roundtrip (validated) ----
  __syncthreads();  // all Ks/Vt/Psh reads done before overlaying Rs
#pragma unroll
  for (int jn = 0; jn < 4; jn++)
#pragma unroll
    for (int i = 0; i < 4; i++)
      Rs[(wid * 16 + 4 * lg + i) * LDR + jn * 16 + lr] = oacc[jn][i];
  __syncthreads();
  if (tid < 128) {
    float s1 = 0.f, s2 = 0.f;
    for (int j = 0; j < 64; j++) { float v = Rs[tid * LDR + j]; s1 += v; s2 += v * v; }
    float mu = s1 * (1.f / 64.f);
    float var = s2 * (1.f / 64.f) - mu * mu;
    mus[tid] = mu; rstds[tid] = rsqrtf(var + 1e-5f);
  }
  __syncthreads();
  for (int p = tid; p < 8192; p += 512) {
    int sl = p >> 6, j = p & 63;
    float y = (Rs[sl * LDR + j] - mus[sl]) * rstds[sl] * lnw[j] + lnb[j];
    y = y / (1.f + expf(-y));
    Y[((size_t)b * 2048 + qbase + sl) * 1024 + h * 64 + j] = f2h(y);
  }
}

// ---------------- f32 patch for rows s < SP, from rotated hi+lo (validated) ----------------
#define SP 32
__global__ __launch_bounds__(256) void k_patch(
    const u16* __restrict__ Qr, const u16* __restrict__ qlo,
    const u16* __restrict__ Kr, const u16* __restrict__ klo,
    const u16* __restrict__ vh_,
    const float* __restrict__ lnw, const float* __restrict__ lnb,
    u16* __restrict__ Y) {
  const int bh = blockIdx.x, b = bh >> 4, h = bh & 15;
  __shared__ float qs[SP][132], ks[SP][132];
  __shared__ float vs[SP][64], rs[SP][64];
  __shared__ float ps[SP][SP];
  __shared__ float mus[SP], rstds[SP];
  const int tid = threadIdx.x;
  const float lg2g = log2f(1.0f - exp2f(-5.0f - (float)h));

  for (int p = tid; p < SP * 128; p += 256) {
    int s = p >> 7, d = p & 127;
    size_t oh = ((size_t)bh * 2048 + s) * 128 + d;
    size_t ol = ((size_t)bh * 32 + s) * 128 + d;
    qs[s][d] = h2f(Qr[oh]) + h2f(qlo[ol]);
    ks[s][d] = h2f(Kr[oh]) + h2f(klo[ol]);
  }
  for (int p = tid; p < SP * 64; p += 256) {
    int s = p >> 6, d = p & 63;
    vs[s][d] = h2f(vh_[((size_t)bh * 2048 + s) * 64 + d]);
  }
  __syncthreads();
  for (int p = tid; p < SP * SP; p += 256) {
    int s = p / SP, t = p % SP;
    float sc = 0.f;
    if (t <= s) {
      for (int d = 0; d < 128; d += 4) {
        float4 q4 = *reinterpret_cast<const float4*>(&qs[s][d]);
        float4 k4 = *reinterpret_cast<const float4*>(&ks[t][d]);
        sc += q4.x * k4.x + q4.y * k4.y + q4.z * k4.z + q4.w * k4.w;
      }
      sc *= exp2f((float)(s - t) * lg2g);
    }
    ps[s][t] = sc;
  }
  __syncthreads();
  for (int p = tid; p < SP * 64; p += 256) {
    int s = p >> 6, j = p & 63;
    float r = 0.f;
    for (int t = 0; t <= s; t++) r += ps[s][t] * vs[t][j];
    rs[s][j] = r;
  }
  __syncthreads();
  if (tid < SP) {
    float s1 = 0.f, s2 = 0.f;
    for (int j = 0; j < 64; j++) { float v = rs[tid][j]; s1 += v; s2 += v * v; }
    float mu = s1 * (1.f / 64.f);
    float var = s2 * (1.f / 64.f) - mu * mu;
    mus[tid] = mu; rstds[tid] = rsqrtf(var + 1e-5f);
  }
  __syncthreads();
  for (int p = tid; p < SP * 64; p += 256) {
    int s = p >> 6, j = p & 63;
    float y = (rs[s][j] - mus[s]) * rstds[s] * lnw[j] + lnb[j];
    y = y / (1.f + expf(-y));
    Y[((size_t)b * 2048 + s) * 1024 + h * 64 + j] = f2h(y);
  }
}

extern "C" void kernel_launch(void* const* d_in, const int* in_sizes, int n_in,
                              void* d_out, int out_size, void* d_ws, size_t ws_size,
                              hipStream_t stream) {
  const float* x   = (const float*)d_in[0];
  const float* Wq  = (const float*)d_in[1];
  const float* Wk  = (const float*)d_in[2];
  const float* Wv  = (const float*)d_in[3];
  const float* Wo  = (const float*)d_in[4];
  const float* lnw = (const float*)d_in[5];
  const float* lnb = (const float*)d_in[6];
  float* out = (float*)d_out;

  char* ws = (char*)d_ws;
  u16*   Qr   = (u16*)(ws + 0);            // [BH][S][128] rotated fp16, 32 MB
  u16*   Kr   = (u16*)(ws + 33554432);     // 32 MB
  u16*   vh   = (u16*)(ws + 67108864);     // [BH][S][64] fp16, 16 MB
  u16*   Y    = (u16*)(ws + 83886080);     // [B*S][D] fp16, 16 MB
  float* cosT = (float*)(ws + 100663296);  // [S][64] f32
  float* sinT = (float*)(ws + 101187584);
  u16*   qlo  = (u16*)(ws + 101711872);    // [BH][32][128] fp16 lo-residual
  u16*   klo  = (u16*)(ws + 102236160);
  u16*   VT   = (u16*)(ws + 102760448);    // [BH][64][S] fp16, 16 MB
  // total 119,537,664 B

  k_trig<<<512, 256, 0, stream>>>(cosT, sinT);

  dim3 gg(8, 64);  // N/128, M/128
  k_gemm_split<0><<<gg, 256, 0, stream>>>(x, Wq, 8192, 1024, 1024, Qr, qlo, cosT, sinT);
  k_gemm_split<0><<<gg, 256, 0, stream>>>(x, Wk, 8192, 1024, 1024, Kr, klo, cosT, sinT);
  k_gemm_split<2><<<gg, 256, 0, stream>>>(x, Wv, 8192, 1024, 1024, vh, nullptr, nullptr, nullptr);

  k_vt<<<dim3(32, 64), 256, 0, stream>>>(vh, VT);

  k_retention<<<dim3(16, 64), 512, 0, stream>>>(Qr, Kr, VT, lnw, lnb, Y);

  k_patch<<<64, 256, 0, stream>>>(Qr, qlo, Kr, klo, vh, lnw, lnb, Y);

  k_gemm_out<<<gg, 256, 0, stream>>>(Y, Wo, 8192, 1024, 1024, out);
}

// Round 16
// 432.941 us; speedup vs baseline: 9.7979x; 1.0040x over previous
//
#include <hip/hip_runtime.h>

typedef unsigned short u16;
typedef _Float16 f16;
typedef _Float16 f16x8 __attribute__((ext_vector_type(8)));
typedef float f32x4 __attribute__((ext_vector_type(4)));
typedef unsigned short u16x8 __attribute__((ext_vector_type(8)));
typedef unsigned short u16x4 __attribute__((ext_vector_type(4)));

static __device__ __forceinline__ u16 f2h(float f) {
  f16 h = (f16)f;
  return __builtin_bit_cast(u16, h);
}
static __device__ __forceinline__ float h2f(u16 h) {
  return (float)__builtin_bit_cast(f16, h);
}

static __device__ __forceinline__ f32x4 mfma16h(u16x8 a, u16x8 b, f32x4 c) {
  return __builtin_amdgcn_mfma_f32_16x16x32_f16(
      __builtin_bit_cast(f16x8, a), __builtin_bit_cast(f16x8, b), c, 0, 0, 0);
}

// ---------------- cos/sin tables [S][64], f64-accurate ----------------
__global__ void k_trig(float* __restrict__ cosT, float* __restrict__ sinT) {
  int idx = blockIdx.x * blockDim.x + threadIdx.x;  // S*64 threads
  int s = idx >> 6, j = idx & 63;
  double theta = exp2(-0.4152410118609203 * (double)j);  // 10000^(-j/32), f64
  double ang = (double)s * theta;
  cosT[idx] = (float)cos(ang);
  sinT[idx] = (float)sin(ang);
}

// ---------------- f32 -> fp16 hi/lo Dekker pre-split (bit-identical to in-kernel split) ----------------
__global__ void k_split(const float* __restrict__ src, u16* __restrict__ hi,
                        u16* __restrict__ lo, int n) {
  int i = (blockIdx.x * blockDim.x + threadIdx.x) * 4;
  if (i >= n) return;
  float4 v = *reinterpret_cast<const float4*>(src + i);
  const float* vp = reinterpret_cast<const float*>(&v);
  u16x4 hv, lv;
#pragma unroll
  for (int e = 0; e < 4; e++) {
    hv[e] = f2h(vp[e]);
    lv[e] = f2h(vp[e] - h2f(hv[e]));
  }
  *reinterpret_cast<u16x4*>(hi + i) = hv;
  *reinterpret_cast<u16x4*>(lo + i) = lv;
}

// ---------------- TN GEMM, pre-split fp16 A; B f32 converted in-stage ----------------
// MODE 0: 3-pass Dekker (A hi/lo, B hi/lo); epilogue rotates, scatters [BH][S][128] + lo (s<32)
// MODE 2: single-pass (A hi, B hi); scatter [BH][S][64] (V)
// MODE 3: single-pass; outF f32 row-major (out-GEMM, A = Y fp16)
template <int MODE>
__global__ __launch_bounds__(256) void k_gemm16(
    const u16* __restrict__ Ah_, const u16* __restrict__ Al_,
    const float* __restrict__ Bw,
    int M, int N, int K,
    u16* __restrict__ outH, u16* __restrict__ loB, float* __restrict__ outF,
    const float* __restrict__ cosT, const float* __restrict__ sinT) {
  constexpr int LDT = 40;
  __shared__ __align__(16) u16 Ash[128 * LDT];
  __shared__ __align__(16) u16 Asl[128 * LDT];
  __shared__ __align__(16) u16 Bsh[128 * LDT];
  __shared__ __align__(16) u16 Bsl[128 * LDT];
  const int tid = threadIdx.x;
  const int m0 = blockIdx.y * 128;
  const int n0 = blockIdx.x * 128;
  const int lane = tid & 63, lr = lane & 15, lg = lane >> 4;
  const int wid = tid >> 6;
  const int wm = (wid >> 1) * 64, wn = (wid & 1) * 64;

  const f32x4 fz = {0.f, 0.f, 0.f, 0.f};
  f32x4 acc[4][4];
#pragma unroll
  for (int i = 0; i < 4; i++)
#pragma unroll
    for (int j = 0; j < 4; j++) acc[i][j] = fz;

  for (int k0 = 0; k0 < K; k0 += 32) {
    __syncthreads();
    // A: pure int4 copies from pre-split hi (and lo for MODE 0)
#pragma unroll
    for (int p = 0; p < 2; p++) {
      int c = p * 256 + tid;
      int row = c >> 2, col = (c & 3) * 8;
      *reinterpret_cast<int4*>(&Ash[row * LDT + col]) =
          *reinterpret_cast<const int4*>(&Ah_[(size_t)(m0 + row) * K + k0 + col]);
      if constexpr (MODE == 0)
        *reinterpret_cast<int4*>(&Asl[row * LDT + col]) =
            *reinterpret_cast<const int4*>(&Al_[(size_t)(m0 + row) * K + k0 + col]);
    }
    // B: f32 -> fp16 hi (and lo), vectorized u16x4 LDS writes
#pragma unroll
    for (int p = 0; p < 4; p++) {
      int c = p * 256 + tid;
      int row = c >> 3, col = (c & 7) * 4;
      float4 bv = *reinterpret_cast<const float4*>(&Bw[(size_t)(n0 + row) * K + k0 + col]);
      const float* bp = reinterpret_cast<const float*>(&bv);
      u16x4 hv, lv;
#pragma unroll
      for (int e = 0; e < 4; e++) {
        hv[e] = f2h(bp[e]);
        if constexpr (MODE == 0) lv[e] = f2h(bp[e] - h2f(hv[e]));
      }
      *reinterpret_cast<u16x4*>(&Bsh[row * LDT + col]) = hv;
      if constexpr (MODE == 0) *reinterpret_cast<u16x4*>(&Bsl[row * LDT + col]) = lv;
    }
    __syncthreads();
    u16x8 ah[4], al[4], bh[4], bl[4];
#pragma unroll
    for (int i = 0; i < 4; i++) {
      ah[i] = *reinterpret_cast<const u16x8*>(&Ash[(wm + i * 16 + lr) * LDT + 8 * lg]);
      if constexpr (MODE == 0)
        al[i] = *reinterpret_cast<const u16x8*>(&Asl[(wm + i * 16 + lr) * LDT + 8 * lg]);
    }
#pragma unroll
    for (int j = 0; j < 4; j++) {
      bh[j] = *reinterpret_cast<const u16x8*>(&Bsh[(wn + j * 16 + lr) * LDT + 8 * lg]);
      if constexpr (MODE == 0)
        bl[j] = *reinterpret_cast<const u16x8*>(&Bsl[(wn + j * 16 + lr) * LDT + 8 * lg]);
    }
#pragma unroll
    for (int i = 0; i < 4; i++)
#pragma unroll
      for (int j = 0; j < 4; j++) {
        acc[i][j] = mfma16h(ah[i], bh[j], acc[i][j]);
        if constexpr (MODE == 0) {
          acc[i][j] = mfma16h(ah[i], bl[j], acc[i][j]);
          acc[i][j] = mfma16h(al[i], bh[j], acc[i][j]);
        }
      }
  }

#pragma unroll
  for (int i = 0; i < 4; i++)
#pragma unroll
    for (int j = 0; j < 4; j++)
#pragma unroll
      for (int r = 0; r < 4; r++) {
        int m = m0 + wm + i * 16 + 4 * lg + r;
        int n = n0 + wn + j * 16 + lr;
        float v = acc[i][j][r];
        if constexpr (MODE == 3) {
          outF[(size_t)m * N + n] = v;
        } else {
          int b = m >> 11, s = m & 2047;  // S = 2048
          int h = n >> 6, jj = n & 63;
          if constexpr (MODE == 2) {
            outH[(((size_t)(b * 16 + h)) * 2048 + s) * 64 + jj] = f2h(v);
          } else {
            float cv = cosT[s * 64 + jj], sv = sinT[s * 64 + jj];
            float a = v * cv, bb = v * sv;
            size_t o = (((size_t)(b * 16 + h)) * 2048 + s) * 128 + jj;
            u16 ahh = f2h(a), bhh = f2h(bb);
            outH[o] = ahh;
            outH[o + 64] = bhh;
            if (s < 32) {
              size_t ol = (((size_t)(b * 16 + h)) * 32 + s) * 128 + jj;
              loB[ol] = f2h(a - h2f(ahh));
              loB[ol + 64] = f2h(bb - h2f(bhh));
            }
          }
        }
      }
}

// ---------------- V transpose: vh [BH][S][64] -> VT [BH][64][S] (validated) ----------------
__global__ __launch_bounds__(256) void k_vt(const u16* __restrict__ vh,
                                            u16* __restrict__ VT) {
  __shared__ u16 T[64][72];
  const int tid = threadIdx.x;
  const int bh = blockIdx.y, s0 = blockIdx.x * 64;
#pragma unroll
  for (int p = 0; p < 2; p++) {
    int c = p * 256 + tid;
    int r = c >> 3, j0 = (c & 7) * 8;
    *reinterpret_cast<u16x8*>(&T[r][j0]) =
        *reinterpret_cast<const u16x8*>(&vh[((size_t)bh * 2048 + s0 + r) * 64 + j0]);
  }
  __syncthreads();
#pragma unroll
  for (int p = 0; p < 2; p++) {
    int c = p * 256 + tid;
    int j = c >> 3, r0 = (c & 7) * 8;
    u16x8 o;
#pragma unroll
    for (int e = 0; e < 8; e++) o[e] = T[r0 + e][j];
    *reinterpret_cast<u16x8*>(&VT[((size_t)bh * 64 + j) * 2048 + s0 + r0]) = o;
  }
}

// ---------------- retention: QBLK=128, fp16 P, V^T LDS, register double-buffered staging ----------------
constexpr int LDK = 136;   // u16 stride, rotated Q'/K' tile [64][128]
constexpr int LDPh = 72;   // u16 stride, P tile fp16 [128 q][64 t]
constexpr int LDVT = 72;   // u16 stride, V^T tile [64 j][64 t]
constexpr int LDR = 65;    // f32 stride, O tile [128 q][64 j]

// stage a [64][128] fp16 tile via pure int4 copies, 512 threads (2 chunks each)
static __device__ __forceinline__ void stage_tile(
    const u16* __restrict__ src, int bh, int r0, int tid, u16* Ks) {
#pragma unroll
  for (int p = 0; p < 2; p++) {
    int c = p * 512 + tid;
    int row = c >> 4, col = (c & 15) * 8;
    *reinterpret_cast<int4*>(&Ks[row * LDK + col]) =
        *reinterpret_cast<const int4*>(&src[((size_t)bh * 2048 + r0 + row) * 128 + col]);
  }
}

__global__ __launch_bounds__(512) void k_retention(
    const u16* __restrict__ Qr, const u16* __restrict__ Kr,
    const u16* __restrict__ VT_,
    const float* __restrict__ lnw, const float* __restrict__ lnb,
    u16* __restrict__ Y) {
  // LDS: Ks 17408 | Vt 9216 | Psh 18432 = 45056 B; Rs (33280) overlays SM base.
  __shared__ __align__(16) char SM[17408 + 9216 + 18432];
  u16*   Ks  = (u16*)SM;
  u16*   Vt  = (u16*)(SM + 17408);
  u16*   Psh = (u16*)(SM + 17408 + 9216);
  float* Rs  = (float*)SM;  // overlays everything after kt loop
  __shared__ float mus[128], rstds[128];

  const int tid = threadIdx.x;
  const int bh = blockIdx.y, b = bh >> 4, h = bh & 15;
  const int qt = (int)gridDim.x - 1 - (int)blockIdx.x;  // heavy tiles first
  const int qbase = qt * 128;
  const int wid = tid >> 6, lane = tid & 63, lr = lane & 15, lg = lane >> 4;
  const int qg = qbase + wid * 16;  // this wave's first q row
  const float lg2g = log2f(1.0f - exp2f(-5.0f - (float)h));

  // ---- prologue: stage Q' in two 64-row halves through Ks, read A-fragments ----
  u16x8 qa[4];
  stage_tile(Qr, bh, qbase, tid, Ks);
  __syncthreads();
  if (wid < 4) {
#pragma unroll
    for (int dc = 0; dc < 4; dc++)
      qa[dc] = *reinterpret_cast<const u16x8*>(&Ks[(wid * 16 + lr) * LDK + dc * 32 + 8 * lg]);
  }
  __syncthreads();
  stage_tile(Qr, bh, qbase + 64, tid, Ks);
  __syncthreads();
  if (wid >= 4) {
#pragma unroll
    for (int dc = 0; dc < 4; dc++)
      qa[dc] = *reinterpret_cast<const u16x8*>(&Ks[((wid - 4) * 16 + lr) * LDK + dc * 32 + 8 * lg]);
  }

  const f32x4 fz = {0.f, 0.f, 0.f, 0.f};
  f32x4 oacc[4];
#pragma unroll
  for (int j = 0; j < 4; j++) oacc[j] = fz;

  // ---- register double-buffer: K tile = 2 int4/thread, V^T tile = 1 int4/thread ----
  const int krow = tid >> 4, kcol = (tid & 15) * 8;  // chunks c=tid and c=512+tid (row+32)
  const int vj = tid >> 3, vt0 = (tid & 7) * 8;
  int4 kbuf0, kbuf1, vbuf;
  {
    const int t0 = 0;
    kbuf0 = *reinterpret_cast<const int4*>(&Kr[((size_t)bh * 2048 + t0 + krow) * 128 + kcol]);
    kbuf1 = *reinterpret_cast<const int4*>(&Kr[((size_t)bh * 2048 + t0 + 32 + krow) * 128 + kcol]);
    vbuf  = *reinterpret_cast<const int4*>(&VT_[((size_t)bh * 64 + vj) * 2048 + t0 + vt0]);
  }

  const int ntiles = 2 * qt + 2;
  for (int kt = 0; kt < ntiles; ++kt) {
    const int t0 = kt * 64;
    const bool active = (t0 <= qg + 15);  // wave-uniform
    __syncthreads();  // prior tile's Ks/Vt/Psh reads done (and prologue frag reads)
    // dump staged registers to LDS
    *reinterpret_cast<int4*>(&Ks[krow * LDK + kcol]) = kbuf0;
    *reinterpret_cast<int4*>(&Ks[(krow + 32) * LDK + kcol]) = kbuf1;
    *reinterpret_cast<int4*>(&Vt[vj * LDVT + vt0]) = vbuf;
    // issue next tile's loads (latency hides under this tile's compute)
    if (kt + 1 < ntiles) {
      const int t1 = t0 + 64;
      kbuf0 = *reinterpret_cast<const int4*>(&Kr[((size_t)bh * 2048 + t1 + krow) * 128 + kcol]);
      kbuf1 = *reinterpret_cast<const int4*>(&Kr[((size_t)bh * 2048 + t1 + 32 + krow) * 128 + kcol]);
      vbuf  = *reinterpret_cast<const int4*>(&VT_[((size_t)bh * 64 + vj) * 2048 + t1 + vt0]);
    }
    __syncthreads();

    if (active) {
      // ---- QK^T: D rows = q (4*lg+i), cols = t (lr); P stored fp16 ----
#pragma unroll
      for (int tn = 0; tn < 4; tn++) {
        f32x4 st = fz;
#pragma unroll
        for (int dc = 0; dc < 4; dc++) {
          u16x8 kb = *reinterpret_cast<const u16x8*>(&Ks[(tn * 16 + lr) * LDK + dc * 32 + 8 * lg]);
          st = mfma16h(qa[dc], kb, st);
        }
        const int t = t0 + tn * 16 + lr;
#pragma unroll
        for (int i = 0; i < 4; i++) {
          int q = qg + 4 * lg + i;
          float v = st[i];
          v = (t <= q) ? v * exp2f((float)(q - t) * lg2g) : 0.f;
          Psh[(wid * 16 + 4 * lg + i) * LDPh + tn * 16 + lr] = f2h(v);
        }
      }
      // wave-local fence (R13-validated)
      asm volatile("s_waitcnt lgkmcnt(0)" ::: "memory");
      __builtin_amdgcn_sched_barrier(0);
      // ---- PV MFMA: A = P fp16 (af pattern), B = V^T vector reads ----
#pragma unroll
      for (int c2 = 0; c2 < 2; c2++) {
        u16x8 pa = *reinterpret_cast<const u16x8*>(&Psh[(wid * 16 + lr) * LDPh + c2 * 32 + 8 * lg]);
#pragma unroll
        for (int jn = 0; jn < 4; jn++) {
          u16x8 vb = *reinterpret_cast<const u16x8*>(&Vt[(jn * 16 + lr) * LDVT + c2 * 32 + 8 * lg]);
          oacc[jn] = mfma16h(pa, vb, oacc[jn]);
        }
      }
    }
  }

  // ---- epilogue via LDS roundtrip (validated) ----
  __syncthreads();
#pragma unroll
  for (int jn = 0; jn < 4; jn++)
#pragma unroll
    for (int i = 0; i < 4; i++)
      Rs[(wid * 16 + 4 * lg + i) * LDR + jn * 16 + lr] = oacc[jn][i];
  __syncthreads();
  if (tid < 128) {
    float s1 = 0.f, s2 = 0.f;
    for (int j = 0; j < 64; j++) { float v = Rs[tid * LDR + j]; s1 += v; s2 += v * v; }
    float mu = s1 * (1.f / 64.f);
    float var = s2 * (1.f / 64.f) - mu * mu;
    mus[tid] = mu; rstds[tid] = rsqrtf(var + 1e-5f);
  }
  __syncthreads();
  for (int p = tid; p < 8192; p += 512) {
    int sl = p >> 6, j = p & 63;
    float y = (Rs[sl * LDR + j] - mus[sl]) * rstds[sl] * lnw[j] + lnb[j];
    y = y / (1.f + expf(-y));
    Y[((size_t)b * 2048 + qbase + sl) * 1024 + h * 64 + j] = f2h(y);
  }
}

// ---------------- f32 patch for rows s < SP, from rotated hi+lo (validated) ----------------
#define SP 32
__global__ __launch_bounds__(256) void k_patch(
    const u16* __restrict__ Qr, const u16* __restrict__ qlo,
    const u16* __restrict__ Kr, const u16* __restrict__ klo,
    const u16* __restrict__ vh_,
    const float* __restrict__ lnw, const float* __restrict__ lnb,
    u16* __restrict__ Y) {
  const int bh = blockIdx.x, b = bh >> 4, h = bh & 15;
  __shared__ float qs[SP][132], ks[SP][132];
  __shared__ float vs[SP][64], rs[SP][64];
  __shared__ float ps[SP][SP];
  __shared__ float mus[SP], rstds[SP];
  const int tid = threadIdx.x;
  const float lg2g = log2f(1.0f - exp2f(-5.0f - (float)h));

  for (int p = tid; p < SP * 128; p += 256) {
    int s = p >> 7, d = p & 127;
    size_t oh = ((size_t)bh * 2048 + s) * 128 + d;
    size_t ol = ((size_t)bh * 32 + s) * 128 + d;
    qs[s][d] = h2f(Qr[oh]) + h2f(qlo[ol]);
    ks[s][d] = h2f(Kr[oh]) + h2f(klo[ol]);
  }
  for (int p = tid; p < SP * 64; p += 256) {
    int s = p >> 6, d = p & 63;
    vs[s][d] = h2f(vh_[((size_t)bh * 2048 + s) * 64 + d]);
  }
  __syncthreads();
  for (int p = tid; p < SP * SP; p += 256) {
    int s = p / SP, t = p % SP;
    float sc = 0.f;
    if (t <= s) {
      for (int d = 0; d < 128; d += 4) {
        float4 q4 = *reinterpret_cast<const float4*>(&qs[s][d]);
        float4 k4 = *reinterpret_cast<const float4*>(&ks[t][d]);
        sc += q4.x * k4.x + q4.y * k4.y + q4.z * k4.z + q4.w * k4.w;
      }
      sc *= exp2f((float)(s - t) * lg2g);
    }
    ps[s][t] = sc;
  }
  __syncthreads();
  for (int p = tid; p < SP * 64; p += 256) {
    int s = p >> 6, j = p & 63;
    float r = 0.f;
    for (int t = 0; t <= s; t++) r += ps[s][t] * vs[t][j];
    rs[s][j] = r;
  }
  __syncthreads();
  if (tid < SP) {
    float s1 = 0.f, s2 = 0.f;
    for (int j = 0; j < 64; j++) { float v = rs[tid][j]; s1 += v; s2 += v * v; }
    float mu = s1 * (1.f / 64.f);
    float var = s2 * (1.f / 64.f) - mu * mu;
    mus[tid] = mu; rstds[tid] = rsqrtf(var + 1e-5f);
  }
  __syncthreads();
  for (int p = tid; p < SP * 64; p += 256) {
    int s = p >> 6, j = p & 63;
    float y = (rs[s][j] - mus[s]) * rstds[s] * lnw[j] + lnb[j];
    y = y / (1.f + expf(-y));
    Y[((size_t)b * 2048 + s) * 1024 + h * 64 + j] = f2h(y);
  }
}

extern "C" void kernel_launch(void* const* d_in, const int* in_sizes, int n_in,
                              void* d_out, int out_size, void* d_ws, size_t ws_size,
                              hipStream_t stream) {
  const float* x   = (const float*)d_in[0];
  const float* Wq  = (const float*)d_in[1];
  const float* Wk  = (const float*)d_in[2];
  const float* Wv  = (const float*)d_in[3];
  const float* Wo  = (const float*)d_in[4];
  const float* lnw = (const float*)d_in[5];
  const float* lnb = (const float*)d_in[6];
  float* out = (float*)d_out;

  char* ws = (char*)d_ws;
  u16*   Qr   = (u16*)(ws + 0);            // [BH][S][128] rotated fp16, 32 MB
  u16*   Kr   = (u16*)(ws + 33554432);     // 32 MB
  u16*   vh   = (u16*)(ws + 67108864);     // [BH][S][64] fp16, 16 MB
  u16*   xh   = (u16*)(ws + 83886080);     // [M][K] fp16 hi, 16 MB  (VT overlays after GEMMs)
  u16*   xl   = (u16*)(ws + 100663296);    // [M][K] fp16 lo, 16 MB  (Y overlays after GEMMs)
  u16*   VT   = (u16*)(ws + 83886080);     // [BH][64][S] fp16 (overlays xh)
  u16*   Y    = (u16*)(ws + 100663296);    // [B*S][D] fp16 (overlays xl)
  u16*   qlo  = (u16*)(ws + 117440512);    // [BH][32][128] fp16 lo-residual
  u16*   klo  = (u16*)(ws + 117964800);
  float* cosT = (float*)(ws + 118489088);  // [S][64] f32
  float* sinT = (float*)(ws + 119013376);
  // total 119,537,664 B (same proven budget as R15)

  k_trig<<<512, 256, 0, stream>>>(cosT, sinT);
  k_split<<<8192, 256, 0, stream>>>(x, xh, xl, 8388608);

  dim3 gg(8, 64);  // N/128, M/128
  k_gemm16<0><<<gg, 256, 0, stream>>>(xh, xl, Wq, 8192, 1024, 1024, Qr, qlo, nullptr, cosT, sinT);
  k_gemm16<0><<<gg, 256, 0, stream>>>(xh, xl, Wk, 8192, 1024, 1024, Kr, klo, nullptr, cosT, sinT);
  k_gemm16<2><<<gg, 256, 0, stream>>>(xh, nullptr, Wv, 8192, 1024, 1024, vh, nullptr, nullptr, nullptr, nullptr);

  k_vt<<<dim3(32, 64), 256, 0, stream>>>(vh, VT);   // xh dead from here

  k_retention<<<dim3(16, 64), 512, 0, stream>>>(Qr, Kr, VT, lnw, lnb, Y);  // xl dead from here

  k_patch<<<64, 256, 0, stream>>>(Qr, qlo, Kr, klo, vh, lnw, lnb, Y);

  k_gemm16<3><<<gg, 256, 0, stream>>>(Y, nullptr, Wo, 8192, 1024, 1024, nullptr, nullptr, out, nullptr, nullptr);
}

// Round 17
// 428.925 us; speedup vs baseline: 9.8896x; 1.0094x over previous
//
#include <hip/hip_runtime.h>

typedef unsigned short u16;
typedef _Float16 f16;
typedef _Float16 f16x8 __attribute__((ext_vector_type(8)));
typedef float f32x4 __attribute__((ext_vector_type(4)));
typedef unsigned short u16x8 __attribute__((ext_vector_type(8)));
typedef unsigned short u16x4 __attribute__((ext_vector_type(4)));

typedef __attribute__((address_space(3))) unsigned int lds_u32;
typedef __attribute__((address_space(1))) unsigned int glb_u32;

static __device__ __forceinline__ u16 f2h(float f) {
  f16 h = (f16)f;
  return __builtin_bit_cast(u16, h);
}
static __device__ __forceinline__ float h2f(u16 h) {
  return (float)__builtin_bit_cast(f16, h);
}

static __device__ __forceinline__ f32x4 mfma16h(u16x8 a, u16x8 b, f32x4 c) {
  return __builtin_amdgcn_mfma_f32_16x16x32_f16(
      __builtin_bit_cast(f16x8, a), __builtin_bit_cast(f16x8, b), c, 0, 0, 0);
}

// async global->LDS, 16B per lane; lds dest must be the wave-uniform base
static __device__ __forceinline__ void glds16(const u16* g, u16* l) {
  __builtin_amdgcn_global_load_lds((const glb_u32*)g, (lds_u32*)l, 16, 0, 0);
}

// stage a [128][32] u16 linear tile (512 16B-chunks) via global_load_lds, 256 threads
static __device__ __forceinline__ void glds_tile(
    const u16* __restrict__ src, int row0, int K, int k0, u16* tile, int tid) {
#pragma unroll
  for (int call = 0; call < 2; call++) {
    int c = call * 256 + tid;
    int row = c >> 2, col = (c & 3) * 8;
    glds16(&src[(size_t)(row0 + row) * K + k0 + col], tile + (size_t)(c & ~63) * 8);
  }
}

// ---------------- cos/sin tables [S][64], f64-accurate ----------------
__global__ void k_trig(float* __restrict__ cosT, float* __restrict__ sinT) {
  int idx = blockIdx.x * blockDim.x + threadIdx.x;  // S*64 threads
  int s = idx >> 6, j = idx & 63;
  double theta = exp2(-0.4152410118609203 * (double)j);  // 10000^(-j/32), f64
  double ang = (double)s * theta;
  cosT[idx] = (float)cos(ang);
  sinT[idx] = (float)sin(ang);
}

// ---------------- f32 -> fp16 hi/lo Dekker pre-split ----------------
__global__ void k_split(const float* __restrict__ src, u16* __restrict__ hi,
                        u16* __restrict__ lo, int n) {
  int i = (blockIdx.x * blockDim.x + threadIdx.x) * 4;
  if (i >= n) return;
  float4 v = *reinterpret_cast<const float4*>(src + i);
  const float* vp = reinterpret_cast<const float*>(&v);
  u16x4 hv, lv;
#pragma unroll
  for (int e = 0; e < 4; e++) {
    hv[e] = f2h(vp[e]);
    lv[e] = f2h(vp[e] - h2f(hv[e]));
  }
  *reinterpret_cast<u16x4*>(hi + i) = hv;
  *reinterpret_cast<u16x4*>(lo + i) = lv;
}

// ---------------- TN GEMM, global_load_lds staging, linear [128][32] tiles ----------------
// MODE 0: 3-pass Dekker (A hi/lo, B hi/lo all pre-split fp16); rotate-scatter epilogue + lo (s<32)
// MODE 2: single-pass (A hi; B f32 converted in-stage); scatter [BH][S][64] (V)
// MODE 3: single-pass; outF f32 row-major (out-GEMM, A = Y fp16)
template <int MODE>
__global__ __launch_bounds__(256) void k_gemm16(
    const u16* __restrict__ Ah_, const u16* __restrict__ Al_,
    const u16* __restrict__ Bh_, const u16* __restrict__ Bl_,
    const float* __restrict__ Bw,
    int M, int N, int K,
    u16* __restrict__ outH, u16* __restrict__ loB, float* __restrict__ outF,
    const float* __restrict__ cosT, const float* __restrict__ sinT) {
  constexpr int LDT = 32;  // linear: global_load_lds requires contiguous lane-ordered dest
  constexpr int NTILE = (MODE == 0) ? 4 : 2;
  __shared__ __align__(16) u16 SMEM[NTILE * 128 * 32];
  u16* Ash = SMEM;
  u16* Asl = SMEM + 4096;            // MODE 0 only
  u16* Bsh = SMEM + (MODE == 0 ? 8192 : 4096);
  u16* Bsl = SMEM + 12288;           // MODE 0 only
  const int tid = threadIdx.x;
  const int m0 = blockIdx.y * 128;
  const int n0 = blockIdx.x * 128;
  const int lane = tid & 63, lr = lane & 15, lg = lane >> 4;
  const int wid = tid >> 6;
  const int wm = (wid >> 1) * 64, wn = (wid & 1) * 64;

  const f32x4 fz = {0.f, 0.f, 0.f, 0.f};
  f32x4 acc[4][4];
#pragma unroll
  for (int i = 0; i < 4; i++)
#pragma unroll
    for (int j = 0; j < 4; j++) acc[i][j] = fz;

  for (int k0 = 0; k0 < K; k0 += 32) {
    __syncthreads();
    glds_tile(Ah_, m0, K, k0, Ash, tid);
    if constexpr (MODE == 0) {
      glds_tile(Al_, m0, K, k0, Asl, tid);
      glds_tile(Bh_, n0, K, k0, Bsh, tid);
      glds_tile(Bl_, n0, K, k0, Bsl, tid);
    } else {
      // B: f32 -> fp16 hi, vectorized u16x4 LDS writes
#pragma unroll
      for (int p = 0; p < 4; p++) {
        int c = p * 256 + tid;
        int row = c >> 3, col = (c & 7) * 4;
        float4 bv = *reinterpret_cast<const float4*>(&Bw[(size_t)(n0 + row) * K + k0 + col]);
        const float* bp = reinterpret_cast<const float*>(&bv);
        u16x4 hv;
#pragma unroll
        for (int e = 0; e < 4; e++) hv[e] = f2h(bp[e]);
        *reinterpret_cast<u16x4*>(&Bsh[row * LDT + col]) = hv;
      }
    }
    __syncthreads();  // drains vmcnt(0) (global_load_lds) + lgkmcnt

    u16x8 ah[4], al[4], bh[4], bl[4];
#pragma unroll
    for (int i = 0; i < 4; i++) {
      ah[i] = *reinterpret_cast<const u16x8*>(&Ash[(wm + i * 16 + lr) * LDT + 8 * lg]);
      if constexpr (MODE == 0)
        al[i] = *reinterpret_cast<const u16x8*>(&Asl[(wm + i * 16 + lr) * LDT + 8 * lg]);
    }
#pragma unroll
    for (int j = 0; j < 4; j++) {
      bh[j] = *reinterpret_cast<const u16x8*>(&Bsh[(wn + j * 16 + lr) * LDT + 8 * lg]);
      if constexpr (MODE == 0)
        bl[j] = *reinterpret_cast<const u16x8*>(&Bsl[(wn + j * 16 + lr) * LDT + 8 * lg]);
    }
#pragma unroll
    for (int i = 0; i < 4; i++)
#pragma unroll
      for (int j = 0; j < 4; j++) {
        acc[i][j] = mfma16h(ah[i], bh[j], acc[i][j]);
        if constexpr (MODE == 0) {
          acc[i][j] = mfma16h(ah[i], bl[j], acc[i][j]);
          acc[i][j] = mfma16h(al[i], bh[j], acc[i][j]);
        }
      }
  }

#pragma unroll
  for (int i = 0; i < 4; i++)
#pragma unroll
    for (int j = 0; j < 4; j++)
#pragma unroll
      for (int r = 0; r < 4; r++) {
        int m = m0 + wm + i * 16 + 4 * lg + r;
        int n = n0 + wn + j * 16 + lr;
        float v = acc[i][j][r];
        if constexpr (MODE == 3) {
          outF[(size_t)m * N + n] = v;
        } else {
          int b = m >> 11, s = m & 2047;  // S = 2048
          int h = n >> 6, jj = n & 63;
          if constexpr (MODE == 2) {
            outH[(((size_t)(b * 16 + h)) * 2048 + s) * 64 + jj] = f2h(v);
          } else {
            float cv = cosT[s * 64 + jj], sv = sinT[s * 64 + jj];
            float a = v * cv, bb = v * sv;
            size_t o = (((size_t)(b * 16 + h)) * 2048 + s) * 128 + jj;
            u16 ahh = f2h(a), bhh = f2h(bb);
            outH[o] = ahh;
            outH[o + 64] = bhh;
            if (s < 32) {
              size_t ol = (((size_t)(b * 16 + h)) * 32 + s) * 128 + jj;
              loB[ol] = f2h(a - h2f(ahh));
              loB[ol + 64] = f2h(bb - h2f(bhh));
            }
          }
        }
      }
}

// ---------------- V transpose: vh [BH][S][64] -> VT [BH][64][S] (validated) ----------------
__global__ __launch_bounds__(256) void k_vt(const u16* __restrict__ vh,
                                            u16* __restrict__ VT) {
  __shared__ u16 T[64][72];
  const int tid = threadIdx.x;
  const int bh = blockIdx.y, s0 = blockIdx.x * 64;
#pragma unroll
  for (int p = 0; p < 2; p++) {
    int c = p * 256 + tid;
    int r = c >> 3, j0 = (c & 7) * 8;
    *reinterpret_cast<u16x8*>(&T[r][j0]) =
        *reinterpret_cast<const u16x8*>(&vh[((size_t)bh * 2048 + s0 + r) * 64 + j0]);
  }
  __syncthreads();
#pragma unroll
  for (int p = 0; p < 2; p++) {
    int c = p * 256 + tid;
    int j = c >> 3, r0 = (c & 7) * 8;
    u16x8 o;
#pragma unroll
    for (int e = 0; e < 8; e++) o[e] = T[r0 + e][j];
    *reinterpret_cast<u16x8*>(&VT[((size_t)bh * 64 + j) * 2048 + s0 + r0]) = o;
  }
}

// ---------------- retention (R16-validated, unchanged) ----------------
constexpr int LDK = 136;
constexpr int LDPh = 72;
constexpr int LDVT = 72;
constexpr int LDR = 65;

static __device__ __forceinline__ void stage_tile(
    const u16* __restrict__ src, int bh, int r0, int tid, u16* Ks) {
#pragma unroll
  for (int p = 0; p < 2; p++) {
    int c = p * 512 + tid;
    int row = c >> 4, col = (c & 15) * 8;
    *reinterpret_cast<int4*>(&Ks[row * LDK + col]) =
        *reinterpret_cast<const int4*>(&src[((size_t)bh * 2048 + r0 + row) * 128 + col]);
  }
}

__global__ __launch_bounds__(512) void k_retention(
    const u16* __restrict__ Qr, const u16* __restrict__ Kr,
    const u16* __restrict__ VT_,
    const float* __restrict__ lnw, const float* __restrict__ lnb,
    u16* __restrict__ Y) {
  __shared__ __align__(16) char SM[17408 + 9216 + 18432];
  u16*   Ks  = (u16*)SM;
  u16*   Vt  = (u16*)(SM + 17408);
  u16*   Psh = (u16*)(SM + 17408 + 9216);
  float* Rs  = (float*)SM;
  __shared__ float mus[128], rstds[128];

  const int tid = threadIdx.x;
  const int bh = blockIdx.y, b = bh >> 4, h = bh & 15;
  const int qt = (int)gridDim.x - 1 - (int)blockIdx.x;
  const int qbase = qt * 128;
  const int wid = tid >> 6, lane = tid & 63, lr = lane & 15, lg = lane >> 4;
  const int qg = qbase + wid * 16;
  const float lg2g = log2f(1.0f - exp2f(-5.0f - (float)h));

  u16x8 qa[4];
  stage_tile(Qr, bh, qbase, tid, Ks);
  __syncthreads();
  if (wid < 4) {
#pragma unroll
    for (int dc = 0; dc < 4; dc++)
      qa[dc] = *reinterpret_cast<const u16x8*>(&Ks[(wid * 16 + lr) * LDK + dc * 32 + 8 * lg]);
  }
  __syncthreads();
  stage_tile(Qr, bh, qbase + 64, tid, Ks);
  __syncthreads();
  if (wid >= 4) {
#pragma unroll
    for (int dc = 0; dc < 4; dc++)
      qa[dc] = *reinterpret_cast<const u16x8*>(&Ks[((wid - 4) * 16 + lr) * LDK + dc * 32 + 8 * lg]);
  }

  const f32x4 fz = {0.f, 0.f, 0.f, 0.f};
  f32x4 oacc[4];
#pragma unroll
  for (int j = 0; j < 4; j++) oacc[j] = fz;

  const int krow = tid >> 4, kcol = (tid & 15) * 8;
  const int vj = tid >> 3, vt0 = (tid & 7) * 8;
  int4 kbuf0, kbuf1, vbuf;
  {
    kbuf0 = *reinterpret_cast<const int4*>(&Kr[((size_t)bh * 2048 + krow) * 128 + kcol]);
    kbuf1 = *reinterpret_cast<const int4*>(&Kr[((size_t)bh * 2048 + 32 + krow) * 128 + kcol]);
    vbuf  = *reinterpret_cast<const int4*>(&VT_[((size_t)bh * 64 + vj) * 2048 + vt0]);
  }

  const int ntiles = 2 * qt + 2;
  for (int kt = 0; kt < ntiles; ++kt) {
    const int t0 = kt * 64;
    const bool active = (t0 <= qg + 15);
    __syncthreads();
    *reinterpret_cast<int4*>(&Ks[krow * LDK + kcol]) = kbuf0;
    *reinterpret_cast<int4*>(&Ks[(krow + 32) * LDK + kcol]) = kbuf1;
    *reinterpret_cast<int4*>(&Vt[vj * LDVT + vt0]) = vbuf;
    if (kt + 1 < ntiles) {
      const int t1 = t0 + 64;
      kbuf0 = *reinterpret_cast<const int4*>(&Kr[((size_t)bh * 2048 + t1 + krow) * 128 + kcol]);
      kbuf1 = *reinterpret_cast<const int4*>(&Kr[((size_t)bh * 2048 + t1 + 32 + krow) * 128 + kcol]);
      vbuf  = *reinterpret_cast<const int4*>(&VT_[((size_t)bh * 64 + vj) * 2048 + t1 + vt0]);
    }
    __syncthreads();

    if (active) {
#pragma unroll
      for (int tn = 0; tn < 4; tn++) {
        f32x4 st = fz;
#pragma unroll
        for (int dc = 0; dc < 4; dc++) {
          u16x8 kb = *reinterpret_cast<const u16x8*>(&Ks[(tn * 16 + lr) * LDK + dc * 32 + 8 * lg]);
          st = mfma16h(qa[dc], kb, st);
        }
        const int t = t0 + tn * 16 + lr;
#pragma unroll
        for (int i = 0; i < 4; i++) {
          int q = qg + 4 * lg + i;
          float v = st[i];
          v = (t <= q) ? v * exp2f((float)(q - t) * lg2g) : 0.f;
          Psh[(wid * 16 + 4 * lg + i) * LDPh + tn * 16 + lr] = f2h(v);
        }
      }
      asm volatile("s_waitcnt lgkmcnt(0)" ::: "memory");
      __builtin_amdgcn_sched_barrier(0);
#pragma unroll
      for (int c2 = 0; c2 < 2; c2++) {
        u16x8 pa = *reinterpret_cast<const u16x8*>(&Psh[(wid * 16 + lr) * LDPh + c2 * 32 + 8 * lg]);
#pragma unroll
        for (int jn = 0; jn < 4; jn++) {
          u16x8 vb = *reinterpret_cast<const u16x8*>(&Vt[(jn * 16 + lr) * LDVT + c2 * 32 + 8 * lg]);
          oacc[jn] = mfma16h(pa, vb, oacc[jn]);
        }
      }
    }
  }

  __syncthreads();
#pragma unroll
  for (int jn = 0; jn < 4; jn++)
#pragma unroll
    for (int i = 0; i < 4; i++)
      Rs[(wid * 16 + 4 * lg + i) * LDR + jn * 16 + lr] = oacc[jn][i];
  __syncthreads();
  if (tid < 128) {
    float s1 = 0.f, s2 = 0.f;
    for (int j = 0; j < 64; j++) { float v = Rs[tid * LDR + j]; s1 += v; s2 += v * v; }
    float mu = s1 * (1.f / 64.f);
    float var = s2 * (1.f / 64.f) - mu * mu;
    mus[tid] = mu; rstds[tid] = rsqrtf(var + 1e-5f);
  }
  __syncthreads();
  for (int p = tid; p < 8192; p += 512) {
    int sl = p >> 6, j = p & 63;
    float y = (Rs[sl * LDR + j] - mus[sl]) * rstds[sl] * lnw[j] + lnb[j];
    y = y / (1.f + expf(-y));
    Y[((size_t)b * 2048 + qbase + sl) * 1024 + h * 64 + j] = f2h(y);
  }
}

// ---------------- f32 patch for rows s < SP, from rotated hi+lo (validated) ----------------
#define SP 32
__global__ __launch_bounds__(256) void k_patch(
    const u16* __restrict__ Qr, const u16* __restrict__ qlo,
    const u16* __restrict__ Kr, const u16* __restrict__ klo,
    const u16* __restrict__ vh_,
    const float* __restrict__ lnw, const float* __restrict__ lnb,
    u16* __restrict__ Y) {
  const int bh = blockIdx.x, b = bh >> 4, h = bh & 15;
  __shared__ float qs[SP][132], ks[SP][132];
  __shared__ float vs[SP][64], rs[SP][64];
  __shared__ float ps[SP][SP];
  __shared__ float mus[SP], rstds[SP];
  const int tid = threadIdx.x;
  const float lg2g = log2f(1.0f - exp2f(-5.0f - (float)h));

  for (int p = tid; p < SP * 128; p += 256) {
    int s = p >> 7, d = p & 127;
    size_t oh = ((size_t)bh * 2048 + s) * 128 + d;
    size_t ol = ((size_t)bh * 32 + s) * 128 + d;
    qs[s][d] = h2f(Qr[oh]) + h2f(qlo[ol]);
    ks[s][d] = h2f(Kr[oh]) + h2f(klo[ol]);
  }
  for (int p = tid; p < SP * 64; p += 256) {
    int s = p >> 6, d = p & 63;
    vs[s][d] = h2f(vh_[((size_t)bh * 2048 + s) * 64 + d]);
  }
  __syncthreads();
  for (int p = tid; p < SP * SP; p += 256) {
    int s = p / SP, t = p % SP;
    float sc = 0.f;
    if (t <= s) {
      for (int d = 0; d < 128; d += 4) {
        float4 q4 = *reinterpret_cast<const float4*>(&qs[s][d]);
        float4 k4 = *reinterpret_cast<const float4*>(&ks[t][d]);
        sc += q4.x * k4.x + q4.y * k4.y + q4.z * k4.z + q4.w * k4.w;
      }
      sc *= exp2f((float)(s - t) * lg2g);
    }
    ps[s][t] = sc;
  }
  __syncthreads();
  for (int p = tid; p < SP * 64; p += 256) {
    int s = p >> 6, j = p & 63;
    float r = 0.f;
    for (int t = 0; t <= s; t++) r += ps[s][t] * vs[t][j];
    rs[s][j] = r;
  }
  __syncthreads();
  if (tid < SP) {
    float s1 = 0.f, s2 = 0.f;
    for (int j = 0; j < 64; j++) { float v = rs[tid][j]; s1 += v; s2 += v * v; }
    float mu = s1 * (1.f / 64.f);
    float var = s2 * (1.f / 64.f) - mu * mu;
    mus[tid] = mu; rstds[tid] = rsqrtf(var + 1e-5f);
  }
  __syncthreads();
  for (int p = tid; p < SP * 64; p += 256) {
    int s = p >> 6, j = p & 63;
    float y = (rs[s][j] - mus[s]) * rstds[s] * lnw[j] + lnb[j];
    y = y / (1.f + expf(-y));
    Y[((size_t)b * 2048 + s) * 1024 + h * 64 + j] = f2h(y);
  }
}

extern "C" void kernel_launch(void* const* d_in, const int* in_sizes, int n_in,
                              void* d_out, int out_size, void* d_ws, size_t ws_size,
                              hipStream_t stream) {
  const float* x   = (const float*)d_in[0];
  const float* Wq  = (const float*)d_in[1];
  const float* Wk  = (const float*)d_in[2];
  const float* Wv  = (const float*)d_in[3];
  const float* Wo  = (const float*)d_in[4];
  const float* lnw = (const float*)d_in[5];
  const float* lnb = (const float*)d_in[6];
  float* out = (float*)d_out;

  char* ws = (char*)d_ws;
  u16*   Qr   = (u16*)(ws + 0);            // [BH][S][128] rotated fp16, 32 MB
  u16*   Kr   = (u16*)(ws + 33554432);     // 32 MB
  u16*   vh   = (u16*)(ws + 67108864);     // [BH][S][64] fp16, 16 MB
  u16*   Wqh  = (u16*)(ws + 67108864);     // weight splits overlay vh (dead before V-GEMM)
  u16*   Wql  = (u16*)(ws + 69206016);
  u16*   Wkh  = (u16*)(ws + 71303168);
  u16*   Wkl  = (u16*)(ws + 73400320);
  u16*   xh   = (u16*)(ws + 83886080);     // [M][K] fp16 hi, 16 MB  (VT overlays after GEMMs)
  u16*   xl   = (u16*)(ws + 100663296);    // [M][K] fp16 lo, 16 MB  (Y overlays after GEMMs)
  u16*   VT   = (u16*)(ws + 83886080);     // [BH][64][S] fp16 (overlays xh)
  u16*   Y    = (u16*)(ws + 100663296);    // [B*S][D] fp16 (overlays xl)
  u16*   qlo  = (u16*)(ws + 117440512);    // [BH][32][128] fp16 lo-residual
  u16*   klo  = (u16*)(ws + 117964800);
  float* cosT = (float*)(ws + 118489088);  // [S][64] f32
  float* sinT = (float*)(ws + 119013376);
  // total 119,537,664 B (same proven budget as R15/R16)

  k_trig<<<512, 256, 0, stream>>>(cosT, sinT);
  k_split<<<8192, 256, 0, stream>>>(x, xh, xl, 8388608);
  k_split<<<1024, 256, 0, stream>>>(Wq, Wqh, Wql, 1048576);
  k_split<<<1024, 256, 0, stream>>>(Wk, Wkh, Wkl, 1048576);

  dim3 gg(8, 64);  // N/128, M/128
  k_gemm16<0><<<gg, 256, 0, stream>>>(xh, xl, Wqh, Wql, nullptr, 8192, 1024, 1024, Qr, qlo, nullptr, cosT, sinT);
  k_gemm16<0><<<gg, 256, 0, stream>>>(xh, xl, Wkh, Wkl, nullptr, 8192, 1024, 1024, Kr, klo, nullptr, cosT, sinT);
  k_gemm16<2><<<gg, 256, 0, stream>>>(xh, nullptr, nullptr, nullptr, Wv, 8192, 1024, 1024, vh, nullptr, nullptr, nullptr, nullptr);  // clobbers W splits (dead)

  k_vt<<<dim3(32, 64), 256, 0, stream>>>(vh, VT);   // xh dead from here

  k_retention<<<dim3(16, 64), 512, 0, stream>>>(Qr, Kr, VT, lnw, lnb, Y);  // xl dead from here

  k_patch<<<64, 256, 0, stream>>>(Qr, qlo, Kr, klo, vh, lnw, lnb, Y);

  k_gemm16<3><<<gg, 256, 0, stream>>>(Y, nullptr, nullptr, nullptr, Wo, 8192, 1024, 1024, nullptr, nullptr, out, nullptr, nullptr);
}

// Round 18
// 394.689 us; speedup vs baseline: 10.7475x; 1.0867x over previous
//
#include <hip/hip_runtime.h>

typedef unsigned short u16;
typedef _Float16 f16;
typedef _Float16 f16x8 __attribute__((ext_vector_type(8)));
typedef float f32x4 __attribute__((ext_vector_type(4)));
typedef unsigned short u16x8 __attribute__((ext_vector_type(8)));
typedef unsigned short u16x4 __attribute__((ext_vector_type(4)));

typedef __attribute__((address_space(3))) unsigned int lds_u32;
typedef __attribute__((address_space(1))) unsigned int glb_u32;

static __device__ __forceinline__ u16 f2h(float f) {
  f16 h = (f16)f;
  return __builtin_bit_cast(u16, h);
}
static __device__ __forceinline__ float h2f(u16 h) {
  return (float)__builtin_bit_cast(f16, h);
}

static __device__ __forceinline__ f32x4 mfma16h(u16x8 a, u16x8 b, f32x4 c) {
  return __builtin_amdgcn_mfma_f32_16x16x32_f16(
      __builtin_bit_cast(f16x8, a), __builtin_bit_cast(f16x8, b), c, 0, 0, 0);
}

static __device__ __forceinline__ void glds16(const u16* g, u16* l) {
  __builtin_amdgcn_global_load_lds((const glb_u32*)g, (lds_u32*)l, 16, 0, 0);
}

// stage a [128][32] u16 linear tile (512 16B-chunks) via global_load_lds, 256 threads
static __device__ __forceinline__ void glds_tile(
    const u16* __restrict__ src, int row0, int K, int k0, u16* tile, int tid) {
#pragma unroll
  for (int call = 0; call < 2; call++) {
    int c = call * 256 + tid;
    int row = c >> 2, col = (c & 3) * 8;
    glds16(&src[(size_t)(row0 + row) * K + k0 + col], tile + (size_t)(c & ~63) * 8);
  }
}

// ---------------- cos/sin tables [S][64], f64-accurate ----------------
__global__ void k_trig(float* __restrict__ cosT, float* __restrict__ sinT) {
  int idx = blockIdx.x * blockDim.x + threadIdx.x;  // S*64 threads
  int s = idx >> 6, j = idx & 63;
  double theta = exp2(-0.4152410118609203 * (double)j);  // 10000^(-j/32), f64
  double ang = (double)s * theta;
  cosT[idx] = (float)cos(ang);
  sinT[idx] = (float)sin(ang);
}

// ---------------- f32 -> fp16 hi/lo Dekker pre-split ----------------
__global__ void k_split(const float* __restrict__ src, u16* __restrict__ hi,
                        u16* __restrict__ lo, int n) {
  int i = (blockIdx.x * blockDim.x + threadIdx.x) * 4;
  if (i >= n) return;
  float4 v = *reinterpret_cast<const float4*>(src + i);
  const float* vp = reinterpret_cast<const float*>(&v);
  u16x4 hv, lv;
#pragma unroll
  for (int e = 0; e < 4; e++) {
    hv[e] = f2h(vp[e]);
    lv[e] = f2h(vp[e] - h2f(hv[e]));
  }
  *reinterpret_cast<u16x4*>(hi + i) = hv;
  *reinterpret_cast<u16x4*>(lo + i) = lv;
}

// ---------------- TN GEMM, global_load_lds staging, linear [128][32] tiles ----------------
// MODE 0: 3-pass Dekker (A hi/lo, B hi/lo pre-split fp16); rotate-scatter epilogue + lo (s<32)
// MODE 2: single-pass (A hi, B hi pre-split); scatter [BH][S][64] (V)
// MODE 3: single-pass (A=Y fp16, B hi pre-split); outF f32 row-major
template <int MODE>
__global__ __launch_bounds__(256) void k_gemm16(
    const u16* __restrict__ Ah_, const u16* __restrict__ Al_,
    const u16* __restrict__ Bh_, const u16* __restrict__ Bl_,
    int M, int N, int K,
    u16* __restrict__ outH, u16* __restrict__ loB, float* __restrict__ outF,
    const float* __restrict__ cosT, const float* __restrict__ sinT) {
  constexpr int LDT = 32;
  constexpr int NTILE = (MODE == 0) ? 4 : 2;
  __shared__ __align__(16) u16 SMEM[NTILE * 128 * 32];
  u16* Ash = SMEM;
  u16* Asl = SMEM + 4096;
  u16* Bsh = SMEM + (MODE == 0 ? 8192 : 4096);
  u16* Bsl = SMEM + 12288;
  const int tid = threadIdx.x;
  // XCD swizzle: each XCD owns 8 consecutive A row-panels (grid must be 8 x 64)
  const int lB = (int)blockIdx.y * 8 + (int)blockIdx.x;
  const int xcd = lB & 7, rr = lB >> 3;
  const int m0 = (xcd * 8 + (rr >> 3)) * 128;
  const int n0 = (rr & 7) * 128;
  const int lane = tid & 63, lr = lane & 15, lg = lane >> 4;
  const int wid = tid >> 6;
  const int wm = (wid >> 1) * 64, wn = (wid & 1) * 64;

  const f32x4 fz = {0.f, 0.f, 0.f, 0.f};
  f32x4 acc[4][4];
#pragma unroll
  for (int i = 0; i < 4; i++)
#pragma unroll
    for (int j = 0; j < 4; j++) acc[i][j] = fz;

  for (int k0 = 0; k0 < K; k0 += 32) {
    __syncthreads();
    glds_tile(Ah_, m0, K, k0, Ash, tid);
    glds_tile(Bh_, n0, K, k0, Bsh, tid);
    if constexpr (MODE == 0) {
      glds_tile(Al_, m0, K, k0, Asl, tid);
      glds_tile(Bl_, n0, K, k0, Bsl, tid);
    }
    __syncthreads();  // drains vmcnt(0) for global_load_lds

    u16x8 ah[4], al[4], bh[4], bl[4];
#pragma unroll
    for (int i = 0; i < 4; i++) {
      ah[i] = *reinterpret_cast<const u16x8*>(&Ash[(wm + i * 16 + lr) * LDT + 8 * lg]);
      if constexpr (MODE == 0)
        al[i] = *reinterpret_cast<const u16x8*>(&Asl[(wm + i * 16 + lr) * LDT + 8 * lg]);
    }
#pragma unroll
    for (int j = 0; j < 4; j++) {
      bh[j] = *reinterpret_cast<const u16x8*>(&Bsh[(wn + j * 16 + lr) * LDT + 8 * lg]);
      if constexpr (MODE == 0)
        bl[j] = *reinterpret_cast<const u16x8*>(&Bsl[(wn + j * 16 + lr) * LDT + 8 * lg]);
    }
#pragma unroll
    for (int i = 0; i < 4; i++)
#pragma unroll
      for (int j = 0; j < 4; j++) {
        acc[i][j] = mfma16h(ah[i], bh[j], acc[i][j]);
        if constexpr (MODE == 0) {
          acc[i][j] = mfma16h(ah[i], bl[j], acc[i][j]);
          acc[i][j] = mfma16h(al[i], bh[j], acc[i][j]);
        }
      }
  }

#pragma unroll
  for (int i = 0; i < 4; i++)
#pragma unroll
    for (int j = 0; j < 4; j++)
#pragma unroll
      for (int r = 0; r < 4; r++) {
        int m = m0 + wm + i * 16 + 4 * lg + r;
        int n = n0 + wn + j * 16 + lr;
        float v = acc[i][j][r];
        if constexpr (MODE == 3) {
          outF[(size_t)m * N + n] = v;
        } else {
          int b = m >> 11, s = m & 2047;  // S = 2048
          int h = n >> 6, jj = n & 63;
          if constexpr (MODE == 2) {
            outH[(((size_t)(b * 16 + h)) * 2048 + s) * 64 + jj] = f2h(v);
          } else {
            float cv = cosT[s * 64 + jj], sv = sinT[s * 64 + jj];
            float a = v * cv, bb = v * sv;
            size_t o = (((size_t)(b * 16 + h)) * 2048 + s) * 128 + jj;
            u16 ahh = f2h(a), bhh = f2h(bb);
            outH[o] = ahh;
            outH[o + 64] = bhh;
            if (s < 32) {
              size_t ol = (((size_t)(b * 16 + h)) * 32 + s) * 128 + jj;
              loB[ol] = f2h(a - h2f(ahh));
              loB[ol + 64] = f2h(bb - h2f(bhh));
            }
          }
        }
      }
}

// ---------------- V transpose: vh [BH][S][64] -> VT [BH][64][S] (validated) ----------------
__global__ __launch_bounds__(256) void k_vt(const u16* __restrict__ vh,
                                            u16* __restrict__ VT) {
  __shared__ u16 T[64][72];
  const int tid = threadIdx.x;
  const int bh = blockIdx.y, s0 = blockIdx.x * 64;
#pragma unroll
  for (int p = 0; p < 2; p++) {
    int c = p * 256 + tid;
    int r = c >> 3, j0 = (c & 7) * 8;
    *reinterpret_cast<u16x8*>(&T[r][j0]) =
        *reinterpret_cast<const u16x8*>(&vh[((size_t)bh * 2048 + s0 + r) * 64 + j0]);
  }
  __syncthreads();
#pragma unroll
  for (int p = 0; p < 2; p++) {
    int c = p * 256 + tid;
    int j = c >> 3, r0 = (c & 7) * 8;
    u16x8 o;
#pragma unroll
    for (int e = 0; e < 8; e++) o[e] = T[r0 + e][j];
    *reinterpret_cast<u16x8*>(&VT[((size_t)bh * 64 + j) * 2048 + s0 + r0]) = o;
  }
}

// ---------------- retention: QBLK=256 (16 waves), fp16 P, V^T LDS, XCD-clustered ----------------
constexpr int LDK = 136;
constexpr int LDPh = 72;
constexpr int LDVT = 72;
constexpr int LDR = 65;

__global__ __launch_bounds__(1024) void k_retention(
    const u16* __restrict__ Qr, const u16* __restrict__ Kr,
    const u16* __restrict__ VT_,
    const float* __restrict__ lnw, const float* __restrict__ lnb,
    u16* __restrict__ Y) {
  // LDS: Ks 17408 | Vt 9216 | Psh[256][72] 36864 = 63488; Rs (128x65x4=33280) overlays base.
  __shared__ __align__(16) char SM[17408 + 9216 + 36864];
  u16*   Ks  = (u16*)SM;
  u16*   Vt  = (u16*)(SM + 17408);
  u16*   Psh = (u16*)(SM + 26624);
  float* Rs  = (float*)SM;
  __shared__ float mus[128], rstds[128];

  const int tid = threadIdx.x;
  // XCD swizzle: each XCD owns 8 whole bh's; heavy q-tiles first within each stream
  const int lB = blockIdx.x;            // 512 blocks
  const int xcd = lB & 7, i2 = lB >> 3; // i2: 0..63
  const int bh = xcd * 8 + (i2 >> 3);
  const int qt = 7 - (i2 & 7);
  const int b = bh >> 4, h = bh & 15;
  const int qbase = qt * 256;
  const int wid = tid >> 6, lane = tid & 63, lr = lane & 15, lg = lane >> 4;
  const int qg = qbase + wid * 16;  // this wave's first q row
  const float lg2g = log2f(1.0f - exp2f(-5.0f - (float)h));
  const float gam = exp2f(lg2g);
  const float gam2 = gam * gam, gam3 = gam2 * gam;

  // ---- prologue: stage Q' in four 64-row rounds through Ks, read A-fragments ----
  u16x8 qa[4];
#pragma unroll
  for (int hh = 0; hh < 4; hh++) {
    {  // stage 64x128 tile: 1024 chunks, 1 per thread
      int row = tid >> 4, col = (tid & 15) * 8;
      *reinterpret_cast<int4*>(&Ks[row * LDK + col]) =
          *reinterpret_cast<const int4*>(&Qr[((size_t)bh * 2048 + qbase + hh * 64 + row) * 128 + col]);
    }
    __syncthreads();
    if ((wid >> 2) == hh) {
      int wl = wid & 3;
#pragma unroll
      for (int dc = 0; dc < 4; dc++)
        qa[dc] = *reinterpret_cast<const u16x8*>(&Ks[(wl * 16 + lr) * LDK + dc * 32 + 8 * lg]);
    }
    __syncthreads();
  }

  const f32x4 fz = {0.f, 0.f, 0.f, 0.f};
  f32x4 oacc[4];
#pragma unroll
  for (int j = 0; j < 4; j++) oacc[j] = fz;

  const int ntiles = 4 * qt + 4;
  for (int kt = 0; kt < ntiles; ++kt) {
    const int t0 = kt * 64;
    const bool active = (t0 <= qg + 15);  // wave-uniform
    __syncthreads();  // prior tile's Ks/Vt/Psh reads done
    {  // stage K tile: 1024 chunks, 1 per thread
      int row = tid >> 4, col = (tid & 15) * 8;
      *reinterpret_cast<int4*>(&Ks[row * LDK + col]) =
          *reinterpret_cast<const int4*>(&Kr[((size_t)bh * 2048 + t0 + row) * 128 + col]);
    }
    if (tid < 512) {  // stage V^T tile: 512 chunks (waves 0-7)
      int j = tid >> 3, tl0 = (tid & 7) * 8;
      *reinterpret_cast<u16x8*>(&Vt[j * LDVT + tl0]) =
          *reinterpret_cast<const u16x8*>(&VT_[((size_t)bh * 64 + j) * 2048 + t0 + tl0]);
    }
    __syncthreads();

    if (active) {
      // ---- QK^T: D rows = q (4*lg+i), cols = t (lr); decay via 1 exp2 + muls ----
#pragma unroll
      for (int tn = 0; tn < 4; tn++) {
        f32x4 st = fz;
#pragma unroll
        for (int dc = 0; dc < 4; dc++) {
          u16x8 kb = *reinterpret_cast<const u16x8*>(&Ks[(tn * 16 + lr) * LDK + dc * 32 + 8 * lg]);
          st = mfma16h(qa[dc], kb, st);
        }
        const int t = t0 + tn * 16 + lr;
        const int q0 = qg + 4 * lg;
        const float dec0 = exp2f((float)(q0 - t) * lg2g);
        const float dd[4] = {dec0, dec0 * gam, dec0 * gam2, dec0 * gam3};
#pragma unroll
        for (int i = 0; i < 4; i++) {
          float v = (t <= q0 + i) ? st[i] * dd[i] : 0.f;
          Psh[(wid * 16 + 4 * lg + i) * LDPh + tn * 16 + lr] = f2h(v);
        }
      }
      asm volatile("s_waitcnt lgkmcnt(0)" ::: "memory");
      __builtin_amdgcn_sched_barrier(0);
      // ---- PV MFMA: A = P fp16 (af pattern), B = V^T vector reads ----
#pragma unroll
      for (int c2 = 0; c2 < 2; c2++) {
        u16x8 pa = *reinterpret_cast<const u16x8*>(&Psh[(wid * 16 + lr) * LDPh + c2 * 32 + 8 * lg]);
#pragma unroll
        for (int jn = 0; jn < 4; jn++) {
          u16x8 vb = *reinterpret_cast<const u16x8*>(&Vt[(jn * 16 + lr) * LDVT + c2 * 32 + 8 * lg]);
          oacc[jn] = mfma16h(pa, vb, oacc[jn]);
        }
      }
    }
  }

  // ---- epilogue: two 128-row chunks through Rs (validated pattern each) ----
#pragma unroll
  for (int ch = 0; ch < 2; ch++) {
    __syncthreads();  // Psh reads (ch0) / prior chunk stores (ch1) done
    if ((wid >> 3) == ch) {
      int wl = wid & 7;
#pragma unroll
      for (int jn = 0; jn < 4; jn++)
#pragma unroll
        for (int i = 0; i < 4; i++)
          Rs[(wl * 16 + 4 * lg + i) * LDR + jn * 16 + lr] = oacc[jn][i];
    }
    __syncthreads();
    if (tid < 128) {
      float s1 = 0.f, s2 = 0.f;
      for (int j = 0; j < 64; j++) { float v = Rs[tid * LDR + j]; s1 += v; s2 += v * v; }
      float mu = s1 * (1.f / 64.f);
      float var = s2 * (1.f / 64.f) - mu * mu;
      mus[tid] = mu; rstds[tid] = rsqrtf(var + 1e-5f);
    }
    __syncthreads();
    for (int p = tid; p < 8192; p += 1024) {
      int sl = p >> 6, j = p & 63;
      float y = (Rs[sl * LDR + j] - mus[sl]) * rstds[sl] * lnw[j] + lnb[j];
      y = y / (1.f + expf(-y));
      Y[((size_t)b * 2048 + qbase + ch * 128 + sl) * 1024 + h * 64 + j] = f2h(y);
    }
  }
}

// ---------------- f32 patch for rows s < SP, from rotated hi+lo (validated) ----------------
#define SP 32
__global__ __launch_bounds__(256) void k_patch(
    const u16* __restrict__ Qr, const u16* __restrict__ qlo,
    const u16* __restrict__ Kr, const u16* __restrict__ klo,
    const u16* __restrict__ vh_,
    const float* __restrict__ lnw, const float* __restrict__ lnb,
    u16* __restrict__ Y) {
  const int bh = blockIdx.x, b = bh >> 4, h = bh & 15;
  __shared__ float qs[SP][132], ks[SP][132];
  __shared__ float vs[SP][64], rs[SP][64];
  __shared__ float ps[SP][SP];
  __shared__ float mus[SP], rstds[SP];
  const int tid = threadIdx.x;
  const float lg2g = log2f(1.0f - exp2f(-5.0f - (float)h));

  for (int p = tid; p < SP * 128; p += 256) {
    int s = p >> 7, d = p & 127;
    size_t oh = ((size_t)bh * 2048 + s) * 128 + d;
    size_t ol = ((size_t)bh * 32 + s) * 128 + d;
    qs[s][d] = h2f(Qr[oh]) + h2f(qlo[ol]);
    ks[s][d] = h2f(Kr[oh]) + h2f(klo[ol]);
  }
  for (int p = tid; p < SP * 64; p += 256) {
    int s = p >> 6, d = p & 63;
    vs[s][d] = h2f(vh_[((size_t)bh * 2048 + s) * 64 + d]);
  }
  __syncthreads();
  for (int p = tid; p < SP * SP; p += 256) {
    int s = p / SP, t = p % SP;
    float sc = 0.f;
    if (t <= s) {
      for (int d = 0; d < 128; d += 4) {
        float4 q4 = *reinterpret_cast<const float4*>(&qs[s][d]);
        float4 k4 = *reinterpret_cast<const float4*>(&ks[t][d]);
        sc += q4.x * k4.x + q4.y * k4.y + q4.z * k4.z + q4.w * k4.w;
      }
      sc *= exp2f((float)(s - t) * lg2g);
    }
    ps[s][t] = sc;
  }
  __syncthreads();
  for (int p = tid; p < SP * 64; p += 256) {
    int s = p >> 6, j = p & 63;
    float r = 0.f;
    for (int t = 0; t <= s; t++) r += ps[s][t] * vs[t][j];
    rs[s][j] = r;
  }
  __syncthreads();
  if (tid < SP) {
    float s1 = 0.f, s2 = 0.f;
    for (int j = 0; j < 64; j++) { float v = rs[tid][j]; s1 += v; s2 += v * v; }
    float mu = s1 * (1.f / 64.f);
    float var = s2 * (1.f / 64.f) - mu * mu;
    mus[tid] = mu; rstds[tid] = rsqrtf(var + 1e-5f);
  }
  __syncthreads();
  for (int p = tid; p < SP * 64; p += 256) {
    int s = p >> 6, j = p & 63;
    float y = (rs[s][j] - mus[s]) * rstds[s] * lnw[j] + lnb[j];
    y = y / (1.f + expf(-y));
    Y[((size_t)b * 2048 + s) * 1024 + h * 64 + j] = f2h(y);
  }
}

extern "C" void kernel_launch(void* const* d_in, const int* in_sizes, int n_in,
                              void* d_out, int out_size, void* d_ws, size_t ws_size,
                              hipStream_t stream) {
  const float* x   = (const float*)d_in[0];
  const float* Wq  = (const float*)d_in[1];
  const float* Wk  = (const float*)d_in[2];
  const float* Wv  = (const float*)d_in[3];
  const float* Wo  = (const float*)d_in[4];
  const float* lnw = (const float*)d_in[5];
  const float* lnb = (const float*)d_in[6];
  float* out = (float*)d_out;

  char* ws = (char*)d_ws;
  u16*   Qr   = (u16*)(ws + 0);            // [BH][S][128] rotated fp16, 32 MB
  u16*   Kr   = (u16*)(ws + 33554432);     // 32 MB
  u16*   vh   = (u16*)(ws + 67108864);     // [BH][S][64] fp16, 16 MB
  u16*   Wqh  = (u16*)(ws + 67108864);     // Wq/Wk splits overlay vh (dead before V-GEMM)
  u16*   Wql  = (u16*)(ws + 69206016);
  u16*   Wkh  = (u16*)(ws + 71303168);
  u16*   Wkl  = (u16*)(ws + 73400320);
  u16*   xh   = (u16*)(ws + 83886080);     // fp16 hi, 16 MB (VT overlays after GEMMs)
  u16*   xl   = (u16*)(ws + 100663296);    // fp16 lo, 16 MB (Y overlays after GEMMs)
  u16*   VT   = (u16*)(ws + 83886080);
  u16*   Y    = (u16*)(ws + 100663296);
  u16*   qlo  = (u16*)(ws + 117440512);    // [BH][32][128] lo-residual
  u16*   klo  = (u16*)(ws + 117964800);
  float* cosT = (float*)(ws + 118489088);
  float* sinT = (float*)(ws + 119013376);
  u16*   Wvh  = (u16*)(ws + 119537664);    // 2 MB each
  u16*   Wvl  = (u16*)(ws + 121634816);
  u16*   Woh  = (u16*)(ws + 123731968);
  u16*   Wol  = (u16*)(ws + 125829120);
  // total 127,926,272 B

  k_trig<<<512, 256, 0, stream>>>(cosT, sinT);
  k_split<<<8192, 256, 0, stream>>>(x, xh, xl, 8388608);
  k_split<<<1024, 256, 0, stream>>>(Wq, Wqh, Wql, 1048576);
  k_split<<<1024, 256, 0, stream>>>(Wk, Wkh, Wkl, 1048576);
  k_split<<<1024, 256, 0, stream>>>(Wv, Wvh, Wvl, 1048576);
  k_split<<<1024, 256, 0, stream>>>(Wo, Woh, Wol, 1048576);

  dim3 gg(8, 64);  // N/128, M/128 (swizzled inside)
  k_gemm16<0><<<gg, 256, 0, stream>>>(xh, xl, Wqh, Wql, 8192, 1024, 1024, Qr, qlo, nullptr, cosT, sinT);
  k_gemm16<0><<<gg, 256, 0, stream>>>(xh, xl, Wkh, Wkl, 8192, 1024, 1024, Kr, klo, nullptr, cosT, sinT);
  k_gemm16<2><<<gg, 256, 0, stream>>>(xh, nullptr, Wvh, nullptr, 8192, 1024, 1024, vh, nullptr, nullptr, nullptr, nullptr);  // clobbers Wq/Wk splits (dead)

  k_vt<<<dim3(32, 64), 256, 0, stream>>>(vh, VT);   // xh dead from here

  k_retention<<<512, 1024, 0, stream>>>(Qr, Kr, VT, lnw, lnb, Y);  // xl dead from here

  k_patch<<<64, 256, 0, stream>>>(Qr, qlo, Kr, klo, vh, lnw, lnb, Y);

  k_gemm16<3><<<gg, 256, 0, stream>>>(Y, nullptr, Woh, nullptr, 8192, 1024, 1024, nullptr, nullptr, out, nullptr, nullptr);
}

// Round 19
// 361.792 us; speedup vs baseline: 11.7247x; 1.0909x over previous
//
#include <hip/hip_runtime.h>

typedef unsigned short u16;
typedef _Float16 f16;
typedef _Float16 f16x8 __attribute__((ext_vector_type(8)));
typedef float f32x4 __attribute__((ext_vector_type(4)));
typedef unsigned short u16x8 __attribute__((ext_vector_type(8)));
typedef unsigned short u16x4 __attribute__((ext_vector_type(4)));

typedef __attribute__((address_space(3))) unsigned int lds_u32;
typedef __attribute__((address_space(1))) unsigned int glb_u32;

static __device__ __forceinline__ u16 f2h(float f) {
  f16 h = (f16)f;
  return __builtin_bit_cast(u16, h);
}
static __device__ __forceinline__ float h2f(u16 h) {
  return (float)__builtin_bit_cast(f16, h);
}

static __device__ __forceinline__ f32x4 mfma16h(u16x8 a, u16x8 b, f32x4 c) {
  return __builtin_amdgcn_mfma_f32_16x16x32_f16(
      __builtin_bit_cast(f16x8, a), __builtin_bit_cast(f16x8, b), c, 0, 0, 0);
}

static __device__ __forceinline__ void glds16(const u16* g, u16* l) {
  __builtin_amdgcn_global_load_lds((const glb_u32*)g, (lds_u32*)l, 16, 0, 0);
}

// stage a [128][32] u16 linear tile (512 16B-chunks) via global_load_lds, 256 threads
static __device__ __forceinline__ void glds_tile(
    const u16* __restrict__ src, int row0, int K, int k0, u16* tile, int tid) {
#pragma unroll
  for (int call = 0; call < 2; call++) {
    int c = call * 256 + tid;
    int row = c >> 2, col = (c & 3) * 8;
    glds16(&src[(size_t)(row0 + row) * K + k0 + col], tile + (size_t)(c & ~63) * 8);
  }
}

// ---------------- cos/sin tables [S][64], f64-accurate ----------------
__global__ void k_trig(float* __restrict__ cosT, float* __restrict__ sinT) {
  int idx = blockIdx.x * blockDim.x + threadIdx.x;  // S*64 threads
  int s = idx >> 6, j = idx & 63;
  double theta = exp2(-0.4152410118609203 * (double)j);  // 10000^(-j/32), f64
  double ang = (double)s * theta;
  cosT[idx] = (float)cos(ang);
  sinT[idx] = (float)sin(ang);
}

// ---------------- f32 -> fp16 hi/lo Dekker pre-split ----------------
__global__ void k_split(const float* __restrict__ src, u16* __restrict__ hi,
                        u16* __restrict__ lo, int n) {
  int i = (blockIdx.x * blockDim.x + threadIdx.x) * 4;
  if (i >= n) return;
  float4 v = *reinterpret_cast<const float4*>(src + i);
  const float* vp = reinterpret_cast<const float*>(&v);
  u16x4 hv, lv;
#pragma unroll
  for (int e = 0; e < 4; e++) {
    hv[e] = f2h(vp[e]);
    lv[e] = f2h(vp[e] - h2f(hv[e]));
  }
  *reinterpret_cast<u16x4*>(hi + i) = hv;
  *reinterpret_cast<u16x4*>(lo + i) = lv;
}

// ---------------- TN GEMM, global_load_lds staging, linear [128][32] tiles ----------------
// MODE 0: 3-pass Dekker (A hi/lo, B hi/lo pre-split fp16); rotate-scatter epilogue + lo (s<32)
// MODE 2: single-pass (A hi, B hi pre-split); scatter [BH][S][64] (V)
// MODE 3: single-pass (A=Y fp16, B hi pre-split); outF f32 row-major
template <int MODE>
__global__ __launch_bounds__(256) void k_gemm16(
    const u16* __restrict__ Ah_, const u16* __restrict__ Al_,
    const u16* __restrict__ Bh_, const u16* __restrict__ Bl_,
    int M, int N, int K,
    u16* __restrict__ outH, u16* __restrict__ loB, float* __restrict__ outF,
    const float* __restrict__ cosT, const float* __restrict__ sinT) {
  constexpr int LDT = 32;
  constexpr int NTILE = (MODE == 0) ? 4 : 2;
  __shared__ __align__(16) u16 SMEM[NTILE * 128 * 32];
  u16* Ash = SMEM;
  u16* Asl = SMEM + 4096;
  u16* Bsh = SMEM + (MODE == 0 ? 8192 : 4096);
  u16* Bsl = SMEM + 12288;
  const int tid = threadIdx.x;
  // XCD swizzle: each XCD owns 8 consecutive A row-panels (grid must be 8 x 64)
  const int lB = (int)blockIdx.y * 8 + (int)blockIdx.x;
  const int xcd = lB & 7, rr = lB >> 3;
  const int m0 = (xcd * 8 + (rr >> 3)) * 128;
  const int n0 = (rr & 7) * 128;
  const int lane = tid & 63, lr = lane & 15, lg = lane >> 4;
  const int wid = tid >> 6;
  const int wm = (wid >> 1) * 64, wn = (wid & 1) * 64;

  const f32x4 fz = {0.f, 0.f, 0.f, 0.f};
  f32x4 acc[4][4];
#pragma unroll
  for (int i = 0; i < 4; i++)
#pragma unroll
    for (int j = 0; j < 4; j++) acc[i][j] = fz;

  for (int k0 = 0; k0 < K; k0 += 32) {
    __syncthreads();
    glds_tile(Ah_, m0, K, k0, Ash, tid);
    glds_tile(Bh_, n0, K, k0, Bsh, tid);
    if constexpr (MODE == 0) {
      glds_tile(Al_, m0, K, k0, Asl, tid);
      glds_tile(Bl_, n0, K, k0, Bsl, tid);
    }
    __syncthreads();  // drains vmcnt(0) for global_load_lds

    u16x8 ah[4], al[4], bh[4], bl[4];
#pragma unroll
    for (int i = 0; i < 4; i++) {
      ah[i] = *reinterpret_cast<const u16x8*>(&Ash[(wm + i * 16 + lr) * LDT + 8 * lg]);
      if constexpr (MODE == 0)
        al[i] = *reinterpret_cast<const u16x8*>(&Asl[(wm + i * 16 + lr) * LDT + 8 * lg]);
    }
#pragma unroll
    for (int j = 0; j < 4; j++) {
      bh[j] = *reinterpret_cast<const u16x8*>(&Bsh[(wn + j * 16 + lr) * LDT + 8 * lg]);
      if constexpr (MODE == 0)
        bl[j] = *reinterpret_cast<const u16x8*>(&Bsl[(wn + j * 16 + lr) * LDT + 8 * lg]);
    }
#pragma unroll
    for (int i = 0; i < 4; i++)
#pragma unroll
      for (int j = 0; j < 4; j++) {
        acc[i][j] = mfma16h(ah[i], bh[j], acc[i][j]);
        if constexpr (MODE == 0) {
          acc[i][j] = mfma16h(ah[i], bl[j], acc[i][j]);
          acc[i][j] = mfma16h(al[i], bh[j], acc[i][j]);
        }
      }
  }

#pragma unroll
  for (int i = 0; i < 4; i++)
#pragma unroll
    for (int j = 0; j < 4; j++)
#pragma unroll
      for (int r = 0; r < 4; r++) {
        int m = m0 + wm + i * 16 + 4 * lg + r;
        int n = n0 + wn + j * 16 + lr;
        float v = acc[i][j][r];
        if constexpr (MODE == 3) {
          outF[(size_t)m * N + n] = v;
        } else {
          int b = m >> 11, s = m & 2047;  // S = 2048
          int h = n >> 6, jj = n & 63;
          if constexpr (MODE == 2) {
            outH[(((size_t)(b * 16 + h)) * 2048 + s) * 64 + jj] = f2h(v);
          } else {
            float cv = cosT[s * 64 + jj], sv = sinT[s * 64 + jj];
            float a = v * cv, bb = v * sv;
            size_t o = (((size_t)(b * 16 + h)) * 2048 + s) * 128 + jj;
            u16 ahh = f2h(a), bhh = f2h(bb);
            outH[o] = ahh;
            outH[o + 64] = bhh;
            if (s < 32) {
              size_t ol = (((size_t)(b * 16 + h)) * 32 + s) * 128 + jj;
              loB[ol] = f2h(a - h2f(ahh));
              loB[ol + 64] = f2h(bb - h2f(bhh));
            }
          }
        }
      }
}

// ---------------- V transpose: vh [BH][S][64] -> VT [BH][64][S] (validated) ----------------
__global__ __launch_bounds__(256) void k_vt(const u16* __restrict__ vh,
                                            u16* __restrict__ VT) {
  __shared__ u16 T[64][72];
  const int tid = threadIdx.x;
  const int bh = blockIdx.y, s0 = blockIdx.x * 64;
#pragma unroll
  for (int p = 0; p < 2; p++) {
    int c = p * 256 + tid;
    int r = c >> 3, j0 = (c & 7) * 8;
    *reinterpret_cast<u16x8*>(&T[r][j0]) =
        *reinterpret_cast<const u16x8*>(&vh[((size_t)bh * 2048 + s0 + r) * 64 + j0]);
  }
  __syncthreads();
#pragma unroll
  for (int p = 0; p < 2; p++) {
    int c = p * 256 + tid;
    int j = c >> 3, r0 = (c & 7) * 8;
    u16x8 o;
#pragma unroll
    for (int e = 0; e < 8; e++) o[e] = T[r0 + e][j];
    *reinterpret_cast<u16x8*>(&VT[((size_t)bh * 64 + j) * 2048 + s0 + r0]) = o;
  }
}

// ---------------- retention: QBLK=256 (16 waves), balanced heavy/light pairing ----------------
constexpr int LDK = 136;
constexpr int LDPh = 72;
constexpr int LDVT = 72;
constexpr int LDR = 65;

__global__ __launch_bounds__(1024) void k_retention(
    const u16* __restrict__ Qr, const u16* __restrict__ Kr,
    const u16* __restrict__ VT_,
    const float* __restrict__ lnw, const float* __restrict__ lnb,
    u16* __restrict__ Y) {
  // LDS: Ks 17408 | Vt 9216 | Psh[256][72] 36864 = 63488; Rs (128x65x4=33280) overlays base.
  __shared__ __align__(16) char SM[17408 + 9216 + 36864];
  u16*   Ks  = (u16*)SM;
  u16*   Vt  = (u16*)(SM + 17408);
  u16*   Psh = (u16*)(SM + 26624);
  float* Rs  = (float*)SM;
  __shared__ float mus[128], rstds[128];

  const int tid = threadIdx.x;
  // Balanced pairing: blocks lB and lB+256 land on the same CU under round-robin
  // dispatch; arrange qt so their work sums to the per-CU average (4qt+4 pairs sum 36).
  // XCD clustering preserved: bh = xcd*8 + w.
  const int lB = blockIdx.x;            // 512 blocks
  const int half = lB >> 8;             // 0 = heavy half, 1 = light half
  const int r = lB & 255;
  const int xcd = r & 7;
  const int v = (r >> 3) & 3;
  const int w = r >> 5;                 // 0..7
  const int bh = xcd * 8 + w;
  const int qt = half ? v : 7 - v;      // pair sums: (7-v) + v = 7
  const int b = bh >> 4, h = bh & 15;
  const int qbase = qt * 256;
  const int wid = tid >> 6, lane = tid & 63, lr = lane & 15, lg = lane >> 4;
  const int qg = qbase + wid * 16;  // this wave's first q row
  const float lg2g = log2f(1.0f - exp2f(-5.0f - (float)h));
  const float gam = exp2f(lg2g);
  const float gam2 = gam * gam, gam3 = gam2 * gam;

  // ---- prologue: stage Q' in four 64-row rounds through Ks, read A-fragments ----
  u16x8 qa[4];
#pragma unroll
  for (int hh = 0; hh < 4; hh++) {
    {  // stage 64x128 tile: 1024 chunks, 1 per thread
      int row = tid >> 4, col = (tid & 15) * 8;
      *reinterpret_cast<int4*>(&Ks[row * LDK + col]) =
          *reinterpret_cast<const int4*>(&Qr[((size_t)bh * 2048 + qbase + hh * 64 + row) * 128 + col]);
    }
    __syncthreads();
    if ((wid >> 2) == hh) {
      int wl = wid & 3;
#pragma unroll
      for (int dc = 0; dc < 4; dc++)
        qa[dc] = *reinterpret_cast<const u16x8*>(&Ks[(wl * 16 + lr) * LDK + dc * 32 + 8 * lg]);
    }
    __syncthreads();
  }

  const f32x4 fz = {0.f, 0.f, 0.f, 0.f};
  f32x4 oacc[4];
#pragma unroll
  for (int j = 0; j < 4; j++) oacc[j] = fz;

  const int ntiles = 4 * qt + 4;
  for (int kt = 0; kt < ntiles; ++kt) {
    const int t0 = kt * 64;
    const bool active = (t0 <= qg + 15);  // wave-uniform
    __syncthreads();  // prior tile's Ks/Vt/Psh reads done
    {  // stage K tile: 1024 chunks, 1 per thread
      int row = tid >> 4, col = (tid & 15) * 8;
      *reinterpret_cast<int4*>(&Ks[row * LDK + col]) =
          *reinterpret_cast<const int4*>(&Kr[((size_t)bh * 2048 + t0 + row) * 128 + col]);
    }
    if (tid < 512) {  // stage V^T tile: 512 chunks (waves 0-7)
      int j = tid >> 3, tl0 = (tid & 7) * 8;
      *reinterpret_cast<u16x8*>(&Vt[j * LDVT + tl0]) =
          *reinterpret_cast<const u16x8*>(&VT_[((size_t)bh * 64 + j) * 2048 + t0 + tl0]);
    }
    __syncthreads();

    if (active) {
      // ---- QK^T: D rows = q (4*lg+i), cols = t (lr); decay via 1 exp2 + muls ----
#pragma unroll
      for (int tn = 0; tn < 4; tn++) {
        f32x4 st = fz;
#pragma unroll
        for (int dc = 0; dc < 4; dc++) {
          u16x8 kb = *reinterpret_cast<const u16x8*>(&Ks[(tn * 16 + lr) * LDK + dc * 32 + 8 * lg]);
          st = mfma16h(qa[dc], kb, st);
        }
        const int t = t0 + tn * 16 + lr;
        const int q0 = qg + 4 * lg;
        const float dec0 = exp2f((float)(q0 - t) * lg2g);
        const float dd[4] = {dec0, dec0 * gam, dec0 * gam2, dec0 * gam3};
#pragma unroll
        for (int i = 0; i < 4; i++) {
          float v2 = (t <= q0 + i) ? st[i] * dd[i] : 0.f;
          Psh[(wid * 16 + 4 * lg + i) * LDPh + tn * 16 + lr] = f2h(v2);
        }
      }
      asm volatile("s_waitcnt lgkmcnt(0)" ::: "memory");
      __builtin_amdgcn_sched_barrier(0);
      // ---- PV MFMA: A = P fp16 (af pattern), B = V^T vector reads ----
#pragma unroll
      for (int c2 = 0; c2 < 2; c2++) {
        u16x8 pa = *reinterpret_cast<const u16x8*>(&Psh[(wid * 16 + lr) * LDPh + c2 * 32 + 8 * lg]);
#pragma unroll
        for (int jn = 0; jn < 4; jn++) {
          u16x8 vb = *reinterpret_cast<const u16x8*>(&Vt[(jn * 16 + lr) * LDVT + c2 * 32 + 8 * lg]);
          oacc[jn] = mfma16h(pa, vb, oacc[jn]);
        }
      }
    }
  }

  // ---- epilogue: two 128-row chunks through Rs (validated pattern each) ----
#pragma unroll
  for (int ch = 0; ch < 2; ch++) {
    __syncthreads();  // Psh reads (ch0) / prior chunk stores (ch1) done
    if ((wid >> 3) == ch) {
      int wl = wid & 7;
#pragma unroll
      for (int jn = 0; jn < 4; jn++)
#pragma unroll
        for (int i = 0; i < 4; i++)
          Rs[(wl * 16 + 4 * lg + i) * LDR + jn * 16 + lr] = oacc[jn][i];
    }
    __syncthreads();
    if (tid < 128) {
      float s1 = 0.f, s2 = 0.f;
      for (int j = 0; j < 64; j++) { float v = Rs[tid * LDR + j]; s1 += v; s2 += v * v; }
      float mu = s1 * (1.f / 64.f);
      float var = s2 * (1.f / 64.f) - mu * mu;
      mus[tid] = mu; rstds[tid] = rsqrtf(var + 1e-5f);
    }
    __syncthreads();
    for (int p = tid; p < 8192; p += 1024) {
      int sl = p >> 6, j = p & 63;
      float y = (Rs[sl * LDR + j] - mus[sl]) * rstds[sl] * lnw[j] + lnb[j];
      y = y / (1.f + expf(-y));
      Y[((size_t)b * 2048 + qbase + ch * 128 + sl) * 1024 + h * 64 + j] = f2h(y);
    }
  }
}

// ---------------- f32 patch for rows s < SP, from rotated hi+lo (validated) ----------------
#define SP 32
__global__ __launch_bounds__(256) void k_patch(
    const u16* __restrict__ Qr, const u16* __restrict__ qlo,
    const u16* __restrict__ Kr, const u16* __restrict__ klo,
    const u16* __restrict__ vh_,
    const float* __restrict__ lnw, const float* __restrict__ lnb,
    u16* __restrict__ Y) {
  const int bh = blockIdx.x, b = bh >> 4, h = bh & 15;
  __shared__ float qs[SP][132], ks[SP][132];
  __shared__ float vs[SP][64], rs[SP][64];
  __shared__ float ps[SP][SP];
  __shared__ float mus[SP], rstds[SP];
  const int tid = threadIdx.x;
  const float lg2g = log2f(1.0f - exp2f(-5.0f - (float)h));

  for (int p = tid; p < SP * 128; p += 256) {
    int s = p >> 7, d = p & 127;
    size_t oh = ((size_t)bh * 2048 + s) * 128 + d;
    size_t ol = ((size_t)bh * 32 + s) * 128 + d;
    qs[s][d] = h2f(Qr[oh]) + h2f(qlo[ol]);
    ks[s][d] = h2f(Kr[oh]) + h2f(klo[ol]);
  }
  for (int p = tid; p < SP * 64; p += 256) {
    int s = p >> 6, d = p & 63;
    vs[s][d] = h2f(vh_[((size_t)bh * 2048 + s) * 64 + d]);
  }
  __syncthreads();
  for (int p = tid; p < SP * SP; p += 256) {
    int s = p / SP, t = p % SP;
    float sc = 0.f;
    if (t <= s) {
      for (int d = 0; d < 128; d += 4) {
        float4 q4 = *reinterpret_cast<const float4*>(&qs[s][d]);
        float4 k4 = *reinterpret_cast<const float4*>(&ks[t][d]);
        sc += q4.x * k4.x + q4.y * k4.y + q4.z * k4.z + q4.w * k4.w;
      }
      sc *= exp2f((float)(s - t) * lg2g);
    }
    ps[s][t] = sc;
  }
  __syncthreads();
  for (int p = tid; p < SP * 64; p += 256) {
    int s = p >> 6, j = p & 63;
    float r = 0.f;
    for (int t = 0; t <= s; t++) r += ps[s][t] * vs[t][j];
    rs[s][j] = r;
  }
  __syncthreads();
  if (tid < SP) {
    float s1 = 0.f, s2 = 0.f;
    for (int j = 0; j < 64; j++) { float v = rs[tid][j]; s1 += v; s2 += v * v; }
    float mu = s1 * (1.f / 64.f);
    float var = s2 * (1.f / 64.f) - mu * mu;
    mus[tid] = mu; rstds[tid] = rsqrtf(var + 1e-5f);
  }
  __syncthreads();
  for (int p = tid; p < SP * 64; p += 256) {
    int s = p >> 6, j = p & 63;
    float y = (rs[s][j] - mus[s]) * rstds[s] * lnw[j] + lnb[j];
    y = y / (1.f + expf(-y));
    Y[((size_t)b * 2048 + s) * 1024 + h * 64 + j] = f2h(y);
  }
}

extern "C" void kernel_launch(void* const* d_in, const int* in_sizes, int n_in,
                              void* d_out, int out_size, void* d_ws, size_t ws_size,
                              hipStream_t stream) {
  const float* x   = (const float*)d_in[0];
  const float* Wq  = (const float*)d_in[1];
  const float* Wk  = (const float*)d_in[2];
  const float* Wv  = (const float*)d_in[3];
  const float* Wo  = (const float*)d_in[4];
  const float* lnw = (const float*)d_in[5];
  const float* lnb = (const float*)d_in[6];
  float* out = (float*)d_out;

  char* ws = (char*)d_ws;
  u16*   Qr   = (u16*)(ws + 0);            // [BH][S][128] rotated fp16, 32 MB
  u16*   Kr   = (u16*)(ws + 33554432);     // 32 MB
  u16*   vh   = (u16*)(ws + 67108864);     // [BH][S][64] fp16, 16 MB
  u16*   Wqh  = (u16*)(ws + 67108864);     // Wq/Wk splits overlay vh (dead before V-GEMM)
  u16*   Wql  = (u16*)(ws + 69206016);
  u16*   Wkh  = (u16*)(ws + 71303168);
  u16*   Wkl  = (u16*)(ws + 73400320);
  u16*   xh   = (u16*)(ws + 83886080);     // fp16 hi, 16 MB (VT overlays after GEMMs)
  u16*   xl   = (u16*)(ws + 100663296);    // fp16 lo, 16 MB (Y overlays after GEMMs)
  u16*   VT   = (u16*)(ws + 83886080);
  u16*   Y    = (u16*)(ws + 100663296);
  u16*   qlo  = (u16*)(ws + 117440512);    // [BH][32][128] lo-residual
  u16*   klo  = (u16*)(ws + 117964800);
  float* cosT = (float*)(ws + 118489088);
  float* sinT = (float*)(ws + 119013376);
  u16*   Wvh  = (u16*)(ws + 119537664);    // 2 MB each
  u16*   Wvl  = (u16*)(ws + 121634816);
  u16*   Woh  = (u16*)(ws + 123731968);
  u16*   Wol  = (u16*)(ws + 125829120);
  // total 127,926,272 B

  k_trig<<<512, 256, 0, stream>>>(cosT, sinT);
  k_split<<<8192, 256, 0, stream>>>(x, xh, xl, 8388608);
  k_split<<<1024, 256, 0, stream>>>(Wq, Wqh, Wql, 1048576);
  k_split<<<1024, 256, 0, stream>>>(Wk, Wkh, Wkl, 1048576);
  k_split<<<1024, 256, 0, stream>>>(Wv, Wvh, Wvl, 1048576);
  k_split<<<1024, 256, 0, stream>>>(Wo, Woh, Wol, 1048576);

  dim3 gg(8, 64);  // N/128, M/128 (swizzled inside)
  k_gemm16<0><<<gg, 256, 0, stream>>>(xh, xl, Wqh, Wql, 8192, 1024, 1024, Qr, qlo, nullptr, cosT, sinT);
  k_gemm16<0><<<gg, 256, 0, stream>>>(xh, xl, Wkh, Wkl, 8192, 1024, 1024, Kr, klo, nullptr, cosT, sinT);
  k_gemm16<2><<<gg, 256, 0, stream>>>(xh, nullptr, Wvh, nullptr, 8192, 1024, 1024, vh, nullptr, nullptr, nullptr, nullptr);  // clobbers Wq/Wk splits (dead)

  k_vt<<<dim3(32, 64), 256, 0, stream>>>(vh, VT);   // xh dead from here

  k_retention<<<512, 1024, 0, stream>>>(Qr, Kr, VT, lnw, lnb, Y);  // xl dead from here

  k_patch<<<64, 256, 0, stream>>>(Qr, qlo, Kr, klo, vh, lnw, lnb, Y);

  k_gemm16<3><<<gg, 256, 0, stream>>>(Y, nullptr, Woh, nullptr, 8192, 1024, 1024, nullptr, nullptr, out, nullptr, nullptr);
}